// Round 1
// baseline (652.177 us; speedup 1.0000x reference)
//
#include <hip/hip_runtime.h>

// R1: column-plane layout for all 16-bit feature tensors: [4][rows][16]
// (plane p = cols 16p..16p+16). A g-plane is 3.2MB -> fits one XCD's 4MB L2.
// k_edge_agg is XCD-pinned per plane (blockIdx%8 round-robin), streams
// csr/offs/pos + output via non-temporal ops so the plane owns the L2.

#define N_PTS   100000
#define M_CL    12500
#define E0_N    1600000
#define E1_N    400000

#define NB      256
#define BIN_CAP 32
#define RANGE0  391
#define RANGE1  49           // also used for labels (ceil(12500/256))
#define BCAP0   8192
#define BCAP1   2048
#define BCAPL   1024

#define LSTR    72           // LDS row stride (shorts): 144 B, 16-B aligned

typedef unsigned short ushortT;
typedef short  short8 __attribute__((ext_vector_type(8)));
typedef float  v4f    __attribute__((ext_vector_type(4)));
typedef _Float16 h2   __attribute__((ext_vector_type(2)));
typedef unsigned u4v  __attribute__((ext_vector_type(4)));

__device__ inline ushortT f2bf(float x){
  union{float f; unsigned u;} v; v.f = x;
  unsigned r = v.u + 0x7fffu + ((v.u >> 16) & 1u);   // RNE
  return (ushortT)(r >> 16);
}
__device__ inline float bf2f(ushortT h){
  union{unsigned u; float f;} v; v.u = ((unsigned)h) << 16;
  return v.f;
}
__device__ inline ushortT f2h(float x){
  union{_Float16 h; ushortT u;} v; v.h = (_Float16)x;
  return v.u;
}
__device__ inline float h2f(ushortT u){
  union{ushortT u; _Float16 h;} v; v.u = u;
  return (float)v.h;
}
__device__ inline h2 pkmax(h2 a, h2 b){ return __builtin_elementwise_max(a, b); }
__device__ inline h2 u2h(unsigned u){ union{unsigned u; h2 h;} v{u}; return v.h; }

// ============================ weight prep + counter init (1 dispatch) ============================

struct WSrc { const float* p[16]; };

__global__ __launch_bounds__(256) void k_init_wprep(WSrc s, ushortT* __restrict__ wt, ushortT* __restrict__ wtc,
                                                    int* c0, int* c1, int* cL){
  int blk = blockIdx.x;
  if (blk == 0){
    int t = threadIdx.x;
    c0[t] = t*BCAP0; c1[t] = t*BCAP1; cL[t] = t*BCAPL;
    return;
  }
  int slot = blk - 1;
  if (slot < 15){
    const float* src = s.p[slot];
    ushortT* dst = wt + slot*4096;
    for (int e=threadIdx.x; e<4096; e+=256){
      int nn = e>>6, kk = e&63;
      dst[e] = f2bf(src[kk*64+nn]);
    }
  } else {
    const float* src = s.p[15];
    for (int e=threadIdx.x; e<1024; e+=256){
      int nn = e>>6, kk = e&63;
      wtc[e] = (nn<8) ? f2bf(src[kk*8+nn]) : (ushortT)0;
    }
  }
}

// ============================ bucketed CSR build (l0 + l1 + labels, merged) ============================
// LAB: edge e is (src=e, dst=edges[e]) — the labels list.

template<int RANGE, bool LAB>
__device__ void bin_seg(const int* __restrict__ edges, int E,
                        int* __restrict__ bcur, unsigned* __restrict__ tmp,
                        int bid, int nblk,
                        unsigned* stage, int* scnt, int* sbase){
  int tid = threadIdx.x;
  int nchunks = (E + 2047) / 2048;
  for (int c = bid; c < nchunks; c += nblk){
    int base = c*2048;
    scnt[tid] = 0;
    __syncthreads();
    #pragma unroll
    for (int r=0;r<8;++r){
      int e = base + r*256 + tid;
      if (e < E){
        int s, d;
        if (LAB){ s = e; d = edges[e]; }
        else    { s = edges[2*e]; d = edges[2*e+1]; }
        int bk = d / RANGE;
        unsigned packed = ((unsigned)s << 11) | (unsigned)(d - bk*RANGE);
        int pos = atomicAdd(&scnt[bk], 1);
        if (pos < BIN_CAP) stage[bk*BIN_CAP+pos] = packed;
        else tmp[atomicAdd(&bcur[bk],1)] = packed;
      }
    }
    __syncthreads();
    {
      int nfl = scnt[tid]; if (nfl > BIN_CAP) nfl = BIN_CAP;
      sbase[tid] = atomicAdd(&bcur[tid], nfl);
    }
    __syncthreads();
    int wv = tid >> 6, ln = tid & 63;
    for (int bb=0; bb<32; ++bb){
      int bk = wv*64 + bb*2 + (ln>>5);
      int ent = ln & 31;
      int nf = scnt[bk]; if (nf > BIN_CAP) nf = BIN_CAP;
      if (ent < nf) tmp[sbase[bk]+ent] = stage[bk*BIN_CAP+ent];
    }
    __syncthreads();
  }
}

__global__ __launch_bounds__(256) void k_bin_all(const int* __restrict__ l0e, const int* __restrict__ l1e,
                                                 const int* __restrict__ labels,
                                                 int* bc0, int* bc1, int* bcL,
                                                 unsigned* t0, unsigned* t1, unsigned* tL){
  __shared__ unsigned stage[NB*BIN_CAP];
  __shared__ int scnt[NB];
  __shared__ int sbase[NB];
  int b = blockIdx.x;
  if (b < 256)      bin_seg<RANGE0,false>(l0e, E0_N, bc0, t0, b, 256, stage, scnt, sbase);
  else if (b < 452) bin_seg<RANGE1,false>(l1e, E1_N, bc1, t1, b-256, 196, stage, scnt, sbase);
  else              bin_seg<RANGE1,true >(labels, N_PTS, bcL, tL, b-452, 49, stage, scnt, sbase);
}

// exclusive scan of 256 bucket counts; blocks: 0->l0, 1->l1, 2->labels
__global__ void k_scan_all(const int* c0, int* bb0, int* e0,
                           const int* c1, int* bb1, int* e1,
                           const int* cL, int* bbL, int* eL){
  const int* cur; int* bb; int* offe; int BC;
  if (blockIdx.x == 0){ cur=c0; bb=bb0; offe=e0; BC=BCAP0; }
  else if (blockIdx.x == 1){ cur=c1; bb=bb1; offe=e1; BC=BCAP1; }
  else { cur=cL; bb=bbL; offe=eL; BC=BCAPL; }
  int lane = threadIdx.x & 63;
  int base = lane*4;
  int v0 = cur[base+0] - (base+0)*BC;
  int v1 = cur[base+1] - (base+1)*BC;
  int v2 = cur[base+2] - (base+2)*BC;
  int v3 = cur[base+3] - (base+3)*BC;
  int psum = v0+v1+v2+v3, sc = psum;
  #pragma unroll
  for (int st=1; st<64; st<<=1){
    int x = __shfl_up(sc, st, 64);
    if (lane >= st) sc += x;
  }
  int ex = sc - psum;
  bb[base+0] = ex;
  bb[base+1] = ex + v0;
  bb[base+2] = ex + v0 + v1;
  bb[base+3] = ex + v0 + v1 + v2;
  if (lane == 63) *offe = sc;
}

template<int RANGE, int BCAP, int K>
__device__ void csr_build_seg(const unsigned* __restrict__ tmp, const int* __restrict__ bcur,
                              const int* __restrict__ bb, int n,
                              int* __restrict__ offs, int* __restrict__ csr,
                              int b, int* hist, int* part){
  int tid = threadIdx.x;
  int dlo = b*RANGE;
  int range = n - dlo; if (range > RANGE) range = RANGE; if (range < 0) range = 0;
  int cnt = bcur[b] - b*BCAP;
  for (int t=tid; t<RANGE; t+=256) hist[t] = 0;
  __syncthreads();
  const unsigned* sl = tmp + (size_t)b*BCAP;
  for (int j=tid; j<cnt; j+=256) atomicAdd(&hist[sl[j] & 2047u], 1);
  __syncthreads();
  int s = 0; int loc[K];
  #pragma unroll
  for (int kk=0; kk<K; ++kk){
    int idx = tid*K + kk;
    int v = (idx < RANGE) ? hist[idx] : 0;
    loc[kk] = s; s += v;
  }
  part[tid] = s; __syncthreads();
  int own = s;
  for (int st=1; st<256; st<<=1){
    int x = (tid >= st) ? part[tid-st] : 0;
    __syncthreads();
    part[tid] += x;
    __syncthreads();
  }
  int ebase = part[tid] - own;
  int gb = bb[b];
  __syncthreads();
  #pragma unroll
  for (int kk=0; kk<K; ++kk){
    int idx = tid*K + kk;
    if (idx < RANGE){
      int ex = ebase + loc[kk];
      if (idx < range) offs[dlo+idx] = gb + ex;
      hist[idx] = ex;
    }
  }
  __syncthreads();
  for (int j=tid; j<cnt; j+=256){
    unsigned p = sl[j];
    int pos = atomicAdd(&hist[p & 2047u], 1);
    csr[gb + pos] = (int)(p >> 11);
  }
}

__global__ __launch_bounds__(256) void k_build_all(
    const unsigned* t0, const int* bc0, const int* bb0, int* offs0, int* csr0,
    const unsigned* t1, const int* bc1, const int* bb1, int* offs1, int* csr1,
    const unsigned* tL, const int* bcL, const int* bbL, int* offsL, int* csrL){
  __shared__ int hist[RANGE0];
  __shared__ int part[256];
  int b = blockIdx.x;
  if (b < 256)      csr_build_seg<RANGE0,BCAP0,2>(t0, bc0, bb0, N_PTS, offs0, csr0, b, hist, part);
  else if (b < 512) csr_build_seg<RANGE1,BCAP1,1>(t1, bc1, bb1, M_CL, offs1, csr1, b-256, hist, part);
  else              csr_build_seg<RANGE1,BCAPL,1>(tL, bcL, bbL, M_CL, offsL, csrL, b-512, hist, part);
}

// ============================ fused encoder: rel + f1(bf16) + g0'(f16 via MFMA) ============================
// f1b and gout are written in PLANE layout [4][n][16].

__global__ __launch_bounds__(256) void k_f1g(const float* __restrict__ features, const float* __restrict__ points,
                                             const float* __restrict__ centers, const int* __restrict__ labels,
                                             const float* __restrict__ W, const float* __restrict__ b,
                                             const ushortT* __restrict__ Wt2, const float* __restrict__ bias2,
                                             const float* __restrict__ Wr2,
                                             float* __restrict__ rel, ushortT* __restrict__ f1b,
                                             ushortT* __restrict__ gout, int n, int ntiles){
  __shared__ ushortT lds[4*16*LSTR];
  int tid = threadIdx.x;
  int lane = tid & 63, wslot = tid >> 6;
  int quad = lane >> 4, l15 = lane & 15;
  int gw = (blockIdx.x*256 + tid) >> 6;
  int nw = (gridDim.x*256) >> 6;
  size_t n16 = (size_t)n*16;
  float Wf0=W[0*64+lane], Wf1=W[1*64+lane], Wf2=W[2*64+lane], Wf3=W[3*64+lane];
  float wr0=W[4*64+lane], wr1=W[5*64+lane], wr2=W[6*64+lane];
  float bias=b[lane];
  short8 s0_0 = *(const short8*)(Wt2 + ( 0 + l15)*64 +  0 + quad*8);
  short8 s0_1 = *(const short8*)(Wt2 + ( 0 + l15)*64 + 32 + quad*8);
  short8 s1_0 = *(const short8*)(Wt2 + (16 + l15)*64 +  0 + quad*8);
  short8 s1_1 = *(const short8*)(Wt2 + (16 + l15)*64 + 32 + quad*8);
  short8 s2_0 = *(const short8*)(Wt2 + (32 + l15)*64 +  0 + quad*8);
  short8 s2_1 = *(const short8*)(Wt2 + (32 + l15)*64 + 32 + quad*8);
  short8 s3_0 = *(const short8*)(Wt2 + (48 + l15)*64 +  0 + quad*8);
  short8 s3_1 = *(const short8*)(Wt2 + (48 + l15)*64 + 32 + quad*8);
  float eb0 = bias2[l15], eb1 = bias2[16+l15], eb2 = bias2[32+l15], eb3 = bias2[48+l15];
  float e0c0=Wr2[0*64+l15], e0c1=Wr2[0*64+16+l15], e0c2=Wr2[0*64+32+l15], e0c3=Wr2[0*64+48+l15];
  float e1c0=Wr2[1*64+l15], e1c1=Wr2[1*64+16+l15], e1c2=Wr2[1*64+32+l15], e1c3=Wr2[1*64+48+l15];
  float e2c0=Wr2[2*64+l15], e2c1=Wr2[2*64+16+l15], e2c2=Wr2[2*64+32+l15], e2c3=Wr2[2*64+48+l15];

  for (int t=gw; t<ntiles; t+=nw){
    int i0 = t*16;
    for (int r=0;r<16;++r){
      int row = i0 + r;
      bool ok = row < n;
      int rr = ok ? row : n-1;
      int lb = labels[rr];
      float rx = points[rr*3+0]-centers[lb*3+0];
      float ry = points[rr*3+1]-centers[lb*3+1];
      float rz = points[rr*3+2]-centers[lb*3+2];
      float acc = bias + wr0*rx + wr1*ry + wr2*rz;
      acc += features[rr*4+0]*Wf0 + features[rr*4+1]*Wf1;
      acc += features[rr*4+2]*Wf2 + features[rr*4+3]*Wf3;
      acc = fmaxf(acc, 0.f);
      ushortT ab = f2bf(acc);
      if (ok){
        f1b[(size_t)quad*n16 + (size_t)row*16 + l15] = ab;
        if (lane==0){ rel[row*3+0]=rx; rel[row*3+1]=ry; rel[row*3+2]=rz; }
      }
      lds[wslot*(16*LSTR) + r*LSTR + lane] = ab;
    }
    __builtin_amdgcn_wave_barrier();
    const ushortT* lp = lds + wslot*(16*LSTR) + l15*LSTR + quad*8;
    short8 sa0 = *(const short8*)(lp);
    short8 sa1 = *(const short8*)(lp + 32);
    __builtin_amdgcn_wave_barrier();
    v4f ec0 = {0.f,0.f,0.f,0.f}, ec1 = ec0, ec2 = ec0, ec3 = ec0;
    ec0 = __builtin_amdgcn_mfma_f32_16x16x32_bf16(sa0, s0_0, ec0, 0,0,0);
    ec1 = __builtin_amdgcn_mfma_f32_16x16x32_bf16(sa0, s1_0, ec1, 0,0,0);
    ec2 = __builtin_amdgcn_mfma_f32_16x16x32_bf16(sa0, s2_0, ec2, 0,0,0);
    ec3 = __builtin_amdgcn_mfma_f32_16x16x32_bf16(sa0, s3_0, ec3, 0,0,0);
    ec0 = __builtin_amdgcn_mfma_f32_16x16x32_bf16(sa1, s0_1, ec0, 0,0,0);
    ec1 = __builtin_amdgcn_mfma_f32_16x16x32_bf16(sa1, s1_1, ec1, 0,0,0);
    ec2 = __builtin_amdgcn_mfma_f32_16x16x32_bf16(sa1, s2_1, ec2, 0,0,0);
    ec3 = __builtin_amdgcn_mfma_f32_16x16x32_bf16(sa1, s3_1, ec3, 0,0,0);
    #pragma unroll
    for (int r=0;r<4;++r){
      int row = i0 + quad*4 + r;
      if (row < n){
        float vx=points[row*3+0], vy=points[row*3+1], vz=points[row*3+2];
        float g0 = ec0[r] + eb0 + vx*e0c0 + vy*e1c0 + vz*e2c0;
        float g1 = ec1[r] + eb1 + vx*e0c1 + vy*e1c1 + vz*e2c1;
        float g2 = ec2[r] + eb2 + vx*e0c2 + vy*e1c2 + vz*e2c2;
        float g3 = ec3[r] + eb3 + vx*e0c3 + vy*e1c3 + vz*e2c3;
        size_t pb = (size_t)row*16 + l15;
        gout[pb] = f2h(g0); gout[pb+n16] = f2h(g1); gout[pb+2*n16] = f2h(g2); gout[pb+3*n16] = f2h(g3);
      }
    }
  }
}

// ============================ MFMA GEMM with optional fused secondary GEMM ============================
// A / r1 / r2 / out16 / eout(f16) are all PLANE layout [4][rows][16].
// A row count = na (differs from n only in the GATHER case).

template<bool RELU, int NRES, bool USEREL, bool GATHER, bool OUT16, bool F16O, int EMODE, bool ERELU>
__global__ __launch_bounds__(256) void k_gemm(
    const ushortT* __restrict__ A, const ushortT* __restrict__ Wt,
    const float* __restrict__ bias, const float* __restrict__ Wr,
    const float* __restrict__ rel, const int* __restrict__ gidx,
    const ushortT* __restrict__ r1, const ushortT* __restrict__ r2,
    ushortT* __restrict__ out16,
    const ushortT* __restrict__ Wt2, const float* __restrict__ bias2,
    const float* __restrict__ Wr2, const float* __restrict__ vec2,
    void* __restrict__ eout,
    int n, int na, int ntiles)
{
  constexpr int LDSZ = (EMODE>0) ? 4*16*LSTR : 4;
  __shared__ ushortT lds[LDSZ];
  int tid = threadIdx.x;
  int lane = tid & 63, wslot = tid >> 6;
  int quad = lane >> 4, l15 = lane & 15;
  int gw = (blockIdx.x*256 + tid) >> 6;
  int nw = (gridDim.x*256) >> 6;
  size_t n16  = (size_t)n*16;
  size_t na16 = (size_t)na*16;

  short8 bfr0_0 = *(const short8*)(Wt + ( 0 + l15)*64 +  0 + quad*8);
  short8 bfr0_1 = *(const short8*)(Wt + ( 0 + l15)*64 + 32 + quad*8);
  short8 bfr1_0 = *(const short8*)(Wt + (16 + l15)*64 +  0 + quad*8);
  short8 bfr1_1 = *(const short8*)(Wt + (16 + l15)*64 + 32 + quad*8);
  short8 bfr2_0 = *(const short8*)(Wt + (32 + l15)*64 +  0 + quad*8);
  short8 bfr2_1 = *(const short8*)(Wt + (32 + l15)*64 + 32 + quad*8);
  short8 bfr3_0 = *(const short8*)(Wt + (48 + l15)*64 +  0 + quad*8);
  short8 bfr3_1 = *(const short8*)(Wt + (48 + l15)*64 + 32 + quad*8);
  float bs0 = bias[ 0 + l15], bs1 = bias[16 + l15];
  float bs2 = bias[32 + l15], bs3 = bias[48 + l15];
  float w0c0=0,w0c1=0,w0c2=0,w0c3=0, w1c0=0,w1c1=0,w1c2=0,w1c3=0, w2c0=0,w2c1=0,w2c2=0,w2c3=0;
  if (USEREL){
    w0c0=Wr[0*64+l15]; w0c1=Wr[0*64+16+l15]; w0c2=Wr[0*64+32+l15]; w0c3=Wr[0*64+48+l15];
    w1c0=Wr[1*64+l15]; w1c1=Wr[1*64+16+l15]; w1c2=Wr[1*64+32+l15]; w1c3=Wr[1*64+48+l15];
    w2c0=Wr[2*64+l15]; w2c1=Wr[2*64+16+l15]; w2c2=Wr[2*64+32+l15]; w2c3=Wr[2*64+48+l15];
  }

  short8 s0_0{}, s0_1{}, s1_0{}, s1_1{}, s2_0{}, s2_1{}, s3_0{}, s3_1{};
  float eb0=0, eb1=0, eb2=0, eb3=0;
  float e0c0=0,e0c1=0,e0c2=0,e0c3=0, e1c0=0,e1c1=0,e1c2=0,e1c3=0, e2c0=0,e2c1=0,e2c2=0,e2c3=0;
  float ebias_c = 0.f;
  if (EMODE == 1){
    s0_0 = *(const short8*)(Wt2 + ( 0 + l15)*64 +  0 + quad*8);
    s0_1 = *(const short8*)(Wt2 + ( 0 + l15)*64 + 32 + quad*8);
    s1_0 = *(const short8*)(Wt2 + (16 + l15)*64 +  0 + quad*8);
    s1_1 = *(const short8*)(Wt2 + (16 + l15)*64 + 32 + quad*8);
    s2_0 = *(const short8*)(Wt2 + (32 + l15)*64 +  0 + quad*8);
    s2_1 = *(const short8*)(Wt2 + (32 + l15)*64 + 32 + quad*8);
    s3_0 = *(const short8*)(Wt2 + (48 + l15)*64 +  0 + quad*8);
    s3_1 = *(const short8*)(Wt2 + (48 + l15)*64 + 32 + quad*8);
    eb0 = bias2[l15]; eb1 = bias2[16+l15]; eb2 = bias2[32+l15]; eb3 = bias2[48+l15];
    e0c0=Wr2[0*64+l15]; e0c1=Wr2[0*64+16+l15]; e0c2=Wr2[0*64+32+l15]; e0c3=Wr2[0*64+48+l15];
    e1c0=Wr2[1*64+l15]; e1c1=Wr2[1*64+16+l15]; e1c2=Wr2[1*64+32+l15]; e1c3=Wr2[1*64+48+l15];
    e2c0=Wr2[2*64+l15]; e2c1=Wr2[2*64+16+l15]; e2c2=Wr2[2*64+32+l15]; e2c3=Wr2[2*64+48+l15];
  } else if (EMODE == 2){
    s0_0 = *(const short8*)(Wt2 + l15*64 +  0 + quad*8);
    s0_1 = *(const short8*)(Wt2 + l15*64 + 32 + quad*8);
    ebias_c = (l15 < 8) ? bias2[l15] : 0.f;
  }

  for (int t=gw; t<ntiles; t+=nw){
    int i0 = t*16;
    int rowA = i0 + l15; if (rowA >= n) rowA = n-1;
    if (GATHER) rowA = gidx[rowA];
    // plane layout: a0 covers cols 8q..8q+8 -> plane q>>1, offset (q&1)*8; a1 is 2 planes up
    const ushortT* ap = A + (size_t)(quad>>1)*na16 + (size_t)rowA*16 + (quad&1)*8;
    short8 a0 = *(const short8*)(ap);
    short8 a1 = *(const short8*)(ap + 2*na16);
    v4f ac0 = {0.f,0.f,0.f,0.f}, ac1 = ac0, ac2 = ac0, ac3 = ac0;
    ac0 = __builtin_amdgcn_mfma_f32_16x16x32_bf16(a0, bfr0_0, ac0, 0,0,0);
    ac1 = __builtin_amdgcn_mfma_f32_16x16x32_bf16(a0, bfr1_0, ac1, 0,0,0);
    ac2 = __builtin_amdgcn_mfma_f32_16x16x32_bf16(a0, bfr2_0, ac2, 0,0,0);
    ac3 = __builtin_amdgcn_mfma_f32_16x16x32_bf16(a0, bfr3_0, ac3, 0,0,0);
    ac0 = __builtin_amdgcn_mfma_f32_16x16x32_bf16(a1, bfr0_1, ac0, 0,0,0);
    ac1 = __builtin_amdgcn_mfma_f32_16x16x32_bf16(a1, bfr1_1, ac1, 0,0,0);
    ac2 = __builtin_amdgcn_mfma_f32_16x16x32_bf16(a1, bfr2_1, ac2, 0,0,0);
    ac3 = __builtin_amdgcn_mfma_f32_16x16x32_bf16(a1, bfr3_1, ac3, 0,0,0);

    #pragma unroll
    for (int r=0;r<4;++r){
      int row = i0 + quad*4 + r;
      bool rowok = (row < n);
      float rx=0.f, ry=0.f, rz=0.f;
      if (USEREL && rowok){ rx=rel[row*3+0]; ry=rel[row*3+1]; rz=rel[row*3+2]; }
      float v0 = ac0[r] + bs0, v1 = ac1[r] + bs1, v2 = ac2[r] + bs2, v3 = ac3[r] + bs3;
      if (USEREL){
        v0 += rx*w0c0 + ry*w1c0 + rz*w2c0;
        v1 += rx*w0c1 + ry*w1c1 + rz*w2c1;
        v2 += rx*w0c2 + ry*w1c2 + rz*w2c2;
        v3 += rx*w0c3 + ry*w1c3 + rz*w2c3;
      }
      if (RELU){ v0=fmaxf(v0,0.f); v1=fmaxf(v1,0.f); v2=fmaxf(v2,0.f); v3=fmaxf(v3,0.f); }
      size_t pb = (size_t)row*16 + l15;
      if (rowok){
        if (NRES>=1){
          v0 += bf2f(r1[pb]); v1 += bf2f(r1[pb+n16]); v2 += bf2f(r1[pb+2*n16]); v3 += bf2f(r1[pb+3*n16]);
        }
        if (NRES>=2){
          v0 += bf2f(r2[pb]); v1 += bf2f(r2[pb+n16]); v2 += bf2f(r2[pb+2*n16]); v3 += bf2f(r2[pb+3*n16]);
        }
        if (OUT16){
          if (F16O){
            out16[pb] = f2h(v0); out16[pb+n16] = f2h(v1); out16[pb+2*n16] = f2h(v2); out16[pb+3*n16] = f2h(v3);
          } else {
            out16[pb] = f2bf(v0); out16[pb+n16] = f2bf(v1); out16[pb+2*n16] = f2bf(v2); out16[pb+3*n16] = f2bf(v3);
          }
        }
      }
      if (EMODE > 0){
        int lb = wslot*(16*LSTR) + (quad*4+r)*LSTR + l15;
        lds[lb]      = f2bf(v0);
        lds[lb + 16] = f2bf(v1);
        lds[lb + 32] = f2bf(v2);
        lds[lb + 48] = f2bf(v3);
      }
    }

    if (EMODE > 0){
      __builtin_amdgcn_wave_barrier();
      const ushortT* lp = lds + wslot*(16*LSTR) + l15*LSTR + quad*8;
      short8 sa0 = *(const short8*)(lp);
      short8 sa1 = *(const short8*)(lp + 32);
      __builtin_amdgcn_wave_barrier();
      if (EMODE == 1){
        v4f ec0 = {0.f,0.f,0.f,0.f}, ec1 = ec0, ec2 = ec0, ec3 = ec0;
        ec0 = __builtin_amdgcn_mfma_f32_16x16x32_bf16(sa0, s0_0, ec0, 0,0,0);
        ec1 = __builtin_amdgcn_mfma_f32_16x16x32_bf16(sa0, s1_0, ec1, 0,0,0);
        ec2 = __builtin_amdgcn_mfma_f32_16x16x32_bf16(sa0, s2_0, ec2, 0,0,0);
        ec3 = __builtin_amdgcn_mfma_f32_16x16x32_bf16(sa0, s3_0, ec3, 0,0,0);
        ec0 = __builtin_amdgcn_mfma_f32_16x16x32_bf16(sa1, s0_1, ec0, 0,0,0);
        ec1 = __builtin_amdgcn_mfma_f32_16x16x32_bf16(sa1, s1_1, ec1, 0,0,0);
        ec2 = __builtin_amdgcn_mfma_f32_16x16x32_bf16(sa1, s2_1, ec2, 0,0,0);
        ec3 = __builtin_amdgcn_mfma_f32_16x16x32_bf16(sa1, s3_1, ec3, 0,0,0);
        ushortT* eo = (ushortT*)eout;
        #pragma unroll
        for (int r=0;r<4;++r){
          int row = i0 + quad*4 + r;
          if (row < n){
            float vx=vec2[row*3+0], vy=vec2[row*3+1], vz=vec2[row*3+2];
            float g0 = ec0[r] + eb0 + vx*e0c0 + vy*e1c0 + vz*e2c0;
            float g1 = ec1[r] + eb1 + vx*e0c1 + vy*e1c1 + vz*e2c1;
            float g2 = ec2[r] + eb2 + vx*e0c2 + vy*e1c2 + vz*e2c2;
            float g3 = ec3[r] + eb3 + vx*e0c3 + vy*e1c3 + vz*e2c3;
            if (ERELU){ g0=fmaxf(g0,0.f); g1=fmaxf(g1,0.f); g2=fmaxf(g2,0.f); g3=fmaxf(g3,0.f); }
            size_t pb = (size_t)row*16 + l15;
            eo[pb] = f2h(g0); eo[pb+n16] = f2h(g1); eo[pb+2*n16] = f2h(g2); eo[pb+3*n16] = f2h(g3);
          }
        }
      } else {
        v4f ec = {0.f,0.f,0.f,0.f};
        ec = __builtin_amdgcn_mfma_f32_16x16x32_bf16(sa0, s0_0, ec, 0,0,0);
        ec = __builtin_amdgcn_mfma_f32_16x16x32_bf16(sa1, s0_1, ec, 0,0,0);
        if (l15 < 8){
          float* eo = (float*)eout;
          #pragma unroll
          for (int r=0;r<4;++r){
            int row = i0 + quad*4 + r;
            if (row < n) eo[(size_t)row*8 + l15] = ec[r] + ebias_c;
          }
        }
      }
    }
  }
}

// ============================ edge aggregation: plane-sharded, XCD-pinned ============================
// One plane (16 cols, 3.2MB for N) per XCD pair: blockIdx%8 -> plane (round-robin block->XCD).
// Wave = 32 dsts x 2 lanes x 16B. csr/offs/pos streamed non-temporal; g cached (fits L2).
// Edges batched 8 per latency round (4 interleaved csr loads per lane pair), guarded (no pad dups).

__global__ __launch_bounds__(256) void k_edge_agg(const int* __restrict__ offs, const int* __restrict__ csr,
                                                  const float* __restrict__ pos, const ushortT* __restrict__ g,
                                                  const float* __restrict__ Wp, ushortT* __restrict__ agg,
                                                  int n, int n32){
  int tid = threadIdx.x;
  int lane = tid & 63, wslot = tid >> 6;
  int grp = lane >> 1, h = lane & 1;
  int gbase = lane & 62;
  int b7 = blockIdx.x & 7;
  int plane = b7 >> 1;
  int bp = ((blockIdx.x >> 3) << 1) + (b7 & 1);
  int ii = bp*4 + wslot;
  if (ii >= n32) return;
  const ushortT* gp = g + (size_t)plane*n*16;
  int c0 = plane*16 + h*8;
  float2 w0[4], w1[4], w2[4];
  #pragma unroll
  for (int q=0;q<4;++q){
    w0[q] = *(const float2*)(Wp + 0*64 + c0 + 2*q);
    w1[q] = *(const float2*)(Wp + 1*64 + c0 + 2*q);
    w2[q] = *(const float2*)(Wp + 2*64 + c0 + 2*q);
  }
  const h2 NEGBIG = {(_Float16)-60000.f, (_Float16)-60000.f};
  int ig = ii*32 + grp;
  bool ok = ig < n;
  int igc = ok ? ig : (n-1);
  int bofs = 0, cnt = 0;
  if (ok){
    bofs = __builtin_nontemporal_load(offs + ig);
    cnt  = __builtin_nontemporal_load(offs + ig + 1) - bofs;
  }
  int mx = cnt;
  mx = max(mx, __shfl_xor(mx,  2, 64));
  mx = max(mx, __shfl_xor(mx,  4, 64));
  mx = max(mx, __shfl_xor(mx,  8, 64));
  mx = max(mx, __shfl_xor(mx, 16, 64));
  mx = max(mx, __shfl_xor(mx, 32, 64));
  h2 m0=NEGBIG, m1=NEGBIG, m2=NEGBIG, m3=NEGBIG;
  for (int J=0; J<mx; J+=8){
    // lane h holds edge entries J+h, J+h+2, J+h+4, J+h+6
    int sv0=0, sv1=0, sv2=0, sv3=0;
    if (J+h   < cnt) sv0 = __builtin_nontemporal_load(csr + bofs + J + h);
    if (J+h+2 < cnt) sv1 = __builtin_nontemporal_load(csr + bofs + J + h + 2);
    if (J+h+4 < cnt) sv2 = __builtin_nontemporal_load(csr + bofs + J + h + 4);
    if (J+h+6 < cnt) sv3 = __builtin_nontemporal_load(csr + bofs + J + h + 6);
    #pragma unroll
    for (int jj=0; jj<8; ++jj){
      int sv = (jj<2) ? sv0 : (jj<4) ? sv1 : (jj<6) ? sv2 : sv3;
      if (J + jj < cnt){
        int s = __shfl(sv, gbase + (jj & 1), 64);
        u4v u = *(const u4v*)(gp + (size_t)s*16 + h*8);
        m0 = pkmax(m0, u2h(u.x));
        m1 = pkmax(m1, u2h(u.y));
        m2 = pkmax(m2, u2h(u.z));
        m3 = pkmax(m3, u2h(u.w));
      }
    }
  }
  float px = __builtin_nontemporal_load(pos + igc*3 + 0);
  float py = __builtin_nontemporal_load(pos + igc*3 + 1);
  float pz = __builtin_nontemporal_load(pos + igc*3 + 2);
  u4v outv;
  {
    float sA = w0[0].x*px + w1[0].x*py + w2[0].x*pz;
    float sB = w0[0].y*px + w1[0].y*py + w2[0].y*pz;
    outv.x = (unsigned)f2bf(fmaxf((float)m0.x - sA, 0.f)) |
             ((unsigned)f2bf(fmaxf((float)m0.y - sB, 0.f)) << 16);
  }
  {
    float sA = w0[1].x*px + w1[1].x*py + w2[1].x*pz;
    float sB = w0[1].y*px + w1[1].y*py + w2[1].y*pz;
    outv.y = (unsigned)f2bf(fmaxf((float)m1.x - sA, 0.f)) |
             ((unsigned)f2bf(fmaxf((float)m1.y - sB, 0.f)) << 16);
  }
  {
    float sA = w0[2].x*px + w1[2].x*py + w2[2].x*pz;
    float sB = w0[2].y*px + w1[2].y*py + w2[2].y*pz;
    outv.z = (unsigned)f2bf(fmaxf((float)m2.x - sA, 0.f)) |
             ((unsigned)f2bf(fmaxf((float)m2.y - sB, 0.f)) << 16);
  }
  {
    float sA = w0[3].x*px + w1[3].x*py + w2[3].x*pz;
    float sB = w0[3].y*px + w1[3].y*py + w2[3].y*pz;
    outv.w = (unsigned)f2bf(fmaxf((float)m3.x - sA, 0.f)) |
             ((unsigned)f2bf(fmaxf((float)m3.y - sB, 0.f)) << 16);
  }
  if (ok) __builtin_nontemporal_store(outv, (u4v*)(agg + ((size_t)plane*n + ig)*16 + h*8));
}

// ============================ segment sum via label CSR (f16 in, bf16 out) ============================
// h is plane layout [4][nh][16]; c is plane layout [4][m][16].

__global__ __launch_bounds__(256) void k_seg_gather(const int* __restrict__ offs, const int* __restrict__ csr,
                                                    const ushortT* __restrict__ h, ushortT* __restrict__ c,
                                                    int m, int nh){
  int lane = threadIdx.x & 63;
  int l15 = lane & 15, q = lane >> 4;
  int wv = (blockIdx.x*256 + threadIdx.x) >> 6;
  if (wv >= m) return;
  int b = offs[wv], e = offs[wv+1];
  float acc = 0.f;
  const ushortT* hp = h + (size_t)q*nh*16 + l15;
  for (int k=b; k<e; ++k){
    int i = csr[k];
    acc += h2f(hp[(size_t)i*16]);
  }
  c[((size_t)q*m + wv)*16 + l15] = f2bf(acc);
}

// ============================ host launcher ============================

extern "C" void kernel_launch(void* const* d_in, const int* in_sizes, int n_in,
                              void* d_out, int out_size, void* d_ws, size_t ws_size,
                              hipStream_t stream){
  const float* features = (const float*)d_in[0];
  const float* points   = (const float*)d_in[1];
  const float* centers  = (const float*)d_in[2];
  const int*   l0e      = (const int*)d_in[3];
  const int*   l1e      = (const int*)d_in[4];
  const int*   labels   = (const int*)d_in[5];
  const float* W_fe = (const float*)d_in[6];
  const float* b_fe = (const float*)d_in[7];
  const float* mWe  = (const float*)d_in[8];
  const float* mbe  = (const float*)d_in[9];
  const float* mWu  = (const float*)d_in[10];
  const float* mbu  = (const float*)d_in[11];
  const float* W_m1 = (const float*)d_in[12];
  const float* b_m1 = (const float*)d_in[13];
  const float* W_m2 = (const float*)d_in[14];
  const float* b_m2 = (const float*)d_in[15];
  const float* gWe  = (const float*)d_in[16];
  const float* gbe  = (const float*)d_in[17];
  const float* gWu  = (const float*)d_in[18];
  const float* gbu  = (const float*)d_in[19];
  const float* W_l  = (const float*)d_in[20];
  const float* b_l  = (const float*)d_in[21];
  const float* W_c  = (const float*)d_in[22];
  const float* b_c  = (const float*)d_in[23];
  float* out = (float*)d_out;

  char* w = (char*)d_ws;
  size_t off = 0;
  auto alloc = [&](size_t bytes)->void*{
    void* p = (void*)(w + off);
    off = (off + bytes + 255) & ~(size_t)255;
    return p;
  };
  float* rel  = (float*)alloc((size_t)N_PTS*3*4);
  ushortT* UF1 = (ushortT*)alloc((size_t)N_PTS*64*2);
  ushortT* UF2 = (ushortT*)alloc((size_t)N_PTS*64*2);
  ushortT* UF21= (ushortT*)alloc((size_t)N_PTS*64*2);
  ushortT* UF5 = (ushortT*)alloc((size_t)N_PTS*64*2);
  ushortT* UF6 = (ushortT*)alloc((size_t)N_PTS*64*2);
  ushortT* gbuf= (ushortT*)alloc((size_t)N_PTS*64*2);
  ushortT* abuf= (ushortT*)alloc((size_t)N_PTS*64*2);
  ushortT* cb_b= (ushortT*)alloc((size_t)M_CL*64*2);
  ushortT* UF3 = (ushortT*)alloc((size_t)M_CL*64*2);
  ushortT* UF4 = (ushortT*)alloc((size_t)M_CL*64*2);
  ushortT* cg_b= (ushortT*)alloc((size_t)M_CL*64*2);
  ushortT* cagg_b = (ushortT*)alloc((size_t)M_CL*64*2);
  ushortT* f41_b  = (ushortT*)alloc((size_t)M_CL*64*2);
  ushortT* wt  = (ushortT*)alloc((size_t)15*4096*2);
  ushortT* wtc = (ushortT*)alloc((size_t)1024*2);
  int* offs0 = (int*)alloc((size_t)(N_PTS+1)*4);
  int* csr0  = (int*)alloc((size_t)E0_N*4);
  int* offs1 = (int*)alloc((size_t)(M_CL+1)*4);
  int* csr1  = (int*)alloc((size_t)E1_N*4);
  int* offsL = (int*)alloc((size_t)(M_CL+1)*4);
  int* csrL  = (int*)alloc((size_t)N_PTS*4);
  unsigned* tmp0 = (unsigned*)alloc((size_t)NB*BCAP0*4);
  unsigned* tmp1 = (unsigned*)alloc((size_t)NB*BCAP1*4);
  unsigned* tmpL = (unsigned*)alloc((size_t)NB*BCAPL*4);
  int* bcur0 = (int*)alloc(NB*4);
  int* bcur1 = (int*)alloc(NB*4);
  int* bcurL = (int*)alloc(NB*4);
  int* bb0   = (int*)alloc(NB*4);
  int* bb1   = (int*)alloc(NB*4);
  int* bbL   = (int*)alloc(NB*4);
  (void)ws_size; (void)in_sizes; (void)n_in; (void)out_size;

  const int NT_N = (N_PTS+15)/16;
  const int NT_M = (M_CL +15)/16;
  const int GBG_N = 1563;
  const int GBG_M = 196;
  const int GB_AGG_N = 3128;   // 4 planes x 782 blocks (blockIdx%8 -> XCD pin)
  const int N32_N    = 3125;   // ceil(N/32)
  const int GB_AGG_M = 392;    // 4 planes x 98 blocks
  const int N32_M    = 391;    // ceil(M/32)

  // ---- setup: weights + counters (1), bin all three lists (1), scan (1), build (1) ----
  WSrc ws{};
  ws.p[0]=mWu+0*4096; ws.p[1]=mWu+1*4096; ws.p[2]=mWu+2*4096; ws.p[3]=mWu+3*4096;
  ws.p[4]=W_m2; ws.p[5]=gWu+0*4096; ws.p[6]=gWu+1*4096;
  ws.p[7]=mWe+0*4288+192; ws.p[8]=mWe+1*4288+192; ws.p[9]=mWe+2*4288+192; ws.p[10]=mWe+3*4288+192;
  ws.p[11]=W_m1; ws.p[12]=W_l; ws.p[13]=gWe+0*4288+192; ws.p[14]=gWe+1*4288+192;
  ws.p[15]=W_c;
  k_init_wprep<<<17, 256, 0, stream>>>(ws, wt, wtc, bcur0, bcur1, bcurL);
  k_bin_all<<<501, 256, 0, stream>>>(l0e, l1e, labels, bcur0, bcur1, bcurL, tmp0, tmp1, tmpL);
  k_scan_all<<<3, 64, 0, stream>>>(bcur0, bb0, offs0+N_PTS, bcur1, bb1, offs1+M_CL, bcurL, bbL, offsL+M_CL);
  k_build_all<<<768, 256, 0, stream>>>(tmp0, bcur0, bb0, offs0, csr0,
                                       tmp1, bcur1, bb1, offs1, csr1,
                                       tmpL, bcurL, bbL, offsL, csrL);

  // ---- FUSED encoder: rel + f1 (bf16 planes) + g0' (f16 planes) ----
  k_f1g<<<GBG_N, 256, 0, stream>>>(features, points, centers, labels, W_fe, b_fe,
      wt+7*4096, mbe+0, mWe+0*4288, rel, UF1, gbuf, N_PTS, NT_N);

  // ---- layer0: agg -> FUSED [f2 -> UF2] + [g1' -> gbuf] ----
  k_edge_agg<<<GB_AGG_N,256,0,stream>>>(offs0, csr0, points, gbuf, mWe+0*4288, abuf, N_PTS, N32_N);
  k_gemm<true,1,false,false,true,false,1,false><<<GBG_N,256,0,stream>>>(abuf, wt+0*4096, mbu+0,
      nullptr, nullptr, nullptr, UF1, nullptr, UF2,
      wt+8*4096, mbe+64, mWe+1*4288, points, gbuf, N_PTS, N_PTS, NT_N);
  // ---- layer1: agg -> FUSED [f2_1 -> UF21] + [h -> gbuf] ----
  k_edge_agg<<<GB_AGG_N,256,0,stream>>>(offs0, csr0, points, gbuf, mWe+1*4288, abuf, N_PTS, N32_N);
  k_gemm<true,1,false,false,true,false,1,true><<<GBG_N,256,0,stream>>>(abuf, wt+1*4096, mbu+64,
      nullptr, nullptr, nullptr, UF2, nullptr, UF21,
      wt+11*4096, b_m1, W_m1+4096, rel, gbuf, N_PTS, N_PTS, NT_N);
  // ---- c = segsum(h); FUSED [f3 -> UF3] + [cg0' -> cg_b] ----
  k_seg_gather<<<(M_CL*64+255)/256, 256, 0, stream>>>(offsL, csrL, gbuf, cb_b, M_CL, N_PTS);
  k_gemm<true,0,false,false,true,false,1,false><<<GBG_M,256,0,stream>>>(cb_b, wt+4*4096, b_m2,
      nullptr, nullptr, nullptr, nullptr, nullptr, UF3,
      wt+13*4096, gbe+0, gWe+0*4288, centers, cg_b, M_CL, M_CL, NT_M);
  // ---- cluster layer0: agg -> FUSED [f4 -> UF4] + [cg1' -> cg_b] ----
  k_edge_agg<<<GB_AGG_M,256,0,stream>>>(offs1, csr1, centers, cg_b, gWe+0*4288, cagg_b, M_CL, N32_M);
  k_gemm<true,1,false,false,true,false,1,false><<<GBG_M,256,0,stream>>>(cagg_b, wt+5*4096, gbu+0,
      nullptr, nullptr, nullptr, UF3, nullptr, UF4,
      wt+14*4096, gbe+64, gWe+1*4288, centers, cg_b, M_CL, M_CL, NT_M);
  // ---- cluster layer1: agg -> f4_1 -> f41_b ----
  k_edge_agg<<<GB_AGG_M,256,0,stream>>>(offs1, csr1, centers, cg_b, gWe+1*4288, cagg_b, M_CL, N32_M);
  k_gemm<true,1,false,false,true,false,0,false><<<GBG_M,256,0,stream>>>(cagg_b, wt+6*4096, gbu+64,
      nullptr, nullptr, nullptr, UF4, nullptr, f41_b,
      nullptr, nullptr, nullptr, nullptr, nullptr, M_CL, M_CL, NT_M);
  // ---- FUSED [f5 -> UF5] + [g2' -> gbuf] ----
  k_gemm<true,0,true,true,true,false,1,false><<<GBG_N,256,0,stream>>>(f41_b, wt+12*4096, b_l,
      W_l+4096, rel, labels, nullptr, nullptr, UF5,
      wt+9*4096, mbe+128, mWe+2*4288, points, gbuf, N_PTS, M_CL, NT_N);
  // ---- layer2: agg -> FUSED [f6 = relu+f5+f2_1 -> UF6] + [g3' -> gbuf] ----
  k_edge_agg<<<GB_AGG_N,256,0,stream>>>(offs0, csr0, points, gbuf, mWe+2*4288, abuf, N_PTS, N32_N);
  k_gemm<true,2,false,false,true,false,1,false><<<GBG_N,256,0,stream>>>(abuf, wt+2*4096, mbu+128,
      nullptr, nullptr, nullptr, UF5, UF21, UF6,
      wt+10*4096, mbe+192, mWe+3*4288, points, gbuf, N_PTS, N_PTS, NT_N);
  // ---- layer3: agg -> FUSED [final = relu+f6+f2] + [out = final@W_c + b_c] ----
  k_edge_agg<<<GB_AGG_N,256,0,stream>>>(offs0, csr0, points, gbuf, mWe+3*4288, abuf, N_PTS, N32_N);
  k_gemm<true,2,false,false,false,false,2,false><<<GBG_N,256,0,stream>>>(abuf, wt+3*4096, mbu+192,
      nullptr, nullptr, nullptr, UF6, UF2, nullptr,
      wtc, b_c, nullptr, nullptr, out, N_PTS, N_PTS, NT_N);
}

// Round 2
// 649.672 us; speedup vs baseline: 1.0039x; 1.0039x over previous
//
#include <hip/hip_runtime.h>

// R2: plane-sharded XCD-pinned edge agg (g plane = 3.2MB fits 4MB L2) with
// R0-style clustered gathers: ONE guard per 8-edge round, clamped csr indices,
// 8 unconditional 16B gathers pre-issued before the max chain (MLP=8).
// Row-major [rows][64] restored for residual/out16/f1b paths; plane layout
// [4][rows][16] kept only for agg-facing buffers (gbuf/abuf/cg_b/cagg_b).

#define N_PTS   100000
#define M_CL    12500
#define E0_N    1600000
#define E1_N    400000

#define NB      256
#define BIN_CAP 32
#define RANGE0  391
#define RANGE1  49           // also used for labels (ceil(12500/256))
#define BCAP0   8192
#define BCAP1   2048
#define BCAPL   1024

#define LSTR    72           // LDS row stride (shorts): 144 B, 16-B aligned

typedef unsigned short ushortT;
typedef short  short8 __attribute__((ext_vector_type(8)));
typedef float  v4f    __attribute__((ext_vector_type(4)));
typedef _Float16 h2   __attribute__((ext_vector_type(2)));
typedef unsigned u4v  __attribute__((ext_vector_type(4)));

__device__ inline ushortT f2bf(float x){
  union{float f; unsigned u;} v; v.f = x;
  unsigned r = v.u + 0x7fffu + ((v.u >> 16) & 1u);   // RNE
  return (ushortT)(r >> 16);
}
__device__ inline float bf2f(ushortT h){
  union{unsigned u; float f;} v; v.u = ((unsigned)h) << 16;
  return v.f;
}
__device__ inline ushortT f2h(float x){
  union{_Float16 h; ushortT u;} v; v.h = (_Float16)x;
  return v.u;
}
__device__ inline float h2f(ushortT u){
  union{ushortT u; _Float16 h;} v; v.u = u;
  return (float)v.h;
}
__device__ inline h2 pkmax(h2 a, h2 b){ return __builtin_elementwise_max(a, b); }
__device__ inline h2 u2h(unsigned u){ union{unsigned u; h2 h;} v{u}; return v.h; }

// ============================ weight prep + counter init (1 dispatch) ============================

struct WSrc { const float* p[16]; };

__global__ __launch_bounds__(256) void k_init_wprep(WSrc s, ushortT* __restrict__ wt, ushortT* __restrict__ wtc,
                                                    int* c0, int* c1, int* cL){
  int blk = blockIdx.x;
  if (blk == 0){
    int t = threadIdx.x;
    c0[t] = t*BCAP0; c1[t] = t*BCAP1; cL[t] = t*BCAPL;
    return;
  }
  int slot = blk - 1;
  if (slot < 15){
    const float* src = s.p[slot];
    ushortT* dst = wt + slot*4096;
    for (int e=threadIdx.x; e<4096; e+=256){
      int nn = e>>6, kk = e&63;
      dst[e] = f2bf(src[kk*64+nn]);
    }
  } else {
    const float* src = s.p[15];
    for (int e=threadIdx.x; e<1024; e+=256){
      int nn = e>>6, kk = e&63;
      wtc[e] = (nn<8) ? f2bf(src[kk*8+nn]) : (ushortT)0;
    }
  }
}

// ============================ bucketed CSR build (l0 + l1 + labels, merged) ============================

template<int RANGE, bool LAB>
__device__ void bin_seg(const int* __restrict__ edges, int E,
                        int* __restrict__ bcur, unsigned* __restrict__ tmp,
                        int bid, int nblk,
                        unsigned* stage, int* scnt, int* sbase){
  int tid = threadIdx.x;
  int nchunks = (E + 2047) / 2048;
  for (int c = bid; c < nchunks; c += nblk){
    int base = c*2048;
    scnt[tid] = 0;
    __syncthreads();
    #pragma unroll
    for (int r=0;r<8;++r){
      int e = base + r*256 + tid;
      if (e < E){
        int s, d;
        if (LAB){ s = e; d = edges[e]; }
        else    { s = edges[2*e]; d = edges[2*e+1]; }
        int bk = d / RANGE;
        unsigned packed = ((unsigned)s << 11) | (unsigned)(d - bk*RANGE);
        int pos = atomicAdd(&scnt[bk], 1);
        if (pos < BIN_CAP) stage[bk*BIN_CAP+pos] = packed;
        else tmp[atomicAdd(&bcur[bk],1)] = packed;
      }
    }
    __syncthreads();
    {
      int nfl = scnt[tid]; if (nfl > BIN_CAP) nfl = BIN_CAP;
      sbase[tid] = atomicAdd(&bcur[tid], nfl);
    }
    __syncthreads();
    int wv = tid >> 6, ln = tid & 63;
    for (int bb=0; bb<32; ++bb){
      int bk = wv*64 + bb*2 + (ln>>5);
      int ent = ln & 31;
      int nf = scnt[bk]; if (nf > BIN_CAP) nf = BIN_CAP;
      if (ent < nf) tmp[sbase[bk]+ent] = stage[bk*BIN_CAP+ent];
    }
    __syncthreads();
  }
}

__global__ __launch_bounds__(256) void k_bin_all(const int* __restrict__ l0e, const int* __restrict__ l1e,
                                                 const int* __restrict__ labels,
                                                 int* bc0, int* bc1, int* bcL,
                                                 unsigned* t0, unsigned* t1, unsigned* tL){
  __shared__ unsigned stage[NB*BIN_CAP];
  __shared__ int scnt[NB];
  __shared__ int sbase[NB];
  int b = blockIdx.x;
  if (b < 256)      bin_seg<RANGE0,false>(l0e, E0_N, bc0, t0, b, 256, stage, scnt, sbase);
  else if (b < 452) bin_seg<RANGE1,false>(l1e, E1_N, bc1, t1, b-256, 196, stage, scnt, sbase);
  else              bin_seg<RANGE1,true >(labels, N_PTS, bcL, tL, b-452, 49, stage, scnt, sbase);
}

// exclusive scan of 256 bucket counts; blocks: 0->l0, 1->l1, 2->labels
__global__ void k_scan_all(const int* c0, int* bb0, int* e0,
                           const int* c1, int* bb1, int* e1,
                           const int* cL, int* bbL, int* eL){
  const int* cur; int* bb; int* offe; int BC;
  if (blockIdx.x == 0){ cur=c0; bb=bb0; offe=e0; BC=BCAP0; }
  else if (blockIdx.x == 1){ cur=c1; bb=bb1; offe=e1; BC=BCAP1; }
  else { cur=cL; bb=bbL; offe=eL; BC=BCAPL; }
  int lane = threadIdx.x & 63;
  int base = lane*4;
  int v0 = cur[base+0] - (base+0)*BC;
  int v1 = cur[base+1] - (base+1)*BC;
  int v2 = cur[base+2] - (base+2)*BC;
  int v3 = cur[base+3] - (base+3)*BC;
  int psum = v0+v1+v2+v3, sc = psum;
  #pragma unroll
  for (int st=1; st<64; st<<=1){
    int x = __shfl_up(sc, st, 64);
    if (lane >= st) sc += x;
  }
  int ex = sc - psum;
  bb[base+0] = ex;
  bb[base+1] = ex + v0;
  bb[base+2] = ex + v0 + v1;
  bb[base+3] = ex + v0 + v1 + v2;
  if (lane == 63) *offe = sc;
}

template<int RANGE, int BCAP, int K>
__device__ void csr_build_seg(const unsigned* __restrict__ tmp, const int* __restrict__ bcur,
                              const int* __restrict__ bb, int n,
                              int* __restrict__ offs, int* __restrict__ csr,
                              int b, int* hist, int* part){
  int tid = threadIdx.x;
  int dlo = b*RANGE;
  int range = n - dlo; if (range > RANGE) range = RANGE; if (range < 0) range = 0;
  int cnt = bcur[b] - b*BCAP;
  for (int t=tid; t<RANGE; t+=256) hist[t] = 0;
  __syncthreads();
  const unsigned* sl = tmp + (size_t)b*BCAP;
  for (int j=tid; j<cnt; j+=256) atomicAdd(&hist[sl[j] & 2047u], 1);
  __syncthreads();
  int s = 0; int loc[K];
  #pragma unroll
  for (int kk=0; kk<K; ++kk){
    int idx = tid*K + kk;
    int v = (idx < RANGE) ? hist[idx] : 0;
    loc[kk] = s; s += v;
  }
  part[tid] = s; __syncthreads();
  int own = s;
  for (int st=1; st<256; st<<=1){
    int x = (tid >= st) ? part[tid-st] : 0;
    __syncthreads();
    part[tid] += x;
    __syncthreads();
  }
  int ebase = part[tid] - own;
  int gb = bb[b];
  __syncthreads();
  #pragma unroll
  for (int kk=0; kk<K; ++kk){
    int idx = tid*K + kk;
    if (idx < RANGE){
      int ex = ebase + loc[kk];
      if (idx < range) offs[dlo+idx] = gb + ex;
      hist[idx] = ex;
    }
  }
  __syncthreads();
  for (int j=tid; j<cnt; j+=256){
    unsigned p = sl[j];
    int pos = atomicAdd(&hist[p & 2047u], 1);
    csr[gb + pos] = (int)(p >> 11);
  }
}

__global__ __launch_bounds__(256) void k_build_all(
    const unsigned* t0, const int* bc0, const int* bb0, int* offs0, int* csr0,
    const unsigned* t1, const int* bc1, const int* bb1, int* offs1, int* csr1,
    const unsigned* tL, const int* bcL, const int* bbL, int* offsL, int* csrL){
  __shared__ int hist[RANGE0];
  __shared__ int part[256];
  int b = blockIdx.x;
  if (b < 256)      csr_build_seg<RANGE0,BCAP0,2>(t0, bc0, bb0, N_PTS, offs0, csr0, b, hist, part);
  else if (b < 512) csr_build_seg<RANGE1,BCAP1,1>(t1, bc1, bb1, M_CL, offs1, csr1, b-256, hist, part);
  else              csr_build_seg<RANGE1,BCAPL,1>(tL, bcL, bbL, M_CL, offsL, csrL, b-512, hist, part);
}

// ============================ fused encoder: rel + f1(bf16, row-major) + g0'(f16, plane) ============================

__global__ __launch_bounds__(256) void k_f1g(const float* __restrict__ features, const float* __restrict__ points,
                                             const float* __restrict__ centers, const int* __restrict__ labels,
                                             const float* __restrict__ W, const float* __restrict__ b,
                                             const ushortT* __restrict__ Wt2, const float* __restrict__ bias2,
                                             const float* __restrict__ Wr2,
                                             float* __restrict__ rel, ushortT* __restrict__ f1b,
                                             ushortT* __restrict__ gout, int n, int ntiles){
  __shared__ ushortT lds[4*16*LSTR];
  int tid = threadIdx.x;
  int lane = tid & 63, wslot = tid >> 6;
  int quad = lane >> 4, l15 = lane & 15;
  int gw = (blockIdx.x*256 + tid) >> 6;
  int nw = (gridDim.x*256) >> 6;
  size_t n16 = (size_t)n*16;
  float Wf0=W[0*64+lane], Wf1=W[1*64+lane], Wf2=W[2*64+lane], Wf3=W[3*64+lane];
  float wr0=W[4*64+lane], wr1=W[5*64+lane], wr2=W[6*64+lane];
  float bias=b[lane];
  short8 s0_0 = *(const short8*)(Wt2 + ( 0 + l15)*64 +  0 + quad*8);
  short8 s0_1 = *(const short8*)(Wt2 + ( 0 + l15)*64 + 32 + quad*8);
  short8 s1_0 = *(const short8*)(Wt2 + (16 + l15)*64 +  0 + quad*8);
  short8 s1_1 = *(const short8*)(Wt2 + (16 + l15)*64 + 32 + quad*8);
  short8 s2_0 = *(const short8*)(Wt2 + (32 + l15)*64 +  0 + quad*8);
  short8 s2_1 = *(const short8*)(Wt2 + (32 + l15)*64 + 32 + quad*8);
  short8 s3_0 = *(const short8*)(Wt2 + (48 + l15)*64 +  0 + quad*8);
  short8 s3_1 = *(const short8*)(Wt2 + (48 + l15)*64 + 32 + quad*8);
  float eb0 = bias2[l15], eb1 = bias2[16+l15], eb2 = bias2[32+l15], eb3 = bias2[48+l15];
  float e0c0=Wr2[0*64+l15], e0c1=Wr2[0*64+16+l15], e0c2=Wr2[0*64+32+l15], e0c3=Wr2[0*64+48+l15];
  float e1c0=Wr2[1*64+l15], e1c1=Wr2[1*64+16+l15], e1c2=Wr2[1*64+32+l15], e1c3=Wr2[1*64+48+l15];
  float e2c0=Wr2[2*64+l15], e2c1=Wr2[2*64+16+l15], e2c2=Wr2[2*64+32+l15], e2c3=Wr2[2*64+48+l15];

  for (int t=gw; t<ntiles; t+=nw){
    int i0 = t*16;
    for (int r=0;r<16;++r){
      int row = i0 + r;
      bool ok = row < n;
      int rr = ok ? row : n-1;
      int lb = labels[rr];
      float rx = points[rr*3+0]-centers[lb*3+0];
      float ry = points[rr*3+1]-centers[lb*3+1];
      float rz = points[rr*3+2]-centers[lb*3+2];
      float acc = bias + wr0*rx + wr1*ry + wr2*rz;
      acc += features[rr*4+0]*Wf0 + features[rr*4+1]*Wf1;
      acc += features[rr*4+2]*Wf2 + features[rr*4+3]*Wf3;
      acc = fmaxf(acc, 0.f);
      ushortT ab = f2bf(acc);
      if (ok){
        f1b[(size_t)row*64 + lane] = ab;
        if (lane==0){ rel[row*3+0]=rx; rel[row*3+1]=ry; rel[row*3+2]=rz; }
      }
      lds[wslot*(16*LSTR) + r*LSTR + lane] = ab;
    }
    __builtin_amdgcn_wave_barrier();
    const ushortT* lp = lds + wslot*(16*LSTR) + l15*LSTR + quad*8;
    short8 sa0 = *(const short8*)(lp);
    short8 sa1 = *(const short8*)(lp + 32);
    __builtin_amdgcn_wave_barrier();
    v4f ec0 = {0.f,0.f,0.f,0.f}, ec1 = ec0, ec2 = ec0, ec3 = ec0;
    ec0 = __builtin_amdgcn_mfma_f32_16x16x32_bf16(sa0, s0_0, ec0, 0,0,0);
    ec1 = __builtin_amdgcn_mfma_f32_16x16x32_bf16(sa0, s1_0, ec1, 0,0,0);
    ec2 = __builtin_amdgcn_mfma_f32_16x16x32_bf16(sa0, s2_0, ec2, 0,0,0);
    ec3 = __builtin_amdgcn_mfma_f32_16x16x32_bf16(sa0, s3_0, ec3, 0,0,0);
    ec0 = __builtin_amdgcn_mfma_f32_16x16x32_bf16(sa1, s0_1, ec0, 0,0,0);
    ec1 = __builtin_amdgcn_mfma_f32_16x16x32_bf16(sa1, s1_1, ec1, 0,0,0);
    ec2 = __builtin_amdgcn_mfma_f32_16x16x32_bf16(sa1, s2_1, ec2, 0,0,0);
    ec3 = __builtin_amdgcn_mfma_f32_16x16x32_bf16(sa1, s3_1, ec3, 0,0,0);
    #pragma unroll
    for (int r=0;r<4;++r){
      int row = i0 + quad*4 + r;
      if (row < n){
        float vx=points[row*3+0], vy=points[row*3+1], vz=points[row*3+2];
        float g0 = ec0[r] + eb0 + vx*e0c0 + vy*e1c0 + vz*e2c0;
        float g1 = ec1[r] + eb1 + vx*e0c1 + vy*e1c1 + vz*e2c1;
        float g2 = ec2[r] + eb2 + vx*e0c2 + vy*e1c2 + vz*e2c2;
        float g3 = ec3[r] + eb3 + vx*e0c3 + vy*e1c3 + vz*e2c3;
        size_t pb = (size_t)row*16 + l15;
        gout[pb] = f2h(g0); gout[pb+n16] = f2h(g1); gout[pb+2*n16] = f2h(g2); gout[pb+3*n16] = f2h(g3);
      }
    }
  }
}

// ============================ MFMA GEMM with optional fused secondary GEMM ============================
// APLANE: A input in plane layout [4][na][16] (agg outputs). Otherwise row-major [na][64].
// r1/r2/out16: row-major [n][64]. EMODE1 eout (f16): plane layout [4][n][16].

template<bool RELU, int NRES, bool USEREL, bool GATHER, bool APLANE, bool OUT16, bool F16O, int EMODE, bool ERELU>
__global__ __launch_bounds__(256) void k_gemm(
    const ushortT* __restrict__ A, const ushortT* __restrict__ Wt,
    const float* __restrict__ bias, const float* __restrict__ Wr,
    const float* __restrict__ rel, const int* __restrict__ gidx,
    const ushortT* __restrict__ r1, const ushortT* __restrict__ r2,
    ushortT* __restrict__ out16,
    const ushortT* __restrict__ Wt2, const float* __restrict__ bias2,
    const float* __restrict__ Wr2, const float* __restrict__ vec2,
    void* __restrict__ eout,
    int n, int na, int ntiles)
{
  constexpr int LDSZ = (EMODE>0) ? 4*16*LSTR : 4;
  __shared__ ushortT lds[LDSZ];
  int tid = threadIdx.x;
  int lane = tid & 63, wslot = tid >> 6;
  int quad = lane >> 4, l15 = lane & 15;
  int gw = (blockIdx.x*256 + tid) >> 6;
  int nw = (gridDim.x*256) >> 6;
  size_t n16  = (size_t)n*16;
  size_t na16 = (size_t)na*16;

  short8 bfr0_0 = *(const short8*)(Wt + ( 0 + l15)*64 +  0 + quad*8);
  short8 bfr0_1 = *(const short8*)(Wt + ( 0 + l15)*64 + 32 + quad*8);
  short8 bfr1_0 = *(const short8*)(Wt + (16 + l15)*64 +  0 + quad*8);
  short8 bfr1_1 = *(const short8*)(Wt + (16 + l15)*64 + 32 + quad*8);
  short8 bfr2_0 = *(const short8*)(Wt + (32 + l15)*64 +  0 + quad*8);
  short8 bfr2_1 = *(const short8*)(Wt + (32 + l15)*64 + 32 + quad*8);
  short8 bfr3_0 = *(const short8*)(Wt + (48 + l15)*64 +  0 + quad*8);
  short8 bfr3_1 = *(const short8*)(Wt + (48 + l15)*64 + 32 + quad*8);
  float bs0 = bias[ 0 + l15], bs1 = bias[16 + l15];
  float bs2 = bias[32 + l15], bs3 = bias[48 + l15];
  float w0c0=0,w0c1=0,w0c2=0,w0c3=0, w1c0=0,w1c1=0,w1c2=0,w1c3=0, w2c0=0,w2c1=0,w2c2=0,w2c3=0;
  if (USEREL){
    w0c0=Wr[0*64+l15]; w0c1=Wr[0*64+16+l15]; w0c2=Wr[0*64+32+l15]; w0c3=Wr[0*64+48+l15];
    w1c0=Wr[1*64+l15]; w1c1=Wr[1*64+16+l15]; w1c2=Wr[1*64+32+l15]; w1c3=Wr[1*64+48+l15];
    w2c0=Wr[2*64+l15]; w2c1=Wr[2*64+16+l15]; w2c2=Wr[2*64+32+l15]; w2c3=Wr[2*64+48+l15];
  }

  short8 s0_0{}, s0_1{}, s1_0{}, s1_1{}, s2_0{}, s2_1{}, s3_0{}, s3_1{};
  float eb0=0, eb1=0, eb2=0, eb3=0;
  float e0c0=0,e0c1=0,e0c2=0,e0c3=0, e1c0=0,e1c1=0,e1c2=0,e1c3=0, e2c0=0,e2c1=0,e2c2=0,e2c3=0;
  float ebias_c = 0.f;
  if (EMODE == 1){
    s0_0 = *(const short8*)(Wt2 + ( 0 + l15)*64 +  0 + quad*8);
    s0_1 = *(const short8*)(Wt2 + ( 0 + l15)*64 + 32 + quad*8);
    s1_0 = *(const short8*)(Wt2 + (16 + l15)*64 +  0 + quad*8);
    s1_1 = *(const short8*)(Wt2 + (16 + l15)*64 + 32 + quad*8);
    s2_0 = *(const short8*)(Wt2 + (32 + l15)*64 +  0 + quad*8);
    s2_1 = *(const short8*)(Wt2 + (32 + l15)*64 + 32 + quad*8);
    s3_0 = *(const short8*)(Wt2 + (48 + l15)*64 +  0 + quad*8);
    s3_1 = *(const short8*)(Wt2 + (48 + l15)*64 + 32 + quad*8);
    eb0 = bias2[l15]; eb1 = bias2[16+l15]; eb2 = bias2[32+l15]; eb3 = bias2[48+l15];
    e0c0=Wr2[0*64+l15]; e0c1=Wr2[0*64+16+l15]; e0c2=Wr2[0*64+32+l15]; e0c3=Wr2[0*64+48+l15];
    e1c0=Wr2[1*64+l15]; e1c1=Wr2[1*64+16+l15]; e1c2=Wr2[1*64+32+l15]; e1c3=Wr2[1*64+48+l15];
    e2c0=Wr2[2*64+l15]; e2c1=Wr2[2*64+16+l15]; e2c2=Wr2[2*64+32+l15]; e2c3=Wr2[2*64+48+l15];
  } else if (EMODE == 2){
    s0_0 = *(const short8*)(Wt2 + l15*64 +  0 + quad*8);
    s0_1 = *(const short8*)(Wt2 + l15*64 + 32 + quad*8);
    ebias_c = (l15 < 8) ? bias2[l15] : 0.f;
  }

  for (int t=gw; t<ntiles; t+=nw){
    int i0 = t*16;
    int rowA = i0 + l15; if (rowA >= n) rowA = n-1;
    if (GATHER) rowA = gidx[rowA];
    short8 a0, a1;
    if (APLANE){
      // plane layout: quads 0,1 -> planes 0,1 (a0) / 2,3 (a1); fully coalesced
      const ushortT* ap = A + (size_t)(quad>>1)*na16 + (size_t)rowA*16 + (quad&1)*8;
      a0 = *(const short8*)(ap);
      a1 = *(const short8*)(ap + 2*na16);
    } else {
      const ushortT* ap = A + (size_t)rowA*64 + quad*8;
      a0 = *(const short8*)(ap);
      a1 = *(const short8*)(ap + 32);
    }
    v4f ac0 = {0.f,0.f,0.f,0.f}, ac1 = ac0, ac2 = ac0, ac3 = ac0;
    ac0 = __builtin_amdgcn_mfma_f32_16x16x32_bf16(a0, bfr0_0, ac0, 0,0,0);
    ac1 = __builtin_amdgcn_mfma_f32_16x16x32_bf16(a0, bfr1_0, ac1, 0,0,0);
    ac2 = __builtin_amdgcn_mfma_f32_16x16x32_bf16(a0, bfr2_0, ac2, 0,0,0);
    ac3 = __builtin_amdgcn_mfma_f32_16x16x32_bf16(a0, bfr3_0, ac3, 0,0,0);
    ac0 = __builtin_amdgcn_mfma_f32_16x16x32_bf16(a1, bfr0_1, ac0, 0,0,0);
    ac1 = __builtin_amdgcn_mfma_f32_16x16x32_bf16(a1, bfr1_1, ac1, 0,0,0);
    ac2 = __builtin_amdgcn_mfma_f32_16x16x32_bf16(a1, bfr2_1, ac2, 0,0,0);
    ac3 = __builtin_amdgcn_mfma_f32_16x16x32_bf16(a1, bfr3_1, ac3, 0,0,0);

    #pragma unroll
    for (int r=0;r<4;++r){
      int row = i0 + quad*4 + r;
      bool rowok = (row < n);
      float rx=0.f, ry=0.f, rz=0.f;
      if (USEREL && rowok){ rx=rel[row*3+0]; ry=rel[row*3+1]; rz=rel[row*3+2]; }
      float v0 = ac0[r] + bs0, v1 = ac1[r] + bs1, v2 = ac2[r] + bs2, v3 = ac3[r] + bs3;
      if (USEREL){
        v0 += rx*w0c0 + ry*w1c0 + rz*w2c0;
        v1 += rx*w0c1 + ry*w1c1 + rz*w2c1;
        v2 += rx*w0c2 + ry*w1c2 + rz*w2c2;
        v3 += rx*w0c3 + ry*w1c3 + rz*w2c3;
      }
      if (RELU){ v0=fmaxf(v0,0.f); v1=fmaxf(v1,0.f); v2=fmaxf(v2,0.f); v3=fmaxf(v3,0.f); }
      size_t base = (size_t)row*64 + l15;
      if (rowok){
        if (NRES>=1){
          v0 += bf2f(r1[base]); v1 += bf2f(r1[base+16]); v2 += bf2f(r1[base+32]); v3 += bf2f(r1[base+48]);
        }
        if (NRES>=2){
          v0 += bf2f(r2[base]); v1 += bf2f(r2[base+16]); v2 += bf2f(r2[base+32]); v3 += bf2f(r2[base+48]);
        }
        if (OUT16){
          if (F16O){
            out16[base] = f2h(v0); out16[base+16] = f2h(v1); out16[base+32] = f2h(v2); out16[base+48] = f2h(v3);
          } else {
            out16[base] = f2bf(v0); out16[base+16] = f2bf(v1); out16[base+32] = f2bf(v2); out16[base+48] = f2bf(v3);
          }
        }
      }
      if (EMODE > 0){
        int lb = wslot*(16*LSTR) + (quad*4+r)*LSTR + l15;
        lds[lb]      = f2bf(v0);
        lds[lb + 16] = f2bf(v1);
        lds[lb + 32] = f2bf(v2);
        lds[lb + 48] = f2bf(v3);
      }
    }

    if (EMODE > 0){
      __builtin_amdgcn_wave_barrier();
      const ushortT* lp = lds + wslot*(16*LSTR) + l15*LSTR + quad*8;
      short8 sa0 = *(const short8*)(lp);
      short8 sa1 = *(const short8*)(lp + 32);
      __builtin_amdgcn_wave_barrier();
      if (EMODE == 1){
        v4f ec0 = {0.f,0.f,0.f,0.f}, ec1 = ec0, ec2 = ec0, ec3 = ec0;
        ec0 = __builtin_amdgcn_mfma_f32_16x16x32_bf16(sa0, s0_0, ec0, 0,0,0);
        ec1 = __builtin_amdgcn_mfma_f32_16x16x32_bf16(sa0, s1_0, ec1, 0,0,0);
        ec2 = __builtin_amdgcn_mfma_f32_16x16x32_bf16(sa0, s2_0, ec2, 0,0,0);
        ec3 = __builtin_amdgcn_mfma_f32_16x16x32_bf16(sa0, s3_0, ec3, 0,0,0);
        ec0 = __builtin_amdgcn_mfma_f32_16x16x32_bf16(sa1, s0_1, ec0, 0,0,0);
        ec1 = __builtin_amdgcn_mfma_f32_16x16x32_bf16(sa1, s1_1, ec1, 0,0,0);
        ec2 = __builtin_amdgcn_mfma_f32_16x16x32_bf16(sa1, s2_1, ec2, 0,0,0);
        ec3 = __builtin_amdgcn_mfma_f32_16x16x32_bf16(sa1, s3_1, ec3, 0,0,0);
        ushortT* eo = (ushortT*)eout;
        #pragma unroll
        for (int r=0;r<4;++r){
          int row = i0 + quad*4 + r;
          if (row < n){
            float vx=vec2[row*3+0], vy=vec2[row*3+1], vz=vec2[row*3+2];
            float g0 = ec0[r] + eb0 + vx*e0c0 + vy*e1c0 + vz*e2c0;
            float g1 = ec1[r] + eb1 + vx*e0c1 + vy*e1c1 + vz*e2c1;
            float g2 = ec2[r] + eb2 + vx*e0c2 + vy*e1c2 + vz*e2c2;
            float g3 = ec3[r] + eb3 + vx*e0c3 + vy*e1c3 + vz*e2c3;
            if (ERELU){ g0=fmaxf(g0,0.f); g1=fmaxf(g1,0.f); g2=fmaxf(g2,0.f); g3=fmaxf(g3,0.f); }
            size_t pb = (size_t)row*16 + l15;
            eo[pb] = f2h(g0); eo[pb+n16] = f2h(g1); eo[pb+2*n16] = f2h(g2); eo[pb+3*n16] = f2h(g3);
          }
        }
      } else {
        v4f ec = {0.f,0.f,0.f,0.f};
        ec = __builtin_amdgcn_mfma_f32_16x16x32_bf16(sa0, s0_0, ec, 0,0,0);
        ec = __builtin_amdgcn_mfma_f32_16x16x32_bf16(sa1, s0_1, ec, 0,0,0);
        if (l15 < 8){
          float* eo = (float*)eout;
          #pragma unroll
          for (int r=0;r<4;++r){
            int row = i0 + quad*4 + r;
            if (row < n) eo[(size_t)row*8 + l15] = ec[r] + ebias_c;
          }
        }
      }
    }
  }
}

// ============================ edge aggregation: plane-sharded, XCD-pinned, clustered gathers ============================
// One plane (16 cols, 3.2MB for N) per XCD pair via blockIdx%8. Wave = 32 dsts x 2 lanes x 16B.
// R0-style inner loop: ONE guard per 8-edge round, csr indices clamped (dup tail gathers are
// idempotent for max and cache-hit), 8 unconditional 16B gathers issued back-to-back (MLP=8).

__global__ __launch_bounds__(256) void k_edge_agg(const int* __restrict__ offs, const int* __restrict__ csr,
                                                  const float* __restrict__ pos, const ushortT* __restrict__ g,
                                                  const float* __restrict__ Wp, ushortT* __restrict__ agg,
                                                  int n, int n32){
  int tid = threadIdx.x;
  int lane = tid & 63, wslot = tid >> 6;
  int grp = lane >> 1, h = lane & 1;
  int gbase = lane & 62;
  int b7 = blockIdx.x & 7;
  int plane = b7 >> 1;
  int bp = ((blockIdx.x >> 3) << 1) + (b7 & 1);
  int ii = bp*4 + wslot;
  if (ii >= n32) return;
  const ushortT* gp = g + (size_t)plane*n*16;
  int c0 = plane*16 + h*8;
  float2 w0[4], w1[4], w2[4];
  #pragma unroll
  for (int q=0;q<4;++q){
    w0[q] = *(const float2*)(Wp + 0*64 + c0 + 2*q);
    w1[q] = *(const float2*)(Wp + 1*64 + c0 + 2*q);
    w2[q] = *(const float2*)(Wp + 2*64 + c0 + 2*q);
  }
  const h2 NEGBIG = {(_Float16)-60000.f, (_Float16)-60000.f};
  int ig = ii*32 + grp;
  bool ok = ig < n;
  int igc = ok ? ig : (n-1);
  int bofs = __builtin_nontemporal_load(offs + igc);
  int cnt  = __builtin_nontemporal_load(offs + igc + 1) - bofs;
  if (!ok) cnt = 0;
  int c1 = cnt - 1;
  int mx = cnt;
  mx = max(mx, __shfl_xor(mx,  2, 64));
  mx = max(mx, __shfl_xor(mx,  4, 64));
  mx = max(mx, __shfl_xor(mx,  8, 64));
  mx = max(mx, __shfl_xor(mx, 16, 64));
  mx = max(mx, __shfl_xor(mx, 32, 64));
  h2 m0=NEGBIG, m1=NEGBIG, m2=NEGBIG, m3=NEGBIG;
  for (int J=0; J<mx; J+=8){
    if (J < cnt){
      // lane h holds entries J+h, J+h+2, J+h+4, J+h+6 (clamped)
      int sv0 = __builtin_nontemporal_load(csr + bofs + min(J+h,   c1));
      int sv1 = __builtin_nontemporal_load(csr + bofs + min(J+h+2, c1));
      int sv2 = __builtin_nontemporal_load(csr + bofs + min(J+h+4, c1));
      int sv3 = __builtin_nontemporal_load(csr + bofs + min(J+h+6, c1));
      int s0 = __shfl(sv0, gbase,   64);
      int s1 = __shfl(sv0, gbase+1, 64);
      int s2 = __shfl(sv1, gbase,   64);
      int s3 = __shfl(sv1, gbase+1, 64);
      int s4 = __shfl(sv2, gbase,   64);
      int s5 = __shfl(sv2, gbase+1, 64);
      int s6 = __shfl(sv3, gbase,   64);
      int s7 = __shfl(sv3, gbase+1, 64);
      u4v u0 = *(const u4v*)(gp + (size_t)s0*16 + h*8);
      u4v u1 = *(const u4v*)(gp + (size_t)s1*16 + h*8);
      u4v u2 = *(const u4v*)(gp + (size_t)s2*16 + h*8);
      u4v u3 = *(const u4v*)(gp + (size_t)s3*16 + h*8);
      u4v u4_ = *(const u4v*)(gp + (size_t)s4*16 + h*8);
      u4v u5 = *(const u4v*)(gp + (size_t)s5*16 + h*8);
      u4v u6 = *(const u4v*)(gp + (size_t)s6*16 + h*8);
      u4v u7 = *(const u4v*)(gp + (size_t)s7*16 + h*8);
      m0 = pkmax(m0, u2h(u0.x)); m1 = pkmax(m1, u2h(u0.y)); m2 = pkmax(m2, u2h(u0.z)); m3 = pkmax(m3, u2h(u0.w));
      m0 = pkmax(m0, u2h(u1.x)); m1 = pkmax(m1, u2h(u1.y)); m2 = pkmax(m2, u2h(u1.z)); m3 = pkmax(m3, u2h(u1.w));
      m0 = pkmax(m0, u2h(u2.x)); m1 = pkmax(m1, u2h(u2.y)); m2 = pkmax(m2, u2h(u2.z)); m3 = pkmax(m3, u2h(u2.w));
      m0 = pkmax(m0, u2h(u3.x)); m1 = pkmax(m1, u2h(u3.y)); m2 = pkmax(m2, u2h(u3.z)); m3 = pkmax(m3, u2h(u3.w));
      m0 = pkmax(m0, u2h(u4_.x)); m1 = pkmax(m1, u2h(u4_.y)); m2 = pkmax(m2, u2h(u4_.z)); m3 = pkmax(m3, u2h(u4_.w));
      m0 = pkmax(m0, u2h(u5.x)); m1 = pkmax(m1, u2h(u5.y)); m2 = pkmax(m2, u2h(u5.z)); m3 = pkmax(m3, u2h(u5.w));
      m0 = pkmax(m0, u2h(u6.x)); m1 = pkmax(m1, u2h(u6.y)); m2 = pkmax(m2, u2h(u6.z)); m3 = pkmax(m3, u2h(u6.w));
      m0 = pkmax(m0, u2h(u7.x)); m1 = pkmax(m1, u2h(u7.y)); m2 = pkmax(m2, u2h(u7.z)); m3 = pkmax(m3, u2h(u7.w));
    }
  }
  float px = __builtin_nontemporal_load(pos + igc*3 + 0);
  float py = __builtin_nontemporal_load(pos + igc*3 + 1);
  float pz = __builtin_nontemporal_load(pos + igc*3 + 2);
  u4v outv;
  {
    float sA = w0[0].x*px + w1[0].x*py + w2[0].x*pz;
    float sB = w0[0].y*px + w1[0].y*py + w2[0].y*pz;
    outv.x = (unsigned)f2bf(fmaxf((float)m0.x - sA, 0.f)) |
             ((unsigned)f2bf(fmaxf((float)m0.y - sB, 0.f)) << 16);
  }
  {
    float sA = w0[1].x*px + w1[1].x*py + w2[1].x*pz;
    float sB = w0[1].y*px + w1[1].y*py + w2[1].y*pz;
    outv.y = (unsigned)f2bf(fmaxf((float)m1.x - sA, 0.f)) |
             ((unsigned)f2bf(fmaxf((float)m1.y - sB, 0.f)) << 16);
  }
  {
    float sA = w0[2].x*px + w1[2].x*py + w2[2].x*pz;
    float sB = w0[2].y*px + w1[2].y*py + w2[2].y*pz;
    outv.z = (unsigned)f2bf(fmaxf((float)m2.x - sA, 0.f)) |
             ((unsigned)f2bf(fmaxf((float)m2.y - sB, 0.f)) << 16);
  }
  {
    float sA = w0[3].x*px + w1[3].x*py + w2[3].x*pz;
    float sB = w0[3].y*px + w1[3].y*py + w2[3].y*pz;
    outv.w = (unsigned)f2bf(fmaxf((float)m3.x - sA, 0.f)) |
             ((unsigned)f2bf(fmaxf((float)m3.y - sB, 0.f)) << 16);
  }
  if (ok) __builtin_nontemporal_store(outv, (u4v*)(agg + ((size_t)plane*n + ig)*16 + h*8));
}

// ============================ segment sum via label CSR (f16 plane in, bf16 row-major out) ============================

__global__ __launch_bounds__(256) void k_seg_gather(const int* __restrict__ offs, const int* __restrict__ csr,
                                                    const ushortT* __restrict__ h, ushortT* __restrict__ c,
                                                    int m, int nh){
  int lane = threadIdx.x & 63;
  int l15 = lane & 15, q = lane >> 4;
  int wv = (blockIdx.x*256 + threadIdx.x) >> 6;
  if (wv >= m) return;
  int b = offs[wv], e = offs[wv+1];
  float acc = 0.f;
  const ushortT* hp = h + (size_t)q*nh*16 + l15;
  for (int k=b; k<e; ++k){
    int i = csr[k];
    acc += h2f(hp[(size_t)i*16]);
  }
  c[(size_t)wv*64 + lane] = f2bf(acc);
}

// ============================ host launcher ============================

extern "C" void kernel_launch(void* const* d_in, const int* in_sizes, int n_in,
                              void* d_out, int out_size, void* d_ws, size_t ws_size,
                              hipStream_t stream){
  const float* features = (const float*)d_in[0];
  const float* points   = (const float*)d_in[1];
  const float* centers  = (const float*)d_in[2];
  const int*   l0e      = (const int*)d_in[3];
  const int*   l1e      = (const int*)d_in[4];
  const int*   labels   = (const int*)d_in[5];
  const float* W_fe = (const float*)d_in[6];
  const float* b_fe = (const float*)d_in[7];
  const float* mWe  = (const float*)d_in[8];
  const float* mbe  = (const float*)d_in[9];
  const float* mWu  = (const float*)d_in[10];
  const float* mbu  = (const float*)d_in[11];
  const float* W_m1 = (const float*)d_in[12];
  const float* b_m1 = (const float*)d_in[13];
  const float* W_m2 = (const float*)d_in[14];
  const float* b_m2 = (const float*)d_in[15];
  const float* gWe  = (const float*)d_in[16];
  const float* gbe  = (const float*)d_in[17];
  const float* gWu  = (const float*)d_in[18];
  const float* gbu  = (const float*)d_in[19];
  const float* W_l  = (const float*)d_in[20];
  const float* b_l  = (const float*)d_in[21];
  const float* W_c  = (const float*)d_in[22];
  const float* b_c  = (const float*)d_in[23];
  float* out = (float*)d_out;

  char* w = (char*)d_ws;
  size_t off = 0;
  auto alloc = [&](size_t bytes)->void*{
    void* p = (void*)(w + off);
    off = (off + bytes + 255) & ~(size_t)255;
    return p;
  };
  float* rel  = (float*)alloc((size_t)N_PTS*3*4);
  ushortT* UF1 = (ushortT*)alloc((size_t)N_PTS*64*2);
  ushortT* UF2 = (ushortT*)alloc((size_t)N_PTS*64*2);
  ushortT* UF21= (ushortT*)alloc((size_t)N_PTS*64*2);
  ushortT* UF5 = (ushortT*)alloc((size_t)N_PTS*64*2);
  ushortT* UF6 = (ushortT*)alloc((size_t)N_PTS*64*2);
  ushortT* gbuf= (ushortT*)alloc((size_t)N_PTS*64*2);
  ushortT* abuf= (ushortT*)alloc((size_t)N_PTS*64*2);
  ushortT* cb_b= (ushortT*)alloc((size_t)M_CL*64*2);
  ushortT* UF3 = (ushortT*)alloc((size_t)M_CL*64*2);
  ushortT* UF4 = (ushortT*)alloc((size_t)M_CL*64*2);
  ushortT* cg_b= (ushortT*)alloc((size_t)M_CL*64*2);
  ushortT* cagg_b = (ushortT*)alloc((size_t)M_CL*64*2);
  ushortT* f41_b  = (ushortT*)alloc((size_t)M_CL*64*2);
  ushortT* wt  = (ushortT*)alloc((size_t)15*4096*2);
  ushortT* wtc = (ushortT*)alloc((size_t)1024*2);
  int* offs0 = (int*)alloc((size_t)(N_PTS+1)*4);
  int* csr0  = (int*)alloc((size_t)E0_N*4);
  int* offs1 = (int*)alloc((size_t)(M_CL+1)*4);
  int* csr1  = (int*)alloc((size_t)E1_N*4);
  int* offsL = (int*)alloc((size_t)(M_CL+1)*4);
  int* csrL  = (int*)alloc((size_t)N_PTS*4);
  unsigned* tmp0 = (unsigned*)alloc((size_t)NB*BCAP0*4);
  unsigned* tmp1 = (unsigned*)alloc((size_t)NB*BCAP1*4);
  unsigned* tmpL = (unsigned*)alloc((size_t)NB*BCAPL*4);
  int* bcur0 = (int*)alloc(NB*4);
  int* bcur1 = (int*)alloc(NB*4);
  int* bcurL = (int*)alloc(NB*4);
  int* bb0   = (int*)alloc(NB*4);
  int* bb1   = (int*)alloc(NB*4);
  int* bbL   = (int*)alloc(NB*4);
  (void)ws_size; (void)in_sizes; (void)n_in; (void)out_size;

  const int NT_N = (N_PTS+15)/16;
  const int NT_M = (M_CL +15)/16;
  const int GBG_N = 1563;
  const int GBG_M = 196;
  const int GB_AGG_N = 3128;   // 4 planes x 782 blocks (blockIdx%8 -> XCD pin)
  const int N32_N    = 3125;   // ceil(N/32)
  const int GB_AGG_M = 392;    // 4 planes x 98 blocks
  const int N32_M    = 391;    // ceil(M/32)

  // ---- setup: weights + counters (1), bin all three lists (1), scan (1), build (1) ----
  WSrc ws{};
  ws.p[0]=mWu+0*4096; ws.p[1]=mWu+1*4096; ws.p[2]=mWu+2*4096; ws.p[3]=mWu+3*4096;
  ws.p[4]=W_m2; ws.p[5]=gWu+0*4096; ws.p[6]=gWu+1*4096;
  ws.p[7]=mWe+0*4288+192; ws.p[8]=mWe+1*4288+192; ws.p[9]=mWe+2*4288+192; ws.p[10]=mWe+3*4288+192;
  ws.p[11]=W_m1; ws.p[12]=W_l; ws.p[13]=gWe+0*4288+192; ws.p[14]=gWe+1*4288+192;
  ws.p[15]=W_c;
  k_init_wprep<<<17, 256, 0, stream>>>(ws, wt, wtc, bcur0, bcur1, bcurL);
  k_bin_all<<<501, 256, 0, stream>>>(l0e, l1e, labels, bcur0, bcur1, bcurL, tmp0, tmp1, tmpL);
  k_scan_all<<<3, 64, 0, stream>>>(bcur0, bb0, offs0+N_PTS, bcur1, bb1, offs1+M_CL, bcurL, bbL, offsL+M_CL);
  k_build_all<<<768, 256, 0, stream>>>(tmp0, bcur0, bb0, offs0, csr0,
                                       tmp1, bcur1, bb1, offs1, csr1,
                                       tmpL, bcurL, bbL, offsL, csrL);

  // ---- FUSED encoder: rel + f1 (bf16 rows) + g0' (f16 planes) ----
  k_f1g<<<GBG_N, 256, 0, stream>>>(features, points, centers, labels, W_fe, b_fe,
      wt+7*4096, mbe+0, mWe+0*4288, rel, UF1, gbuf, N_PTS, NT_N);

  // ---- layer0: agg -> FUSED [f2 -> UF2] + [g1' -> gbuf] ----
  k_edge_agg<<<GB_AGG_N,256,0,stream>>>(offs0, csr0, points, gbuf, mWe+0*4288, abuf, N_PTS, N32_N);
  k_gemm<true,1,false,false,true,true,false,1,false><<<GBG_N,256,0,stream>>>(abuf, wt+0*4096, mbu+0,
      nullptr, nullptr, nullptr, UF1, nullptr, UF2,
      wt+8*4096, mbe+64, mWe+1*4288, points, gbuf, N_PTS, N_PTS, NT_N);
  // ---- layer1: agg -> FUSED [f2_1 -> UF21] + [h -> gbuf] ----
  k_edge_agg<<<GB_AGG_N,256,0,stream>>>(offs0, csr0, points, gbuf, mWe+1*4288, abuf, N_PTS, N32_N);
  k_gemm<true,1,false,false,true,true,false,1,true><<<GBG_N,256,0,stream>>>(abuf, wt+1*4096, mbu+64,
      nullptr, nullptr, nullptr, UF2, nullptr, UF21,
      wt+11*4096, b_m1, W_m1+4096, rel, gbuf, N_PTS, N_PTS, NT_N);
  // ---- c = segsum(h); FUSED [f3 -> UF3] + [cg0' -> cg_b] ----
  k_seg_gather<<<(M_CL*64+255)/256, 256, 0, stream>>>(offsL, csrL, gbuf, cb_b, M_CL, N_PTS);
  k_gemm<true,0,false,false,false,true,false,1,false><<<GBG_M,256,0,stream>>>(cb_b, wt+4*4096, b_m2,
      nullptr, nullptr, nullptr, nullptr, nullptr, UF3,
      wt+13*4096, gbe+0, gWe+0*4288, centers, cg_b, M_CL, M_CL, NT_M);
  // ---- cluster layer0: agg -> FUSED [f4 -> UF4] + [cg1' -> cg_b] ----
  k_edge_agg<<<GB_AGG_M,256,0,stream>>>(offs1, csr1, centers, cg_b, gWe+0*4288, cagg_b, M_CL, N32_M);
  k_gemm<true,1,false,false,true,true,false,1,false><<<GBG_M,256,0,stream>>>(cagg_b, wt+5*4096, gbu+0,
      nullptr, nullptr, nullptr, UF3, nullptr, UF4,
      wt+14*4096, gbe+64, gWe+1*4288, centers, cg_b, M_CL, M_CL, NT_M);
  // ---- cluster layer1: agg -> f4_1 -> f41_b ----
  k_edge_agg<<<GB_AGG_M,256,0,stream>>>(offs1, csr1, centers, cg_b, gWe+1*4288, cagg_b, M_CL, N32_M);
  k_gemm<true,1,false,false,true,true,false,0,false><<<GBG_M,256,0,stream>>>(cagg_b, wt+6*4096, gbu+64,
      nullptr, nullptr, nullptr, UF4, nullptr, f41_b,
      nullptr, nullptr, nullptr, nullptr, nullptr, M_CL, M_CL, NT_M);
  // ---- FUSED [f5 -> UF5] + [g2' -> gbuf] ----
  k_gemm<true,0,true,true,false,true,false,1,false><<<GBG_N,256,0,stream>>>(f41_b, wt+12*4096, b_l,
      W_l+4096, rel, labels, nullptr, nullptr, UF5,
      wt+9*4096, mbe+128, mWe+2*4288, points, gbuf, N_PTS, M_CL, NT_N);
  // ---- layer2: agg -> FUSED [f6 = relu+f5+f2_1 -> UF6] + [g3' -> gbuf] ----
  k_edge_agg<<<GB_AGG_N,256,0,stream>>>(offs0, csr0, points, gbuf, mWe+2*4288, abuf, N_PTS, N32_N);
  k_gemm<true,2,false,false,true,true,false,1,false><<<GBG_N,256,0,stream>>>(abuf, wt+2*4096, mbu+128,
      nullptr, nullptr, nullptr, UF5, UF21, UF6,
      wt+10*4096, mbe+192, mWe+3*4288, points, gbuf, N_PTS, N_PTS, NT_N);
  // ---- layer3: agg -> FUSED [final = relu+f6+f2] + [out = final@W_c + b_c] ----
  k_edge_agg<<<GB_AGG_N,256,0,stream>>>(offs0, csr0, points, gbuf, mWe+3*4288, abuf, N_PTS, N32_N);
  k_gemm<true,2,false,false,true,false,false,2,false><<<GBG_N,256,0,stream>>>(abuf, wt+3*4096, mbu+192,
      nullptr, nullptr, nullptr, UF6, UF2, nullptr,
      wtc, b_c, nullptr, nullptr, out, N_PTS, N_PTS, NT_N);
}

// Round 3
// 481.825 us; speedup vs baseline: 1.3536x; 1.3484x over previous
//
#include <hip/hip_runtime.h>

// R3: exact R0 structure (row-major [rows][64] everywhere; 128-B-per-edge gathers:
// 8 lanes x 16B per dst row — one fully-utilized cache line per edge, the measured-
// optimal request granularity; plane/L2-pinning experiments R1/R2 reverted: they cut
// HBM traffic to ideal but 4x'd L2 request count and lost 1.7x).
// Single change vs R0: k_edge_agg MLP 8 -> 16 (two csr dwords + 16 in-flight gathers
// per round) to test latency-bound vs L3-throughput-bound.

#define N_PTS   100000
#define M_CL    12500
#define E0_N    1600000
#define E1_N    400000

#define NB      256
#define BIN_CAP 32
#define RANGE0  391
#define RANGE1  49           // also used for labels (ceil(12500/256))
#define BCAP0   8192
#define BCAP1   2048
#define BCAPL   1024

#define LSTR    72           // LDS row stride (shorts): 144 B, 16-B aligned

typedef unsigned short ushortT;
typedef short  short8 __attribute__((ext_vector_type(8)));
typedef float  v4f    __attribute__((ext_vector_type(4)));
typedef _Float16 h2   __attribute__((ext_vector_type(2)));
typedef unsigned u4v  __attribute__((ext_vector_type(4)));

__device__ inline ushortT f2bf(float x){
  union{float f; unsigned u;} v; v.f = x;
  unsigned r = v.u + 0x7fffu + ((v.u >> 16) & 1u);   // RNE
  return (ushortT)(r >> 16);
}
__device__ inline float bf2f(ushortT h){
  union{unsigned u; float f;} v; v.u = ((unsigned)h) << 16;
  return v.f;
}
__device__ inline ushortT f2h(float x){
  union{_Float16 h; ushortT u;} v; v.h = (_Float16)x;
  return v.u;
}
__device__ inline float h2f(ushortT u){
  union{ushortT u; _Float16 h;} v; v.u = u;
  return (float)v.h;
}
__device__ inline h2 pkmax(h2 a, h2 b){ return __builtin_elementwise_max(a, b); }
__device__ inline h2 u2h(unsigned u){ union{unsigned u; h2 h;} v{u}; return v.h; }

// ============================ weight prep + counter init (1 dispatch) ============================

struct WSrc { const float* p[16]; };

__global__ __launch_bounds__(256) void k_init_wprep(WSrc s, ushortT* __restrict__ wt, ushortT* __restrict__ wtc,
                                                    int* c0, int* c1, int* cL){
  int blk = blockIdx.x;
  if (blk == 0){
    int t = threadIdx.x;
    c0[t] = t*BCAP0; c1[t] = t*BCAP1; cL[t] = t*BCAPL;
    return;
  }
  int slot = blk - 1;
  if (slot < 15){
    const float* src = s.p[slot];
    ushortT* dst = wt + slot*4096;
    for (int e=threadIdx.x; e<4096; e+=256){
      int nn = e>>6, kk = e&63;
      dst[e] = f2bf(src[kk*64+nn]);
    }
  } else {
    const float* src = s.p[15];
    for (int e=threadIdx.x; e<1024; e+=256){
      int nn = e>>6, kk = e&63;
      wtc[e] = (nn<8) ? f2bf(src[kk*8+nn]) : (ushortT)0;
    }
  }
}

// ============================ bucketed CSR build (l0 + l1 + labels, merged) ============================
// LAB: edge e is (src=e, dst=edges[e]) — the labels list.

template<int RANGE, bool LAB>
__device__ void bin_seg(const int* __restrict__ edges, int E,
                        int* __restrict__ bcur, unsigned* __restrict__ tmp,
                        int bid, int nblk,
                        unsigned* stage, int* scnt, int* sbase){
  int tid = threadIdx.x;
  int nchunks = (E + 2047) / 2048;
  for (int c = bid; c < nchunks; c += nblk){
    int base = c*2048;
    scnt[tid] = 0;
    __syncthreads();
    #pragma unroll
    for (int r=0;r<8;++r){
      int e = base + r*256 + tid;
      if (e < E){
        int s, d;
        if (LAB){ s = e; d = edges[e]; }
        else    { s = edges[2*e]; d = edges[2*e+1]; }
        int bk = d / RANGE;
        unsigned packed = ((unsigned)s << 11) | (unsigned)(d - bk*RANGE);
        int pos = atomicAdd(&scnt[bk], 1);
        if (pos < BIN_CAP) stage[bk*BIN_CAP+pos] = packed;
        else tmp[atomicAdd(&bcur[bk],1)] = packed;
      }
    }
    __syncthreads();
    {
      int nfl = scnt[tid]; if (nfl > BIN_CAP) nfl = BIN_CAP;
      sbase[tid] = atomicAdd(&bcur[tid], nfl);
    }
    __syncthreads();
    int wv = tid >> 6, ln = tid & 63;
    for (int bb=0; bb<32; ++bb){
      int bk = wv*64 + bb*2 + (ln>>5);
      int ent = ln & 31;
      int nf = scnt[bk]; if (nf > BIN_CAP) nf = BIN_CAP;
      if (ent < nf) tmp[sbase[bk]+ent] = stage[bk*BIN_CAP+ent];
    }
    __syncthreads();
  }
}

__global__ __launch_bounds__(256) void k_bin_all(const int* __restrict__ l0e, const int* __restrict__ l1e,
                                                 const int* __restrict__ labels,
                                                 int* bc0, int* bc1, int* bcL,
                                                 unsigned* t0, unsigned* t1, unsigned* tL){
  __shared__ unsigned stage[NB*BIN_CAP];
  __shared__ int scnt[NB];
  __shared__ int sbase[NB];
  int b = blockIdx.x;
  if (b < 256)      bin_seg<RANGE0,false>(l0e, E0_N, bc0, t0, b, 256, stage, scnt, sbase);
  else if (b < 452) bin_seg<RANGE1,false>(l1e, E1_N, bc1, t1, b-256, 196, stage, scnt, sbase);
  else              bin_seg<RANGE1,true >(labels, N_PTS, bcL, tL, b-452, 49, stage, scnt, sbase);
}

// exclusive scan of 256 bucket counts; blocks: 0->l0, 1->l1, 2->labels
__global__ void k_scan_all(const int* c0, int* bb0, int* e0,
                           const int* c1, int* bb1, int* e1,
                           const int* cL, int* bbL, int* eL){
  const int* cur; int* bb; int* offe; int BC;
  if (blockIdx.x == 0){ cur=c0; bb=bb0; offe=e0; BC=BCAP0; }
  else if (blockIdx.x == 1){ cur=c1; bb=bb1; offe=e1; BC=BCAP1; }
  else { cur=cL; bb=bbL; offe=eL; BC=BCAPL; }
  int lane = threadIdx.x & 63;
  int base = lane*4;
  int v0 = cur[base+0] - (base+0)*BC;
  int v1 = cur[base+1] - (base+1)*BC;
  int v2 = cur[base+2] - (base+2)*BC;
  int v3 = cur[base+3] - (base+3)*BC;
  int psum = v0+v1+v2+v3, sc = psum;
  #pragma unroll
  for (int st=1; st<64; st<<=1){
    int x = __shfl_up(sc, st, 64);
    if (lane >= st) sc += x;
  }
  int ex = sc - psum;
  bb[base+0] = ex;
  bb[base+1] = ex + v0;
  bb[base+2] = ex + v0 + v1;
  bb[base+3] = ex + v0 + v1 + v2;
  if (lane == 63) *offe = sc;
}

template<int RANGE, int BCAP, int K>
__device__ void csr_build_seg(const unsigned* __restrict__ tmp, const int* __restrict__ bcur,
                              const int* __restrict__ bb, int n,
                              int* __restrict__ offs, int* __restrict__ csr,
                              int b, int* hist, int* part){
  int tid = threadIdx.x;
  int dlo = b*RANGE;
  int range = n - dlo; if (range > RANGE) range = RANGE; if (range < 0) range = 0;
  int cnt = bcur[b] - b*BCAP;
  for (int t=tid; t<RANGE; t+=256) hist[t] = 0;
  __syncthreads();
  const unsigned* sl = tmp + (size_t)b*BCAP;
  for (int j=tid; j<cnt; j+=256) atomicAdd(&hist[sl[j] & 2047u], 1);
  __syncthreads();
  int s = 0; int loc[K];
  #pragma unroll
  for (int kk=0; kk<K; ++kk){
    int idx = tid*K + kk;
    int v = (idx < RANGE) ? hist[idx] : 0;
    loc[kk] = s; s += v;
  }
  part[tid] = s; __syncthreads();
  int own = s;
  for (int st=1; st<256; st<<=1){
    int x = (tid >= st) ? part[tid-st] : 0;
    __syncthreads();
    part[tid] += x;
    __syncthreads();
  }
  int ebase = part[tid] - own;
  int gb = bb[b];
  __syncthreads();
  #pragma unroll
  for (int kk=0; kk<K; ++kk){
    int idx = tid*K + kk;
    if (idx < RANGE){
      int ex = ebase + loc[kk];
      if (idx < range) offs[dlo+idx] = gb + ex;
      hist[idx] = ex;
    }
  }
  __syncthreads();
  for (int j=tid; j<cnt; j+=256){
    unsigned p = sl[j];
    int pos = atomicAdd(&hist[p & 2047u], 1);
    csr[gb + pos] = (int)(p >> 11);
  }
}

__global__ __launch_bounds__(256) void k_build_all(
    const unsigned* t0, const int* bc0, const int* bb0, int* offs0, int* csr0,
    const unsigned* t1, const int* bc1, const int* bb1, int* offs1, int* csr1,
    const unsigned* tL, const int* bcL, const int* bbL, int* offsL, int* csrL){
  __shared__ int hist[RANGE0];
  __shared__ int part[256];
  int b = blockIdx.x;
  if (b < 256)      csr_build_seg<RANGE0,BCAP0,2>(t0, bc0, bb0, N_PTS, offs0, csr0, b, hist, part);
  else if (b < 512) csr_build_seg<RANGE1,BCAP1,1>(t1, bc1, bb1, M_CL, offs1, csr1, b-256, hist, part);
  else              csr_build_seg<RANGE1,BCAPL,1>(tL, bcL, bbL, M_CL, offsL, csrL, b-512, hist, part);
}

// ============================ fused encoder: rel + f1(bf16) + g0'(f16 via MFMA) ============================

__global__ __launch_bounds__(256) void k_f1g(const float* __restrict__ features, const float* __restrict__ points,
                                             const float* __restrict__ centers, const int* __restrict__ labels,
                                             const float* __restrict__ W, const float* __restrict__ b,
                                             const ushortT* __restrict__ Wt2, const float* __restrict__ bias2,
                                             const float* __restrict__ Wr2,
                                             float* __restrict__ rel, ushortT* __restrict__ f1b,
                                             ushortT* __restrict__ gout, int n, int ntiles){
  __shared__ ushortT lds[4*16*LSTR];
  int tid = threadIdx.x;
  int lane = tid & 63, wslot = tid >> 6;
  int quad = lane >> 4, l15 = lane & 15;
  int gw = (blockIdx.x*256 + tid) >> 6;
  int nw = (gridDim.x*256) >> 6;
  float Wf0=W[0*64+lane], Wf1=W[1*64+lane], Wf2=W[2*64+lane], Wf3=W[3*64+lane];
  float wr0=W[4*64+lane], wr1=W[5*64+lane], wr2=W[6*64+lane];
  float bias=b[lane];
  short8 s0_0 = *(const short8*)(Wt2 + ( 0 + l15)*64 +  0 + quad*8);
  short8 s0_1 = *(const short8*)(Wt2 + ( 0 + l15)*64 + 32 + quad*8);
  short8 s1_0 = *(const short8*)(Wt2 + (16 + l15)*64 +  0 + quad*8);
  short8 s1_1 = *(const short8*)(Wt2 + (16 + l15)*64 + 32 + quad*8);
  short8 s2_0 = *(const short8*)(Wt2 + (32 + l15)*64 +  0 + quad*8);
  short8 s2_1 = *(const short8*)(Wt2 + (32 + l15)*64 + 32 + quad*8);
  short8 s3_0 = *(const short8*)(Wt2 + (48 + l15)*64 +  0 + quad*8);
  short8 s3_1 = *(const short8*)(Wt2 + (48 + l15)*64 + 32 + quad*8);
  float eb0 = bias2[l15], eb1 = bias2[16+l15], eb2 = bias2[32+l15], eb3 = bias2[48+l15];
  float e0c0=Wr2[0*64+l15], e0c1=Wr2[0*64+16+l15], e0c2=Wr2[0*64+32+l15], e0c3=Wr2[0*64+48+l15];
  float e1c0=Wr2[1*64+l15], e1c1=Wr2[1*64+16+l15], e1c2=Wr2[1*64+32+l15], e1c3=Wr2[1*64+48+l15];
  float e2c0=Wr2[2*64+l15], e2c1=Wr2[2*64+16+l15], e2c2=Wr2[2*64+32+l15], e2c3=Wr2[2*64+48+l15];

  for (int t=gw; t<ntiles; t+=nw){
    int i0 = t*16;
    for (int r=0;r<16;++r){
      int row = i0 + r;
      bool ok = row < n;
      int rr = ok ? row : n-1;
      int lb = labels[rr];
      float rx = points[rr*3+0]-centers[lb*3+0];
      float ry = points[rr*3+1]-centers[lb*3+1];
      float rz = points[rr*3+2]-centers[lb*3+2];
      float acc = bias + wr0*rx + wr1*ry + wr2*rz;
      acc += features[rr*4+0]*Wf0 + features[rr*4+1]*Wf1;
      acc += features[rr*4+2]*Wf2 + features[rr*4+3]*Wf3;
      acc = fmaxf(acc, 0.f);
      ushortT ab = f2bf(acc);
      if (ok){
        f1b[(size_t)row*64+lane] = ab;
        if (lane==0){ rel[row*3+0]=rx; rel[row*3+1]=ry; rel[row*3+2]=rz; }
      }
      lds[wslot*(16*LSTR) + r*LSTR + lane] = ab;
    }
    __builtin_amdgcn_wave_barrier();
    const ushortT* lp = lds + wslot*(16*LSTR) + l15*LSTR + quad*8;
    short8 sa0 = *(const short8*)(lp);
    short8 sa1 = *(const short8*)(lp + 32);
    __builtin_amdgcn_wave_barrier();
    v4f ec0 = {0.f,0.f,0.f,0.f}, ec1 = ec0, ec2 = ec0, ec3 = ec0;
    ec0 = __builtin_amdgcn_mfma_f32_16x16x32_bf16(sa0, s0_0, ec0, 0,0,0);
    ec1 = __builtin_amdgcn_mfma_f32_16x16x32_bf16(sa0, s1_0, ec1, 0,0,0);
    ec2 = __builtin_amdgcn_mfma_f32_16x16x32_bf16(sa0, s2_0, ec2, 0,0,0);
    ec3 = __builtin_amdgcn_mfma_f32_16x16x32_bf16(sa0, s3_0, ec3, 0,0,0);
    ec0 = __builtin_amdgcn_mfma_f32_16x16x32_bf16(sa1, s0_1, ec0, 0,0,0);
    ec1 = __builtin_amdgcn_mfma_f32_16x16x32_bf16(sa1, s1_1, ec1, 0,0,0);
    ec2 = __builtin_amdgcn_mfma_f32_16x16x32_bf16(sa1, s2_1, ec2, 0,0,0);
    ec3 = __builtin_amdgcn_mfma_f32_16x16x32_bf16(sa1, s3_1, ec3, 0,0,0);
    #pragma unroll
    for (int r=0;r<4;++r){
      int row = i0 + quad*4 + r;
      if (row < n){
        float vx=points[row*3+0], vy=points[row*3+1], vz=points[row*3+2];
        float g0 = ec0[r] + eb0 + vx*e0c0 + vy*e1c0 + vz*e2c0;
        float g1 = ec1[r] + eb1 + vx*e0c1 + vy*e1c1 + vz*e2c1;
        float g2 = ec2[r] + eb2 + vx*e0c2 + vy*e1c2 + vz*e2c2;
        float g3 = ec3[r] + eb3 + vx*e0c3 + vy*e1c3 + vz*e2c3;
        size_t base = (size_t)row*64 + l15;
        gout[base] = f2h(g0); gout[base+16] = f2h(g1); gout[base+32] = f2h(g2); gout[base+48] = f2h(g3);
      }
    }
  }
}

// ============================ MFMA GEMM with optional fused secondary GEMM ============================

template<bool RELU, int NRES, bool USEREL, bool GATHER, bool OUT16, bool F16O, int EMODE, bool ERELU>
__global__ __launch_bounds__(256) void k_gemm(
    const ushortT* __restrict__ A, const ushortT* __restrict__ Wt,
    const float* __restrict__ bias, const float* __restrict__ Wr,
    const float* __restrict__ rel, const int* __restrict__ gidx,
    const ushortT* __restrict__ r1, const ushortT* __restrict__ r2,
    ushortT* __restrict__ out16,
    const ushortT* __restrict__ Wt2, const float* __restrict__ bias2,
    const float* __restrict__ Wr2, const float* __restrict__ vec2,
    void* __restrict__ eout,
    int n, int ntiles)
{
  constexpr int LDSZ = (EMODE>0) ? 4*16*LSTR : 4;
  __shared__ ushortT lds[LDSZ];
  int tid = threadIdx.x;
  int lane = tid & 63, wslot = tid >> 6;
  int quad = lane >> 4, l15 = lane & 15;
  int gw = (blockIdx.x*256 + tid) >> 6;
  int nw = (gridDim.x*256) >> 6;

  short8 bfr0_0 = *(const short8*)(Wt + ( 0 + l15)*64 +  0 + quad*8);
  short8 bfr0_1 = *(const short8*)(Wt + ( 0 + l15)*64 + 32 + quad*8);
  short8 bfr1_0 = *(const short8*)(Wt + (16 + l15)*64 +  0 + quad*8);
  short8 bfr1_1 = *(const short8*)(Wt + (16 + l15)*64 + 32 + quad*8);
  short8 bfr2_0 = *(const short8*)(Wt + (32 + l15)*64 +  0 + quad*8);
  short8 bfr2_1 = *(const short8*)(Wt + (32 + l15)*64 + 32 + quad*8);
  short8 bfr3_0 = *(const short8*)(Wt + (48 + l15)*64 +  0 + quad*8);
  short8 bfr3_1 = *(const short8*)(Wt + (48 + l15)*64 + 32 + quad*8);
  float bs0 = bias[ 0 + l15], bs1 = bias[16 + l15];
  float bs2 = bias[32 + l15], bs3 = bias[48 + l15];
  float w0c0=0,w0c1=0,w0c2=0,w0c3=0, w1c0=0,w1c1=0,w1c2=0,w1c3=0, w2c0=0,w2c1=0,w2c2=0,w2c3=0;
  if (USEREL){
    w0c0=Wr[0*64+l15]; w0c1=Wr[0*64+16+l15]; w0c2=Wr[0*64+32+l15]; w0c3=Wr[0*64+48+l15];
    w1c0=Wr[1*64+l15]; w1c1=Wr[1*64+16+l15]; w1c2=Wr[1*64+32+l15]; w1c3=Wr[1*64+48+l15];
    w2c0=Wr[2*64+l15]; w2c1=Wr[2*64+16+l15]; w2c2=Wr[2*64+32+l15]; w2c3=Wr[2*64+48+l15];
  }

  short8 s0_0{}, s0_1{}, s1_0{}, s1_1{}, s2_0{}, s2_1{}, s3_0{}, s3_1{};
  float eb0=0, eb1=0, eb2=0, eb3=0;
  float e0c0=0,e0c1=0,e0c2=0,e0c3=0, e1c0=0,e1c1=0,e1c2=0,e1c3=0, e2c0=0,e2c1=0,e2c2=0,e2c3=0;
  float ebias_c = 0.f;
  if (EMODE == 1){
    s0_0 = *(const short8*)(Wt2 + ( 0 + l15)*64 +  0 + quad*8);
    s0_1 = *(const short8*)(Wt2 + ( 0 + l15)*64 + 32 + quad*8);
    s1_0 = *(const short8*)(Wt2 + (16 + l15)*64 +  0 + quad*8);
    s1_1 = *(const short8*)(Wt2 + (16 + l15)*64 + 32 + quad*8);
    s2_0 = *(const short8*)(Wt2 + (32 + l15)*64 +  0 + quad*8);
    s2_1 = *(const short8*)(Wt2 + (32 + l15)*64 + 32 + quad*8);
    s3_0 = *(const short8*)(Wt2 + (48 + l15)*64 +  0 + quad*8);
    s3_1 = *(const short8*)(Wt2 + (48 + l15)*64 + 32 + quad*8);
    eb0 = bias2[l15]; eb1 = bias2[16+l15]; eb2 = bias2[32+l15]; eb3 = bias2[48+l15];
    e0c0=Wr2[0*64+l15]; e0c1=Wr2[0*64+16+l15]; e0c2=Wr2[0*64+32+l15]; e0c3=Wr2[0*64+48+l15];
    e1c0=Wr2[1*64+l15]; e1c1=Wr2[1*64+16+l15]; e1c2=Wr2[1*64+32+l15]; e1c3=Wr2[1*64+48+l15];
    e2c0=Wr2[2*64+l15]; e2c1=Wr2[2*64+16+l15]; e2c2=Wr2[2*64+32+l15]; e2c3=Wr2[2*64+48+l15];
  } else if (EMODE == 2){
    s0_0 = *(const short8*)(Wt2 + l15*64 +  0 + quad*8);
    s0_1 = *(const short8*)(Wt2 + l15*64 + 32 + quad*8);
    ebias_c = (l15 < 8) ? bias2[l15] : 0.f;
  }

  for (int t=gw; t<ntiles; t+=nw){
    int i0 = t*16;
    int rowA = i0 + l15; if (rowA >= n) rowA = n-1;
    if (GATHER) rowA = gidx[rowA];
    const ushortT* ap = A + (size_t)rowA*64 + quad*8;
    short8 a0 = *(const short8*)(ap);
    short8 a1 = *(const short8*)(ap + 32);
    v4f ac0 = {0.f,0.f,0.f,0.f}, ac1 = ac0, ac2 = ac0, ac3 = ac0;
    ac0 = __builtin_amdgcn_mfma_f32_16x16x32_bf16(a0, bfr0_0, ac0, 0,0,0);
    ac1 = __builtin_amdgcn_mfma_f32_16x16x32_bf16(a0, bfr1_0, ac1, 0,0,0);
    ac2 = __builtin_amdgcn_mfma_f32_16x16x32_bf16(a0, bfr2_0, ac2, 0,0,0);
    ac3 = __builtin_amdgcn_mfma_f32_16x16x32_bf16(a0, bfr3_0, ac3, 0,0,0);
    ac0 = __builtin_amdgcn_mfma_f32_16x16x32_bf16(a1, bfr0_1, ac0, 0,0,0);
    ac1 = __builtin_amdgcn_mfma_f32_16x16x32_bf16(a1, bfr1_1, ac1, 0,0,0);
    ac2 = __builtin_amdgcn_mfma_f32_16x16x32_bf16(a1, bfr2_1, ac2, 0,0,0);
    ac3 = __builtin_amdgcn_mfma_f32_16x16x32_bf16(a1, bfr3_1, ac3, 0,0,0);

    #pragma unroll
    for (int r=0;r<4;++r){
      int row = i0 + quad*4 + r;
      bool rowok = (row < n);
      float rx=0.f, ry=0.f, rz=0.f;
      if (USEREL && rowok){ rx=rel[row*3+0]; ry=rel[row*3+1]; rz=rel[row*3+2]; }
      float v0 = ac0[r] + bs0, v1 = ac1[r] + bs1, v2 = ac2[r] + bs2, v3 = ac3[r] + bs3;
      if (USEREL){
        v0 += rx*w0c0 + ry*w1c0 + rz*w2c0;
        v1 += rx*w0c1 + ry*w1c1 + rz*w2c1;
        v2 += rx*w0c2 + ry*w1c2 + rz*w2c2;
        v3 += rx*w0c3 + ry*w1c3 + rz*w2c3;
      }
      if (RELU){ v0=fmaxf(v0,0.f); v1=fmaxf(v1,0.f); v2=fmaxf(v2,0.f); v3=fmaxf(v3,0.f); }
      size_t base = (size_t)row*64 + l15;
      if (rowok){
        if (NRES>=1){
          v0 += bf2f(r1[base]); v1 += bf2f(r1[base+16]); v2 += bf2f(r1[base+32]); v3 += bf2f(r1[base+48]);
        }
        if (NRES>=2){
          v0 += bf2f(r2[base]); v1 += bf2f(r2[base+16]); v2 += bf2f(r2[base+32]); v3 += bf2f(r2[base+48]);
        }
        if (OUT16){
          if (F16O){
            out16[base] = f2h(v0); out16[base+16] = f2h(v1); out16[base+32] = f2h(v2); out16[base+48] = f2h(v3);
          } else {
            out16[base] = f2bf(v0); out16[base+16] = f2bf(v1); out16[base+32] = f2bf(v2); out16[base+48] = f2bf(v3);
          }
        }
      }
      if (EMODE > 0){
        int lb = wslot*(16*LSTR) + (quad*4+r)*LSTR + l15;
        lds[lb]      = f2bf(v0);
        lds[lb + 16] = f2bf(v1);
        lds[lb + 32] = f2bf(v2);
        lds[lb + 48] = f2bf(v3);
      }
    }

    if (EMODE > 0){
      __builtin_amdgcn_wave_barrier();
      const ushortT* lp = lds + wslot*(16*LSTR) + l15*LSTR + quad*8;
      short8 sa0 = *(const short8*)(lp);
      short8 sa1 = *(const short8*)(lp + 32);
      __builtin_amdgcn_wave_barrier();
      if (EMODE == 1){
        v4f ec0 = {0.f,0.f,0.f,0.f}, ec1 = ec0, ec2 = ec0, ec3 = ec0;
        ec0 = __builtin_amdgcn_mfma_f32_16x16x32_bf16(sa0, s0_0, ec0, 0,0,0);
        ec1 = __builtin_amdgcn_mfma_f32_16x16x32_bf16(sa0, s1_0, ec1, 0,0,0);
        ec2 = __builtin_amdgcn_mfma_f32_16x16x32_bf16(sa0, s2_0, ec2, 0,0,0);
        ec3 = __builtin_amdgcn_mfma_f32_16x16x32_bf16(sa0, s3_0, ec3, 0,0,0);
        ec0 = __builtin_amdgcn_mfma_f32_16x16x32_bf16(sa1, s0_1, ec0, 0,0,0);
        ec1 = __builtin_amdgcn_mfma_f32_16x16x32_bf16(sa1, s1_1, ec1, 0,0,0);
        ec2 = __builtin_amdgcn_mfma_f32_16x16x32_bf16(sa1, s2_1, ec2, 0,0,0);
        ec3 = __builtin_amdgcn_mfma_f32_16x16x32_bf16(sa1, s3_1, ec3, 0,0,0);
        ushortT* eo = (ushortT*)eout;
        #pragma unroll
        for (int r=0;r<4;++r){
          int row = i0 + quad*4 + r;
          if (row < n){
            float vx=vec2[row*3+0], vy=vec2[row*3+1], vz=vec2[row*3+2];
            float g0 = ec0[r] + eb0 + vx*e0c0 + vy*e1c0 + vz*e2c0;
            float g1 = ec1[r] + eb1 + vx*e0c1 + vy*e1c1 + vz*e2c1;
            float g2 = ec2[r] + eb2 + vx*e0c2 + vy*e1c2 + vz*e2c2;
            float g3 = ec3[r] + eb3 + vx*e0c3 + vy*e1c3 + vz*e2c3;
            if (ERELU){ g0=fmaxf(g0,0.f); g1=fmaxf(g1,0.f); g2=fmaxf(g2,0.f); g3=fmaxf(g3,0.f); }
            size_t base = (size_t)row*64 + l15;
            eo[base] = f2h(g0); eo[base+16] = f2h(g1); eo[base+32] = f2h(g2); eo[base+48] = f2h(g3);
          }
        }
      } else {
        v4f ec = {0.f,0.f,0.f,0.f};
        ec = __builtin_amdgcn_mfma_f32_16x16x32_bf16(sa0, s0_0, ec, 0,0,0);
        ec = __builtin_amdgcn_mfma_f32_16x16x32_bf16(sa1, s0_1, ec, 0,0,0);
        if (l15 < 8){
          float* eo = (float*)eout;
          #pragma unroll
          for (int r=0;r<4;++r){
            int row = i0 + quad*4 + r;
            if (row < n) eo[(size_t)row*8 + l15] = ec[r] + ebias_c;
          }
        }
      }
    }
  }
}

// ============================ edge aggregation: 8 dsts/wave, 8 lanes per dst, MLP=16 ============================
// R0 structure (one 128-B fully-coalesced request per edge). Change vs R0: two 8-edge
// batches per round — 2 csr dwords per lane, 16 row-gathers issued before the max chains.

__global__ __launch_bounds__(256) void k_edge_agg(const int* __restrict__ offs, const int* __restrict__ csr,
                                                  const float* __restrict__ pos, const ushortT* __restrict__ g,
                                                  const float* __restrict__ Wp, ushortT* __restrict__ agg, int n){
  int lane = threadIdx.x & 63;
  int grp = lane >> 3, d8 = lane & 7;
  int gbase = lane & 56;
  int gw = (blockIdx.x*256 + threadIdx.x) >> 6;
  int nw = (gridDim.x*256) >> 6;
  const u4v* g4 = (const u4v*)g;
  float2 w0[4], w1[4], w2[4];
  #pragma unroll
  for (int q=0;q<4;++q){
    w0[q] = *(const float2*)(Wp + 0*64 + d8*8 + 2*q);
    w1[q] = *(const float2*)(Wp + 1*64 + d8*8 + 2*q);
    w2[q] = *(const float2*)(Wp + 2*64 + d8*8 + 2*q);
  }
  const h2 NEGBIG = {(_Float16)-60000.f, (_Float16)-60000.f};
  int n8 = (n+7) >> 3;
  for (int ii=gw; ii<n8; ii+=nw){
    int i0 = ii*8;
    int ig = i0 + grp; bool ok = ig < n; if (!ok) ig = n-1;
    int b = offs[ig], e = offs[ig+1];
    int cnt = e - b, c1 = cnt - 1;
    int mx = cnt;
    mx = max(mx, __shfl_xor(mx, 8, 64));
    mx = max(mx, __shfl_xor(mx, 16, 64));
    mx = max(mx, __shfl_xor(mx, 32, 64));
    h2 m0=NEGBIG, m1=NEGBIG, m2=NEGBIG, m3=NEGBIG;
    for (int J=0; J<mx; J+=16){
      if (J < cnt){
        int sva = csr[b + min(J + d8,     c1)];
        int svb = csr[b + min(J + 8 + d8, c1)];
        u4v ua[8], ub[8];
        #pragma unroll
        for (int jj=0; jj<8; ++jj){
          int s = __shfl(sva, gbase + jj, 64);
          ua[jj] = g4[(size_t)s*8 + d8];
        }
        #pragma unroll
        for (int jj=0; jj<8; ++jj){
          int s = __shfl(svb, gbase + jj, 64);
          ub[jj] = g4[(size_t)s*8 + d8];
        }
        #pragma unroll
        for (int jj=0; jj<8; ++jj){
          m0 = pkmax(m0, u2h(ua[jj].x));
          m1 = pkmax(m1, u2h(ua[jj].y));
          m2 = pkmax(m2, u2h(ua[jj].z));
          m3 = pkmax(m3, u2h(ua[jj].w));
        }
        #pragma unroll
        for (int jj=0; jj<8; ++jj){
          m0 = pkmax(m0, u2h(ub[jj].x));
          m1 = pkmax(m1, u2h(ub[jj].y));
          m2 = pkmax(m2, u2h(ub[jj].z));
          m3 = pkmax(m3, u2h(ub[jj].w));
        }
      }
    }
    float px = pos[ig*3+0], py = pos[ig*3+1], pz = pos[ig*3+2];
    u4v outv;
    {
      float sA = w0[0].x*px + w1[0].x*py + w2[0].x*pz;
      float sB = w0[0].y*px + w1[0].y*py + w2[0].y*pz;
      outv.x = (unsigned)f2bf(fmaxf((float)m0.x - sA, 0.f)) |
               ((unsigned)f2bf(fmaxf((float)m0.y - sB, 0.f)) << 16);
    }
    {
      float sA = w0[1].x*px + w1[1].x*py + w2[1].x*pz;
      float sB = w0[1].y*px + w1[1].y*py + w2[1].y*pz;
      outv.y = (unsigned)f2bf(fmaxf((float)m1.x - sA, 0.f)) |
               ((unsigned)f2bf(fmaxf((float)m1.y - sB, 0.f)) << 16);
    }
    {
      float sA = w0[2].x*px + w1[2].x*py + w2[2].x*pz;
      float sB = w0[2].y*px + w1[2].y*py + w2[2].y*pz;
      outv.z = (unsigned)f2bf(fmaxf((float)m2.x - sA, 0.f)) |
               ((unsigned)f2bf(fmaxf((float)m2.y - sB, 0.f)) << 16);
    }
    {
      float sA = w0[3].x*px + w1[3].x*py + w2[3].x*pz;
      float sB = w0[3].y*px + w1[3].y*py + w2[3].y*pz;
      outv.w = (unsigned)f2bf(fmaxf((float)m3.x - sA, 0.f)) |
               ((unsigned)f2bf(fmaxf((float)m3.y - sB, 0.f)) << 16);
    }
    if (ok) ((u4v*)agg)[(size_t)ig*8 + d8] = outv;
  }
}

// ============================ segment sum via label CSR (f16 in, bf16 out) ============================

__global__ __launch_bounds__(256) void k_seg_gather(const int* __restrict__ offs, const int* __restrict__ csr,
                                                    const ushortT* __restrict__ h, ushortT* __restrict__ c, int m){
  int lane = threadIdx.x & 63;
  int wv = (blockIdx.x*256 + threadIdx.x) >> 6;
  if (wv >= m) return;
  int b = offs[wv], e = offs[wv+1];
  float acc = 0.f;
  for (int k=b; k<e; ++k){
    int i = csr[k];
    acc += h2f(h[(size_t)i*64+lane]);
  }
  c[(size_t)wv*64+lane] = f2bf(acc);
}

// ============================ host launcher ============================

extern "C" void kernel_launch(void* const* d_in, const int* in_sizes, int n_in,
                              void* d_out, int out_size, void* d_ws, size_t ws_size,
                              hipStream_t stream){
  const float* features = (const float*)d_in[0];
  const float* points   = (const float*)d_in[1];
  const float* centers  = (const float*)d_in[2];
  const int*   l0e      = (const int*)d_in[3];
  const int*   l1e      = (const int*)d_in[4];
  const int*   labels   = (const int*)d_in[5];
  const float* W_fe = (const float*)d_in[6];
  const float* b_fe = (const float*)d_in[7];
  const float* mWe  = (const float*)d_in[8];
  const float* mbe  = (const float*)d_in[9];
  const float* mWu  = (const float*)d_in[10];
  const float* mbu  = (const float*)d_in[11];
  const float* W_m1 = (const float*)d_in[12];
  const float* b_m1 = (const float*)d_in[13];
  const float* W_m2 = (const float*)d_in[14];
  const float* b_m2 = (const float*)d_in[15];
  const float* gWe  = (const float*)d_in[16];
  const float* gbe  = (const float*)d_in[17];
  const float* gWu  = (const float*)d_in[18];
  const float* gbu  = (const float*)d_in[19];
  const float* W_l  = (const float*)d_in[20];
  const float* b_l  = (const float*)d_in[21];
  const float* W_c  = (const float*)d_in[22];
  const float* b_c  = (const float*)d_in[23];
  float* out = (float*)d_out;

  char* w = (char*)d_ws;
  size_t off = 0;
  auto alloc = [&](size_t bytes)->void*{
    void* p = (void*)(w + off);
    off = (off + bytes + 255) & ~(size_t)255;
    return p;
  };
  float* rel  = (float*)alloc((size_t)N_PTS*3*4);
  ushortT* UF1 = (ushortT*)alloc((size_t)N_PTS*64*2);
  ushortT* UF2 = (ushortT*)alloc((size_t)N_PTS*64*2);
  ushortT* UF21= (ushortT*)alloc((size_t)N_PTS*64*2);
  ushortT* UF5 = (ushortT*)alloc((size_t)N_PTS*64*2);
  ushortT* UF6 = (ushortT*)alloc((size_t)N_PTS*64*2);
  ushortT* gbuf= (ushortT*)alloc((size_t)N_PTS*64*2);
  ushortT* abuf= (ushortT*)alloc((size_t)N_PTS*64*2);
  ushortT* cb_b= (ushortT*)alloc((size_t)M_CL*64*2);
  ushortT* UF3 = (ushortT*)alloc((size_t)M_CL*64*2);
  ushortT* UF4 = (ushortT*)alloc((size_t)M_CL*64*2);
  ushortT* cg_b= (ushortT*)alloc((size_t)M_CL*64*2);
  ushortT* cagg_b = (ushortT*)alloc((size_t)M_CL*64*2);
  ushortT* f41_b  = (ushortT*)alloc((size_t)M_CL*64*2);
  ushortT* wt  = (ushortT*)alloc((size_t)15*4096*2);
  ushortT* wtc = (ushortT*)alloc((size_t)1024*2);
  int* offs0 = (int*)alloc((size_t)(N_PTS+1)*4);
  int* csr0  = (int*)alloc((size_t)E0_N*4);
  int* offs1 = (int*)alloc((size_t)(M_CL+1)*4);
  int* csr1  = (int*)alloc((size_t)E1_N*4);
  int* offsL = (int*)alloc((size_t)(M_CL+1)*4);
  int* csrL  = (int*)alloc((size_t)N_PTS*4);
  unsigned* tmp0 = (unsigned*)alloc((size_t)NB*BCAP0*4);
  unsigned* tmp1 = (unsigned*)alloc((size_t)NB*BCAP1*4);
  unsigned* tmpL = (unsigned*)alloc((size_t)NB*BCAPL*4);
  int* bcur0 = (int*)alloc(NB*4);
  int* bcur1 = (int*)alloc(NB*4);
  int* bcurL = (int*)alloc(NB*4);
  int* bb0   = (int*)alloc(NB*4);
  int* bb1   = (int*)alloc(NB*4);
  int* bbL   = (int*)alloc(NB*4);
  (void)ws_size; (void)in_sizes; (void)n_in; (void)out_size;

  const int NT_N = (N_PTS+15)/16;
  const int NT_M = (M_CL +15)/16;
  const int GBG_N = 1563;
  const int GBG_M = 196;
  const int GB_N  = 3125;

  // ---- setup: weights + counters (1), bin all three lists (1), scan (1), build (1) ----
  WSrc ws{};
  ws.p[0]=mWu+0*4096; ws.p[1]=mWu+1*4096; ws.p[2]=mWu+2*4096; ws.p[3]=mWu+3*4096;
  ws.p[4]=W_m2; ws.p[5]=gWu+0*4096; ws.p[6]=gWu+1*4096;
  ws.p[7]=mWe+0*4288+192; ws.p[8]=mWe+1*4288+192; ws.p[9]=mWe+2*4288+192; ws.p[10]=mWe+3*4288+192;
  ws.p[11]=W_m1; ws.p[12]=W_l; ws.p[13]=gWe+0*4288+192; ws.p[14]=gWe+1*4288+192;
  ws.p[15]=W_c;
  k_init_wprep<<<17, 256, 0, stream>>>(ws, wt, wtc, bcur0, bcur1, bcurL);
  k_bin_all<<<501, 256, 0, stream>>>(l0e, l1e, labels, bcur0, bcur1, bcurL, tmp0, tmp1, tmpL);
  k_scan_all<<<3, 64, 0, stream>>>(bcur0, bb0, offs0+N_PTS, bcur1, bb1, offs1+M_CL, bcurL, bbL, offsL+M_CL);
  k_build_all<<<768, 256, 0, stream>>>(tmp0, bcur0, bb0, offs0, csr0,
                                       tmp1, bcur1, bb1, offs1, csr1,
                                       tmpL, bcurL, bbL, offsL, csrL);

  // ---- FUSED encoder: rel + f1 (bf16) + g0' (f16) ----
  k_f1g<<<GBG_N, 256, 0, stream>>>(features, points, centers, labels, W_fe, b_fe,
      wt+7*4096, mbe+0, mWe+0*4288, rel, UF1, gbuf, N_PTS, NT_N);

  // ---- layer0: agg -> FUSED [f2 -> UF2] + [g1' -> gbuf] ----
  k_edge_agg<<<GB_N,256,0,stream>>>(offs0, csr0, points, gbuf, mWe+0*4288, abuf, N_PTS);
  k_gemm<true,1,false,false,true,false,1,false><<<GBG_N,256,0,stream>>>(abuf, wt+0*4096, mbu+0,
      nullptr, nullptr, nullptr, UF1, nullptr, UF2,
      wt+8*4096, mbe+64, mWe+1*4288, points, gbuf, N_PTS, NT_N);
  // ---- layer1: agg -> FUSED [f2_1 -> UF21] + [h -> gbuf] ----
  k_edge_agg<<<GB_N,256,0,stream>>>(offs0, csr0, points, gbuf, mWe+1*4288, abuf, N_PTS);
  k_gemm<true,1,false,false,true,false,1,true><<<GBG_N,256,0,stream>>>(abuf, wt+1*4096, mbu+64,
      nullptr, nullptr, nullptr, UF2, nullptr, UF21,
      wt+11*4096, b_m1, W_m1+4096, rel, gbuf, N_PTS, NT_N);
  // ---- c = segsum(h); FUSED [f3 -> UF3] + [cg0' -> cg_b] ----
  k_seg_gather<<<(M_CL*64+255)/256, 256, 0, stream>>>(offsL, csrL, gbuf, cb_b, M_CL);
  k_gemm<true,0,false,false,true,false,1,false><<<GBG_M,256,0,stream>>>(cb_b, wt+4*4096, b_m2,
      nullptr, nullptr, nullptr, nullptr, nullptr, UF3,
      wt+13*4096, gbe+0, gWe+0*4288, centers, cg_b, M_CL, NT_M);
  // ---- cluster layer0: agg -> FUSED [f4 -> UF4] + [cg1' -> cg_b] ----
  k_edge_agg<<<GBG_M,256,0,stream>>>(offs1, csr1, centers, cg_b, gWe+0*4288, cagg_b, M_CL);
  k_gemm<true,1,false,false,true,false,1,false><<<GBG_M,256,0,stream>>>(cagg_b, wt+5*4096, gbu+0,
      nullptr, nullptr, nullptr, UF3, nullptr, UF4,
      wt+14*4096, gbe+64, gWe+1*4288, centers, cg_b, M_CL, NT_M);
  // ---- cluster layer1: agg -> f4_1 -> f41_b ----
  k_edge_agg<<<GBG_M,256,0,stream>>>(offs1, csr1, centers, cg_b, gWe+1*4288, cagg_b, M_CL);
  k_gemm<true,1,false,false,true,false,0,false><<<GBG_M,256,0,stream>>>(cagg_b, wt+6*4096, gbu+64,
      nullptr, nullptr, nullptr, UF4, nullptr, f41_b,
      nullptr, nullptr, nullptr, nullptr, nullptr, M_CL, NT_M);
  // ---- FUSED [f5 -> UF5] + [g2' -> gbuf] ----
  k_gemm<true,0,true,true,true,false,1,false><<<GBG_N,256,0,stream>>>(f41_b, wt+12*4096, b_l,
      W_l+4096, rel, labels, nullptr, nullptr, UF5,
      wt+9*4096, mbe+128, mWe+2*4288, points, gbuf, N_PTS, NT_N);
  // ---- layer2: agg -> FUSED [f6 = relu+f5+f2_1 -> UF6] + [g3' -> gbuf] ----
  k_edge_agg<<<GB_N,256,0,stream>>>(offs0, csr0, points, gbuf, mWe+2*4288, abuf, N_PTS);
  k_gemm<true,2,false,false,true,false,1,false><<<GBG_N,256,0,stream>>>(abuf, wt+2*4096, mbu+128,
      nullptr, nullptr, nullptr, UF5, UF21, UF6,
      wt+10*4096, mbe+192, mWe+3*4288, points, gbuf, N_PTS, NT_N);
  // ---- layer3: agg -> FUSED [final = relu+f6+f2] + [out = final@W_c + b_c] ----
  k_edge_agg<<<GB_N,256,0,stream>>>(offs0, csr0, points, gbuf, mWe+3*4288, abuf, N_PTS);
  k_gemm<true,2,false,false,false,false,2,false><<<GBG_N,256,0,stream>>>(abuf, wt+3*4096, mbu+192,
      nullptr, nullptr, nullptr, UF6, UF2, nullptr,
      wtc, b_c, nullptr, nullptr, out, N_PTS, NT_N);
}

// Round 4
// 460.252 us; speedup vs baseline: 1.4170x; 1.0469x over previous
//
#include <hip/hip_runtime.h>

// R4: R0 structure + two changes:
// (1) PERMUTED column storage for all 16-bit activation buffers: physical col
//     p = (c&15)*4 + (c>>4). Each lane's 4 outputs are contiguous -> residual
//     loads / out16 / eout stores / LDS writes become single short4 (8B) ops.
//     Weight prep applies the same K-permutation to B operands (wt/wtc); the
//     agg uses permuted copies of the 3x64 pos-weight rows (wpp). Arithmetic
//     is bit-identical; only storage order changes.
// (2) k_f1g fused into the k_bin_all dispatch (independent work, shared-LDS
//     union) to hide it under the CSR binning phase.
// Agg restored to R0's exact MLP=8 shape (R3 showed MLP=16 neutral -> agg is
// L3 random-line-throughput-bound at ~5.1 TB/s; structural roofline).

#define N_PTS   100000
#define M_CL    12500
#define E0_N    1600000
#define E1_N    400000

#define NB      256
#define BIN_CAP 32
#define RANGE0  391
#define RANGE1  49
#define BCAP0   8192
#define BCAP1   2048
#define BCAPL   1024

#define LSTR    72           // LDS row stride (shorts): 144 B

typedef unsigned short ushortT;
typedef short  short8 __attribute__((ext_vector_type(8)));
typedef short  s4v    __attribute__((ext_vector_type(4)));
typedef float  v4f    __attribute__((ext_vector_type(4)));
typedef _Float16 h2   __attribute__((ext_vector_type(2)));
typedef unsigned u4v  __attribute__((ext_vector_type(4)));

__device__ inline ushortT f2bf(float x){
  union{float f; unsigned u;} v; v.f = x;
  unsigned r = v.u + 0x7fffu + ((v.u >> 16) & 1u);   // RNE
  return (ushortT)(r >> 16);
}
__device__ inline float bf2f(ushortT h){
  union{unsigned u; float f;} v; v.u = ((unsigned)h) << 16;
  return v.f;
}
__device__ inline ushortT f2h(float x){
  union{_Float16 h; ushortT u;} v; v.h = (_Float16)x;
  return v.u;
}
__device__ inline float h2f(ushortT u){
  union{ushortT u; _Float16 h;} v; v.u = u;
  return (float)v.h;
}
__device__ inline h2 pkmax(h2 a, h2 b){ return __builtin_elementwise_max(a, b); }
__device__ inline h2 u2h(unsigned u){ union{unsigned u; h2 h;} v{u}; return v.h; }

// ============================ weight prep + counter init ============================
// K-permutation: physical slot p holds logical k = (p&3)*16 + (p>>2).

struct WSrc { const float* p[22]; };

__global__ __launch_bounds__(256) void k_init_wprep(WSrc s, ushortT* __restrict__ wt, ushortT* __restrict__ wtc,
                                                    float* __restrict__ wpp,
                                                    int* c0, int* c1, int* cL){
  int blk = blockIdx.x;
  if (blk == 0){
    int t = threadIdx.x;
    c0[t] = t*BCAP0; c1[t] = t*BCAP1; cL[t] = t*BCAPL;
    return;
  }
  int slot = blk - 1;
  if (slot < 15){
    const float* src = s.p[slot];
    ushortT* dst = wt + slot*4096;
    for (int e=threadIdx.x; e<4096; e+=256){
      int nn = e>>6, p = e&63;
      int kk = (p&3)*16 + (p>>2);
      dst[e] = f2bf(src[kk*64+nn]);
    }
  } else if (slot == 15){
    const float* src = s.p[15];
    for (int e=threadIdx.x; e<1024; e+=256){
      int nn = e>>6, p = e&63;
      int kk = (p&3)*16 + (p>>2);
      wtc[e] = (nn<8) ? f2bf(src[kk*8+nn]) : (ushortT)0;
    }
  } else {
    // permuted pos-weight rows for the agg epilogue: 6 matrices x 3 rows x 64
    for (int e=threadIdx.x; e<6*192; e+=256){
      int i = e/192, rem = e - i*192, r = rem>>6, p = rem&63;
      wpp[e] = s.p[16+i][r*64 + ((p&3)*16 + (p>>2))];
    }
  }
}

// ============================ bucketed CSR build ============================

template<int RANGE, bool LAB>
__device__ void bin_seg(const int* __restrict__ edges, int E,
                        int* __restrict__ bcur, unsigned* __restrict__ tmp,
                        int bid, int nblk,
                        unsigned* stage, int* scnt, int* sbase){
  int tid = threadIdx.x;
  int nchunks = (E + 2047) / 2048;
  for (int c = bid; c < nchunks; c += nblk){
    int base = c*2048;
    scnt[tid] = 0;
    __syncthreads();
    #pragma unroll
    for (int r=0;r<8;++r){
      int e = base + r*256 + tid;
      if (e < E){
        int s, d;
        if (LAB){ s = e; d = edges[e]; }
        else    { s = edges[2*e]; d = edges[2*e+1]; }
        int bk = d / RANGE;
        unsigned packed = ((unsigned)s << 11) | (unsigned)(d - bk*RANGE);
        int pos = atomicAdd(&scnt[bk], 1);
        if (pos < BIN_CAP) stage[bk*BIN_CAP+pos] = packed;
        else tmp[atomicAdd(&bcur[bk],1)] = packed;
      }
    }
    __syncthreads();
    {
      int nfl = scnt[tid]; if (nfl > BIN_CAP) nfl = BIN_CAP;
      sbase[tid] = atomicAdd(&bcur[tid], nfl);
    }
    __syncthreads();
    int wv = tid >> 6, ln = tid & 63;
    for (int bb=0; bb<32; ++bb){
      int bk = wv*64 + bb*2 + (ln>>5);
      int ent = ln & 31;
      int nf = scnt[bk]; if (nf > BIN_CAP) nf = BIN_CAP;
      if (ent < nf) tmp[sbase[bk]+ent] = stage[bk*BIN_CAP+ent];
    }
    __syncthreads();
  }
}

// exclusive scan of 256 bucket counts
__global__ void k_scan_all(const int* c0, int* bb0, int* e0,
                           const int* c1, int* bb1, int* e1,
                           const int* cL, int* bbL, int* eL){
  const int* cur; int* bb; int* offe; int BC;
  if (blockIdx.x == 0){ cur=c0; bb=bb0; offe=e0; BC=BCAP0; }
  else if (blockIdx.x == 1){ cur=c1; bb=bb1; offe=e1; BC=BCAP1; }
  else { cur=cL; bb=bbL; offe=eL; BC=BCAPL; }
  int lane = threadIdx.x & 63;
  int base = lane*4;
  int v0 = cur[base+0] - (base+0)*BC;
  int v1 = cur[base+1] - (base+1)*BC;
  int v2 = cur[base+2] - (base+2)*BC;
  int v3 = cur[base+3] - (base+3)*BC;
  int psum = v0+v1+v2+v3, sc = psum;
  #pragma unroll
  for (int st=1; st<64; st<<=1){
    int x = __shfl_up(sc, st, 64);
    if (lane >= st) sc += x;
  }
  int ex = sc - psum;
  bb[base+0] = ex;
  bb[base+1] = ex + v0;
  bb[base+2] = ex + v0 + v1;
  bb[base+3] = ex + v0 + v1 + v2;
  if (lane == 63) *offe = sc;
}

template<int RANGE, int BCAP, int K>
__device__ void csr_build_seg(const unsigned* __restrict__ tmp, const int* __restrict__ bcur,
                              const int* __restrict__ bb, int n,
                              int* __restrict__ offs, int* __restrict__ csr,
                              int b, int* hist, int* part){
  int tid = threadIdx.x;
  int dlo = b*RANGE;
  int range = n - dlo; if (range > RANGE) range = RANGE; if (range < 0) range = 0;
  int cnt = bcur[b] - b*BCAP;
  for (int t=tid; t<RANGE; t+=256) hist[t] = 0;
  __syncthreads();
  const unsigned* sl = tmp + (size_t)b*BCAP;
  for (int j=tid; j<cnt; j+=256) atomicAdd(&hist[sl[j] & 2047u], 1);
  __syncthreads();
  int s = 0; int loc[K];
  #pragma unroll
  for (int kk=0; kk<K; ++kk){
    int idx = tid*K + kk;
    int v = (idx < RANGE) ? hist[idx] : 0;
    loc[kk] = s; s += v;
  }
  part[tid] = s; __syncthreads();
  int own = s;
  for (int st=1; st<256; st<<=1){
    int x = (tid >= st) ? part[tid-st] : 0;
    __syncthreads();
    part[tid] += x;
    __syncthreads();
  }
  int ebase = part[tid] - own;
  int gb = bb[b];
  __syncthreads();
  #pragma unroll
  for (int kk=0; kk<K; ++kk){
    int idx = tid*K + kk;
    if (idx < RANGE){
      int ex = ebase + loc[kk];
      if (idx < range) offs[dlo+idx] = gb + ex;
      hist[idx] = ex;
    }
  }
  __syncthreads();
  for (int j=tid; j<cnt; j+=256){
    unsigned p = sl[j];
    int pos = atomicAdd(&hist[p & 2047u], 1);
    csr[gb + pos] = (int)(p >> 11);
  }
}

__global__ __launch_bounds__(256) void k_build_all(
    const unsigned* t0, const int* bc0, const int* bb0, int* offs0, int* csr0,
    const unsigned* t1, const int* bc1, const int* bb1, int* offs1, int* csr1,
    const unsigned* tL, const int* bcL, const int* bbL, int* offsL, int* csrL){
  __shared__ int hist[RANGE0];
  __shared__ int part[256];
  int b = blockIdx.x;
  if (b < 256)      csr_build_seg<RANGE0,BCAP0,2>(t0, bc0, bb0, N_PTS, offs0, csr0, b, hist, part);
  else if (b < 512) csr_build_seg<RANGE1,BCAP1,1>(t1, bc1, bb1, M_CL, offs1, csr1, b-256, hist, part);
  else              csr_build_seg<RANGE1,BCAPL,1>(tL, bcL, bbL, M_CL, offsL, csrL, b-512, hist, part);
}

// ============================ FUSED: CSR binning (blocks 0..500) + f1g encoder (blocks 501+) ============================

__global__ __launch_bounds__(256) void k_bin_f1g(
    const int* __restrict__ l0e, const int* __restrict__ l1e, const int* __restrict__ labels,
    int* bc0, int* bc1, int* bcL,
    unsigned* t0, unsigned* t1, unsigned* tL,
    const float* __restrict__ features, const float* __restrict__ points,
    const float* __restrict__ centers,
    const float* __restrict__ W, const float* __restrict__ bfe,
    const ushortT* __restrict__ Wt2, const float* __restrict__ bias2,
    const float* __restrict__ Wr2,
    float* __restrict__ rel, ushortT* __restrict__ f1b,
    ushortT* __restrict__ gout, int n, int ntiles, int nf1blk)
{
  __shared__ char smem[34816];
  int b = blockIdx.x;
  if (b < 501){
    unsigned* stage = (unsigned*)smem;
    int* scnt = (int*)(smem + 32768);
    int* sbase = (int*)(smem + 33792);
    if (b < 256)      bin_seg<RANGE0,false>(l0e, E0_N, bc0, t0, b, 256, stage, scnt, sbase);
    else if (b < 452) bin_seg<RANGE1,false>(l1e, E1_N, bc1, t1, b-256, 196, stage, scnt, sbase);
    else              bin_seg<RANGE1,true >(labels, N_PTS, bcL, tL, b-452, 49, stage, scnt, sbase);
    return;
  }
  // ---- f1g: rel + f1 (bf16, permuted cols) + g0' (f16, permuted cols) ----
  ushortT* lds = (ushortT*)smem;
  int bb = b - 501;
  int tid = threadIdx.x;
  int lane = tid & 63, wslot = tid >> 6;
  int quad = lane >> 4, l15 = lane & 15;
  int permL = (lane & 15)*4 + (lane >> 4);   // physical slot of logical col `lane`
  int gw = (bb*256 + tid) >> 6;
  int nw = (nf1blk*256) >> 6;
  float Wf0=W[0*64+lane], Wf1=W[1*64+lane], Wf2=W[2*64+lane], Wf3=W[3*64+lane];
  float wr0=W[4*64+lane], wr1=W[5*64+lane], wr2=W[6*64+lane];
  float bias=bfe[lane];
  short8 s0_0 = *(const short8*)(Wt2 + ( 0 + l15)*64 +  0 + quad*8);
  short8 s0_1 = *(const short8*)(Wt2 + ( 0 + l15)*64 + 32 + quad*8);
  short8 s1_0 = *(const short8*)(Wt2 + (16 + l15)*64 +  0 + quad*8);
  short8 s1_1 = *(const short8*)(Wt2 + (16 + l15)*64 + 32 + quad*8);
  short8 s2_0 = *(const short8*)(Wt2 + (32 + l15)*64 +  0 + quad*8);
  short8 s2_1 = *(const short8*)(Wt2 + (32 + l15)*64 + 32 + quad*8);
  short8 s3_0 = *(const short8*)(Wt2 + (48 + l15)*64 +  0 + quad*8);
  short8 s3_1 = *(const short8*)(Wt2 + (48 + l15)*64 + 32 + quad*8);
  float eb0 = bias2[l15], eb1 = bias2[16+l15], eb2 = bias2[32+l15], eb3 = bias2[48+l15];
  float e0c0=Wr2[0*64+l15], e0c1=Wr2[0*64+16+l15], e0c2=Wr2[0*64+32+l15], e0c3=Wr2[0*64+48+l15];
  float e1c0=Wr2[1*64+l15], e1c1=Wr2[1*64+16+l15], e1c2=Wr2[1*64+32+l15], e1c3=Wr2[1*64+48+l15];
  float e2c0=Wr2[2*64+l15], e2c1=Wr2[2*64+16+l15], e2c2=Wr2[2*64+32+l15], e2c3=Wr2[2*64+48+l15];

  for (int t=gw; t<ntiles; t+=nw){
    int i0 = t*16;
    for (int r=0;r<16;++r){
      int row = i0 + r;
      bool ok = row < n;
      int rr = ok ? row : n-1;
      int lb = labels[rr];
      float rx = points[rr*3+0]-centers[lb*3+0];
      float ry = points[rr*3+1]-centers[lb*3+1];
      float rz = points[rr*3+2]-centers[lb*3+2];
      float acc = bias + wr0*rx + wr1*ry + wr2*rz;
      acc += features[rr*4+0]*Wf0 + features[rr*4+1]*Wf1;
      acc += features[rr*4+2]*Wf2 + features[rr*4+3]*Wf3;
      acc = fmaxf(acc, 0.f);
      ushortT ab = f2bf(acc);
      if (ok){
        f1b[(size_t)row*64 + permL] = ab;
        if (lane==0){ rel[row*3+0]=rx; rel[row*3+1]=ry; rel[row*3+2]=rz; }
      }
      lds[wslot*(16*LSTR) + r*LSTR + permL] = ab;
    }
    __builtin_amdgcn_wave_barrier();
    const ushortT* lp = lds + wslot*(16*LSTR) + l15*LSTR + quad*8;
    short8 sa0 = *(const short8*)(lp);
    short8 sa1 = *(const short8*)(lp + 32);
    __builtin_amdgcn_wave_barrier();
    v4f ec0 = {0.f,0.f,0.f,0.f}, ec1 = ec0, ec2 = ec0, ec3 = ec0;
    ec0 = __builtin_amdgcn_mfma_f32_16x16x32_bf16(sa0, s0_0, ec0, 0,0,0);
    ec1 = __builtin_amdgcn_mfma_f32_16x16x32_bf16(sa0, s1_0, ec1, 0,0,0);
    ec2 = __builtin_amdgcn_mfma_f32_16x16x32_bf16(sa0, s2_0, ec2, 0,0,0);
    ec3 = __builtin_amdgcn_mfma_f32_16x16x32_bf16(sa0, s3_0, ec3, 0,0,0);
    ec0 = __builtin_amdgcn_mfma_f32_16x16x32_bf16(sa1, s0_1, ec0, 0,0,0);
    ec1 = __builtin_amdgcn_mfma_f32_16x16x32_bf16(sa1, s1_1, ec1, 0,0,0);
    ec2 = __builtin_amdgcn_mfma_f32_16x16x32_bf16(sa1, s2_1, ec2, 0,0,0);
    ec3 = __builtin_amdgcn_mfma_f32_16x16x32_bf16(sa1, s3_1, ec3, 0,0,0);
    #pragma unroll
    for (int r=0;r<4;++r){
      int row = i0 + quad*4 + r;
      if (row < n){
        float vx=points[row*3+0], vy=points[row*3+1], vz=points[row*3+2];
        float g0 = ec0[r] + eb0 + vx*e0c0 + vy*e1c0 + vz*e2c0;
        float g1 = ec1[r] + eb1 + vx*e0c1 + vy*e1c1 + vz*e2c1;
        float g2 = ec2[r] + eb2 + vx*e0c2 + vy*e1c2 + vz*e2c2;
        float g3 = ec3[r] + eb3 + vx*e0c3 + vy*e1c3 + vz*e2c3;
        s4v o; o.x=(short)f2h(g0); o.y=(short)f2h(g1); o.z=(short)f2h(g2); o.w=(short)f2h(g3);
        *(s4v*)(gout + (size_t)row*64 + l15*4) = o;
      }
    }
  }
}

// ============================ MFMA GEMM with optional fused secondary GEMM ============================
// All 16-bit activation buffers in permuted layout: phys p holds logical (p&3)*16+(p>>4... (p>>2)).
// Lane (quad,l15): accumulators v0..v3 are logical cols {0,16,32,48}+l15 -> stored at phys l15*4+{0..3}.

template<bool RELU, int NRES, bool USEREL, bool GATHER, bool OUT16, bool F16O, int EMODE, bool ERELU>
__global__ __launch_bounds__(256) void k_gemm(
    const ushortT* __restrict__ A, const ushortT* __restrict__ Wt,
    const float* __restrict__ bias, const float* __restrict__ Wr,
    const float* __restrict__ rel, const int* __restrict__ gidx,
    const ushortT* __restrict__ r1, const ushortT* __restrict__ r2,
    ushortT* __restrict__ out16,
    const ushortT* __restrict__ Wt2, const float* __restrict__ bias2,
    const float* __restrict__ Wr2, const float* __restrict__ vec2,
    void* __restrict__ eout,
    int n, int ntiles)
{
  constexpr int LDSZ = (EMODE>0) ? 4*16*LSTR : 4;
  __shared__ ushortT lds[LDSZ];
  int tid = threadIdx.x;
  int lane = tid & 63, wslot = tid >> 6;
  int quad = lane >> 4, l15 = lane & 15;
  int gw = (blockIdx.x*256 + tid) >> 6;
  int nw = (gridDim.x*256) >> 6;

  short8 bfr0_0 = *(const short8*)(Wt + ( 0 + l15)*64 +  0 + quad*8);
  short8 bfr0_1 = *(const short8*)(Wt + ( 0 + l15)*64 + 32 + quad*8);
  short8 bfr1_0 = *(const short8*)(Wt + (16 + l15)*64 +  0 + quad*8);
  short8 bfr1_1 = *(const short8*)(Wt + (16 + l15)*64 + 32 + quad*8);
  short8 bfr2_0 = *(const short8*)(Wt + (32 + l15)*64 +  0 + quad*8);
  short8 bfr2_1 = *(const short8*)(Wt + (32 + l15)*64 + 32 + quad*8);
  short8 bfr3_0 = *(const short8*)(Wt + (48 + l15)*64 +  0 + quad*8);
  short8 bfr3_1 = *(const short8*)(Wt + (48 + l15)*64 + 32 + quad*8);
  float bs0 = bias[ 0 + l15], bs1 = bias[16 + l15];
  float bs2 = bias[32 + l15], bs3 = bias[48 + l15];
  float w0c0=0,w0c1=0,w0c2=0,w0c3=0, w1c0=0,w1c1=0,w1c2=0,w1c3=0, w2c0=0,w2c1=0,w2c2=0,w2c3=0;
  if (USEREL){
    w0c0=Wr[0*64+l15]; w0c1=Wr[0*64+16+l15]; w0c2=Wr[0*64+32+l15]; w0c3=Wr[0*64+48+l15];
    w1c0=Wr[1*64+l15]; w1c1=Wr[1*64+16+l15]; w1c2=Wr[1*64+32+l15]; w1c3=Wr[1*64+48+l15];
    w2c0=Wr[2*64+l15]; w2c1=Wr[2*64+16+l15]; w2c2=Wr[2*64+32+l15]; w2c3=Wr[2*64+48+l15];
  }

  short8 s0_0{}, s0_1{}, s1_0{}, s1_1{}, s2_0{}, s2_1{}, s3_0{}, s3_1{};
  float eb0=0, eb1=0, eb2=0, eb3=0;
  float e0c0=0,e0c1=0,e0c2=0,e0c3=0, e1c0=0,e1c1=0,e1c2=0,e1c3=0, e2c0=0,e2c1=0,e2c2=0,e2c3=0;
  float ebias_c = 0.f;
  if (EMODE == 1){
    s0_0 = *(const short8*)(Wt2 + ( 0 + l15)*64 +  0 + quad*8);
    s0_1 = *(const short8*)(Wt2 + ( 0 + l15)*64 + 32 + quad*8);
    s1_0 = *(const short8*)(Wt2 + (16 + l15)*64 +  0 + quad*8);
    s1_1 = *(const short8*)(Wt2 + (16 + l15)*64 + 32 + quad*8);
    s2_0 = *(const short8*)(Wt2 + (32 + l15)*64 +  0 + quad*8);
    s2_1 = *(const short8*)(Wt2 + (32 + l15)*64 + 32 + quad*8);
    s3_0 = *(const short8*)(Wt2 + (48 + l15)*64 +  0 + quad*8);
    s3_1 = *(const short8*)(Wt2 + (48 + l15)*64 + 32 + quad*8);
    eb0 = bias2[l15]; eb1 = bias2[16+l15]; eb2 = bias2[32+l15]; eb3 = bias2[48+l15];
    e0c0=Wr2[0*64+l15]; e0c1=Wr2[0*64+16+l15]; e0c2=Wr2[0*64+32+l15]; e0c3=Wr2[0*64+48+l15];
    e1c0=Wr2[1*64+l15]; e1c1=Wr2[1*64+16+l15]; e1c2=Wr2[1*64+32+l15]; e1c3=Wr2[1*64+48+l15];
    e2c0=Wr2[2*64+l15]; e2c1=Wr2[2*64+16+l15]; e2c2=Wr2[2*64+32+l15]; e2c3=Wr2[2*64+48+l15];
  } else if (EMODE == 2){
    s0_0 = *(const short8*)(Wt2 + l15*64 +  0 + quad*8);
    s0_1 = *(const short8*)(Wt2 + l15*64 + 32 + quad*8);
    ebias_c = (l15 < 8) ? bias2[l15] : 0.f;
  }

  for (int t=gw; t<ntiles; t+=nw){
    int i0 = t*16;
    int rowA = i0 + l15; if (rowA >= n) rowA = n-1;
    if (GATHER) rowA = gidx[rowA];
    const ushortT* ap = A + (size_t)rowA*64 + quad*8;
    short8 a0 = *(const short8*)(ap);
    short8 a1 = *(const short8*)(ap + 32);
    v4f ac0 = {0.f,0.f,0.f,0.f}, ac1 = ac0, ac2 = ac0, ac3 = ac0;
    ac0 = __builtin_amdgcn_mfma_f32_16x16x32_bf16(a0, bfr0_0, ac0, 0,0,0);
    ac1 = __builtin_amdgcn_mfma_f32_16x16x32_bf16(a0, bfr1_0, ac1, 0,0,0);
    ac2 = __builtin_amdgcn_mfma_f32_16x16x32_bf16(a0, bfr2_0, ac2, 0,0,0);
    ac3 = __builtin_amdgcn_mfma_f32_16x16x32_bf16(a0, bfr3_0, ac3, 0,0,0);
    ac0 = __builtin_amdgcn_mfma_f32_16x16x32_bf16(a1, bfr0_1, ac0, 0,0,0);
    ac1 = __builtin_amdgcn_mfma_f32_16x16x32_bf16(a1, bfr1_1, ac1, 0,0,0);
    ac2 = __builtin_amdgcn_mfma_f32_16x16x32_bf16(a1, bfr2_1, ac2, 0,0,0);
    ac3 = __builtin_amdgcn_mfma_f32_16x16x32_bf16(a1, bfr3_1, ac3, 0,0,0);

    #pragma unroll
    for (int r=0;r<4;++r){
      int row = i0 + quad*4 + r;
      bool rowok = (row < n);
      float rx=0.f, ry=0.f, rz=0.f;
      if (USEREL && rowok){ rx=rel[row*3+0]; ry=rel[row*3+1]; rz=rel[row*3+2]; }
      float v0 = ac0[r] + bs0, v1 = ac1[r] + bs1, v2 = ac2[r] + bs2, v3 = ac3[r] + bs3;
      if (USEREL){
        v0 += rx*w0c0 + ry*w1c0 + rz*w2c0;
        v1 += rx*w0c1 + ry*w1c1 + rz*w2c1;
        v2 += rx*w0c2 + ry*w1c2 + rz*w2c2;
        v3 += rx*w0c3 + ry*w1c3 + rz*w2c3;
      }
      if (RELU){ v0=fmaxf(v0,0.f); v1=fmaxf(v1,0.f); v2=fmaxf(v2,0.f); v3=fmaxf(v3,0.f); }
      size_t pb = (size_t)row*64 + l15*4;
      if (rowok){
        if (NRES>=1){
          s4v rv = *(const s4v*)(r1 + pb);
          v0 += bf2f((ushortT)rv.x); v1 += bf2f((ushortT)rv.y);
          v2 += bf2f((ushortT)rv.z); v3 += bf2f((ushortT)rv.w);
        }
        if (NRES>=2){
          s4v rv = *(const s4v*)(r2 + pb);
          v0 += bf2f((ushortT)rv.x); v1 += bf2f((ushortT)rv.y);
          v2 += bf2f((ushortT)rv.z); v3 += bf2f((ushortT)rv.w);
        }
        if (OUT16){
          s4v o;
          if (F16O){ o.x=(short)f2h(v0); o.y=(short)f2h(v1); o.z=(short)f2h(v2); o.w=(short)f2h(v3); }
          else     { o.x=(short)f2bf(v0); o.y=(short)f2bf(v1); o.z=(short)f2bf(v2); o.w=(short)f2bf(v3); }
          *(s4v*)(out16 + pb) = o;
        }
      }
      if (EMODE > 0){
        int lb = wslot*(16*LSTR) + (quad*4+r)*LSTR + l15*4;
        s4v o; o.x=(short)f2bf(v0); o.y=(short)f2bf(v1); o.z=(short)f2bf(v2); o.w=(short)f2bf(v3);
        *(s4v*)(lds + lb) = o;
      }
    }

    if (EMODE > 0){
      __builtin_amdgcn_wave_barrier();
      const ushortT* lp = lds + wslot*(16*LSTR) + l15*LSTR + quad*8;
      short8 sa0 = *(const short8*)(lp);
      short8 sa1 = *(const short8*)(lp + 32);
      __builtin_amdgcn_wave_barrier();
      if (EMODE == 1){
        v4f ec0 = {0.f,0.f,0.f,0.f}, ec1 = ec0, ec2 = ec0, ec3 = ec0;
        ec0 = __builtin_amdgcn_mfma_f32_16x16x32_bf16(sa0, s0_0, ec0, 0,0,0);
        ec1 = __builtin_amdgcn_mfma_f32_16x16x32_bf16(sa0, s1_0, ec1, 0,0,0);
        ec2 = __builtin_amdgcn_mfma_f32_16x16x32_bf16(sa0, s2_0, ec2, 0,0,0);
        ec3 = __builtin_amdgcn_mfma_f32_16x16x32_bf16(sa0, s3_0, ec3, 0,0,0);
        ec0 = __builtin_amdgcn_mfma_f32_16x16x32_bf16(sa1, s0_1, ec0, 0,0,0);
        ec1 = __builtin_amdgcn_mfma_f32_16x16x32_bf16(sa1, s1_1, ec1, 0,0,0);
        ec2 = __builtin_amdgcn_mfma_f32_16x16x32_bf16(sa1, s2_1, ec2, 0,0,0);
        ec3 = __builtin_amdgcn_mfma_f32_16x16x32_bf16(sa1, s3_1, ec3, 0,0,0);
        ushortT* eo = (ushortT*)eout;
        #pragma unroll
        for (int r=0;r<4;++r){
          int row = i0 + quad*4 + r;
          if (row < n){
            float vx=vec2[row*3+0], vy=vec2[row*3+1], vz=vec2[row*3+2];
            float g0 = ec0[r] + eb0 + vx*e0c0 + vy*e1c0 + vz*e2c0;
            float g1 = ec1[r] + eb1 + vx*e0c1 + vy*e1c1 + vz*e2c1;
            float g2 = ec2[r] + eb2 + vx*e0c2 + vy*e1c2 + vz*e2c2;
            float g3 = ec3[r] + eb3 + vx*e0c3 + vy*e1c3 + vz*e2c3;
            if (ERELU){ g0=fmaxf(g0,0.f); g1=fmaxf(g1,0.f); g2=fmaxf(g2,0.f); g3=fmaxf(g3,0.f); }
            s4v o; o.x=(short)f2h(g0); o.y=(short)f2h(g1); o.z=(short)f2h(g2); o.w=(short)f2h(g3);
            *(s4v*)(eo + (size_t)row*64 + l15*4) = o;
          }
        }
      } else {
        v4f ec = {0.f,0.f,0.f,0.f};
        ec = __builtin_amdgcn_mfma_f32_16x16x32_bf16(sa0, s0_0, ec, 0,0,0);
        ec = __builtin_amdgcn_mfma_f32_16x16x32_bf16(sa1, s0_1, ec, 0,0,0);
        if (l15 < 8){
          float* eo = (float*)eout;
          #pragma unroll
          for (int r=0;r<4;++r){
            int row = i0 + quad*4 + r;
            if (row < n) eo[(size_t)row*8 + l15] = ec[r] + ebias_c;
          }
        }
      }
    }
  }
}

// ============================ edge aggregation: 8 dsts/wave, 8 lanes per dst (R0 shape) ============================
// Wp is the PERMUTED 3x64 pos-weight block (wpp), matching the permuted column storage.

__global__ __launch_bounds__(256) void k_edge_agg(const int* __restrict__ offs, const int* __restrict__ csr,
                                                  const float* __restrict__ pos, const ushortT* __restrict__ g,
                                                  const float* __restrict__ Wp, ushortT* __restrict__ agg, int n){
  int lane = threadIdx.x & 63;
  int grp = lane >> 3, d8 = lane & 7;
  int gbase = lane & 56;
  int gw = (blockIdx.x*256 + threadIdx.x) >> 6;
  int nw = (gridDim.x*256) >> 6;
  const u4v* g4 = (const u4v*)g;
  float2 w0[4], w1[4], w2[4];
  #pragma unroll
  for (int q=0;q<4;++q){
    w0[q] = *(const float2*)(Wp + 0*64 + d8*8 + 2*q);
    w1[q] = *(const float2*)(Wp + 1*64 + d8*8 + 2*q);
    w2[q] = *(const float2*)(Wp + 2*64 + d8*8 + 2*q);
  }
  const h2 NEGBIG = {(_Float16)-60000.f, (_Float16)-60000.f};
  int n8 = (n+7) >> 3;
  for (int ii=gw; ii<n8; ii+=nw){
    int i0 = ii*8;
    int ig = i0 + grp; bool ok = ig < n; if (!ok) ig = n-1;
    int b = offs[ig], e = offs[ig+1];
    int cnt = e - b, c1 = cnt - 1;
    int mx = cnt;
    mx = max(mx, __shfl_xor(mx, 8, 64));
    mx = max(mx, __shfl_xor(mx, 16, 64));
    mx = max(mx, __shfl_xor(mx, 32, 64));
    h2 m0=NEGBIG, m1=NEGBIG, m2=NEGBIG, m3=NEGBIG;
    for (int J=0; J<mx; J+=8){
      if (J < cnt){
        int sv = csr[b + min(J + d8, c1)];
        #pragma unroll
        for (int jj=0; jj<8; ++jj){
          int s = __shfl(sv, gbase + jj, 64);
          u4v u = g4[(size_t)s*8 + d8];
          m0 = pkmax(m0, u2h(u.x));
          m1 = pkmax(m1, u2h(u.y));
          m2 = pkmax(m2, u2h(u.z));
          m3 = pkmax(m3, u2h(u.w));
        }
      }
    }
    float px = pos[ig*3+0], py = pos[ig*3+1], pz = pos[ig*3+2];
    u4v outv;
    {
      float sA = w0[0].x*px + w1[0].x*py + w2[0].x*pz;
      float sB = w0[0].y*px + w1[0].y*py + w2[0].y*pz;
      outv.x = (unsigned)f2bf(fmaxf((float)m0.x - sA, 0.f)) |
               ((unsigned)f2bf(fmaxf((float)m0.y - sB, 0.f)) << 16);
    }
    {
      float sA = w0[1].x*px + w1[1].x*py + w2[1].x*pz;
      float sB = w0[1].y*px + w1[1].y*py + w2[1].y*pz;
      outv.y = (unsigned)f2bf(fmaxf((float)m1.x - sA, 0.f)) |
               ((unsigned)f2bf(fmaxf((float)m1.y - sB, 0.f)) << 16);
    }
    {
      float sA = w0[2].x*px + w1[2].x*py + w2[2].x*pz;
      float sB = w0[2].y*px + w1[2].y*py + w2[2].y*pz;
      outv.z = (unsigned)f2bf(fmaxf((float)m2.x - sA, 0.f)) |
               ((unsigned)f2bf(fmaxf((float)m2.y - sB, 0.f)) << 16);
    }
    {
      float sA = w0[3].x*px + w1[3].x*py + w2[3].x*pz;
      float sB = w0[3].y*px + w1[3].y*py + w2[3].y*pz;
      outv.w = (unsigned)f2bf(fmaxf((float)m3.x - sA, 0.f)) |
               ((unsigned)f2bf(fmaxf((float)m3.y - sB, 0.f)) << 16);
    }
    if (ok) ((u4v*)agg)[(size_t)ig*8 + d8] = outv;
  }
}

// ============================ segment sum via label CSR (f16 in, bf16 out) ============================
// Column-preserving element-wise op: works identically on permuted layout.

__global__ __launch_bounds__(256) void k_seg_gather(const int* __restrict__ offs, const int* __restrict__ csr,
                                                    const ushortT* __restrict__ h, ushortT* __restrict__ c, int m){
  int lane = threadIdx.x & 63;
  int wv = (blockIdx.x*256 + threadIdx.x) >> 6;
  if (wv >= m) return;
  int b = offs[wv], e = offs[wv+1];
  float acc = 0.f;
  for (int k=b; k<e; ++k){
    int i = csr[k];
    acc += h2f(h[(size_t)i*64+lane]);
  }
  c[(size_t)wv*64+lane] = f2bf(acc);
}

// ============================ host launcher ============================

extern "C" void kernel_launch(void* const* d_in, const int* in_sizes, int n_in,
                              void* d_out, int out_size, void* d_ws, size_t ws_size,
                              hipStream_t stream){
  const float* features = (const float*)d_in[0];
  const float* points   = (const float*)d_in[1];
  const float* centers  = (const float*)d_in[2];
  const int*   l0e      = (const int*)d_in[3];
  const int*   l1e      = (const int*)d_in[4];
  const int*   labels   = (const int*)d_in[5];
  const float* W_fe = (const float*)d_in[6];
  const float* b_fe = (const float*)d_in[7];
  const float* mWe  = (const float*)d_in[8];
  const float* mbe  = (const float*)d_in[9];
  const float* mWu  = (const float*)d_in[10];
  const float* mbu  = (const float*)d_in[11];
  const float* W_m1 = (const float*)d_in[12];
  const float* b_m1 = (const float*)d_in[13];
  const float* W_m2 = (const float*)d_in[14];
  const float* b_m2 = (const float*)d_in[15];
  const float* gWe  = (const float*)d_in[16];
  const float* gbe  = (const float*)d_in[17];
  const float* gWu  = (const float*)d_in[18];
  const float* gbu  = (const float*)d_in[19];
  const float* W_l  = (const float*)d_in[20];
  const float* b_l  = (const float*)d_in[21];
  const float* W_c  = (const float*)d_in[22];
  const float* b_c  = (const float*)d_in[23];
  float* out = (float*)d_out;

  char* w = (char*)d_ws;
  size_t off = 0;
  auto alloc = [&](size_t bytes)->void*{
    void* p = (void*)(w + off);
    off = (off + bytes + 255) & ~(size_t)255;
    return p;
  };
  float* rel  = (float*)alloc((size_t)N_PTS*3*4);
  ushortT* UF1 = (ushortT*)alloc((size_t)N_PTS*64*2);
  ushortT* UF2 = (ushortT*)alloc((size_t)N_PTS*64*2);
  ushortT* UF21= (ushortT*)alloc((size_t)N_PTS*64*2);
  ushortT* UF5 = (ushortT*)alloc((size_t)N_PTS*64*2);
  ushortT* UF6 = (ushortT*)alloc((size_t)N_PTS*64*2);
  ushortT* gbuf= (ushortT*)alloc((size_t)N_PTS*64*2);
  ushortT* abuf= (ushortT*)alloc((size_t)N_PTS*64*2);
  ushortT* cb_b= (ushortT*)alloc((size_t)M_CL*64*2);
  ushortT* UF3 = (ushortT*)alloc((size_t)M_CL*64*2);
  ushortT* UF4 = (ushortT*)alloc((size_t)M_CL*64*2);
  ushortT* cg_b= (ushortT*)alloc((size_t)M_CL*64*2);
  ushortT* cagg_b = (ushortT*)alloc((size_t)M_CL*64*2);
  ushortT* f41_b  = (ushortT*)alloc((size_t)M_CL*64*2);
  ushortT* wt  = (ushortT*)alloc((size_t)15*4096*2);
  ushortT* wtc = (ushortT*)alloc((size_t)1024*2);
  float* wpp = (float*)alloc((size_t)6*192*4);
  int* offs0 = (int*)alloc((size_t)(N_PTS+1)*4);
  int* csr0  = (int*)alloc((size_t)E0_N*4);
  int* offs1 = (int*)alloc((size_t)(M_CL+1)*4);
  int* csr1  = (int*)alloc((size_t)E1_N*4);
  int* offsL = (int*)alloc((size_t)(M_CL+1)*4);
  int* csrL  = (int*)alloc((size_t)N_PTS*4);
  unsigned* tmp0 = (unsigned*)alloc((size_t)NB*BCAP0*4);
  unsigned* tmp1 = (unsigned*)alloc((size_t)NB*BCAP1*4);
  unsigned* tmpL = (unsigned*)alloc((size_t)NB*BCAPL*4);
  int* bcur0 = (int*)alloc(NB*4);
  int* bcur1 = (int*)alloc(NB*4);
  int* bcurL = (int*)alloc(NB*4);
  int* bb0   = (int*)alloc(NB*4);
  int* bb1   = (int*)alloc(NB*4);
  int* bbL   = (int*)alloc(NB*4);
  (void)ws_size; (void)in_sizes; (void)n_in; (void)out_size;

  const int NT_N = (N_PTS+15)/16;
  const int NT_M = (M_CL +15)/16;
  const int GBG_N = 1563;
  const int GBG_M = 196;
  const int GB_N  = 3125;

  // ---- setup: weights(K-permuted) + wpp + counters (1), bin+f1g fused (1), scan (1), build (1) ----
  WSrc ws{};
  ws.p[0]=mWu+0*4096; ws.p[1]=mWu+1*4096; ws.p[2]=mWu+2*4096; ws.p[3]=mWu+3*4096;
  ws.p[4]=W_m2; ws.p[5]=gWu+0*4096; ws.p[6]=gWu+1*4096;
  ws.p[7]=mWe+0*4288+192; ws.p[8]=mWe+1*4288+192; ws.p[9]=mWe+2*4288+192; ws.p[10]=mWe+3*4288+192;
  ws.p[11]=W_m1; ws.p[12]=W_l; ws.p[13]=gWe+0*4288+192; ws.p[14]=gWe+1*4288+192;
  ws.p[15]=W_c;
  ws.p[16]=mWe+0*4288; ws.p[17]=mWe+1*4288; ws.p[18]=mWe+2*4288; ws.p[19]=mWe+3*4288;
  ws.p[20]=gWe+0*4288; ws.p[21]=gWe+1*4288;
  k_init_wprep<<<18, 256, 0, stream>>>(ws, wt, wtc, wpp, bcur0, bcur1, bcurL);
  k_bin_f1g<<<501 + GBG_N, 256, 0, stream>>>(l0e, l1e, labels, bcur0, bcur1, bcurL, tmp0, tmp1, tmpL,
      features, points, centers, W_fe, b_fe,
      wt+7*4096, mbe+0, mWe+0*4288, rel, UF1, gbuf, N_PTS, NT_N, GBG_N);
  k_scan_all<<<3, 64, 0, stream>>>(bcur0, bb0, offs0+N_PTS, bcur1, bb1, offs1+M_CL, bcurL, bbL, offsL+M_CL);
  k_build_all<<<768, 256, 0, stream>>>(tmp0, bcur0, bb0, offs0, csr0,
                                       tmp1, bcur1, bb1, offs1, csr1,
                                       tmpL, bcurL, bbL, offsL, csrL);

  // ---- layer0: agg -> FUSED [f2 -> UF2] + [g1' -> gbuf] ----
  k_edge_agg<<<GB_N,256,0,stream>>>(offs0, csr0, points, gbuf, wpp+0*192, abuf, N_PTS);
  k_gemm<true,1,false,false,true,false,1,false><<<GBG_N,256,0,stream>>>(abuf, wt+0*4096, mbu+0,
      nullptr, nullptr, nullptr, UF1, nullptr, UF2,
      wt+8*4096, mbe+64, mWe+1*4288, points, gbuf, N_PTS, NT_N);
  // ---- layer1: agg -> FUSED [f2_1 -> UF21] + [h -> gbuf] ----
  k_edge_agg<<<GB_N,256,0,stream>>>(offs0, csr0, points, gbuf, wpp+1*192, abuf, N_PTS);
  k_gemm<true,1,false,false,true,false,1,true><<<GBG_N,256,0,stream>>>(abuf, wt+1*4096, mbu+64,
      nullptr, nullptr, nullptr, UF2, nullptr, UF21,
      wt+11*4096, b_m1, W_m1+4096, rel, gbuf, N_PTS, NT_N);
  // ---- c = segsum(h); FUSED [f3 -> UF3] + [cg0' -> cg_b] ----
  k_seg_gather<<<(M_CL*64+255)/256, 256, 0, stream>>>(offsL, csrL, gbuf, cb_b, M_CL);
  k_gemm<true,0,false,false,true,false,1,false><<<GBG_M,256,0,stream>>>(cb_b, wt+4*4096, b_m2,
      nullptr, nullptr, nullptr, nullptr, nullptr, UF3,
      wt+13*4096, gbe+0, gWe+0*4288, centers, cg_b, M_CL, NT_M);
  // ---- cluster layer0: agg -> FUSED [f4 -> UF4] + [cg1' -> cg_b] ----
  k_edge_agg<<<GBG_M,256,0,stream>>>(offs1, csr1, centers, cg_b, wpp+4*192, cagg_b, M_CL);
  k_gemm<true,1,false,false,true,false,1,false><<<GBG_M,256,0,stream>>>(cagg_b, wt+5*4096, gbu+0,
      nullptr, nullptr, nullptr, UF3, nullptr, UF4,
      wt+14*4096, gbe+64, gWe+1*4288, centers, cg_b, M_CL, NT_M);
  // ---- cluster layer1: agg -> f4_1 -> f41_b ----
  k_edge_agg<<<GBG_M,256,0,stream>>>(offs1, csr1, centers, cg_b, wpp+5*192, cagg_b, M_CL);
  k_gemm<true,1,false,false,true,false,0,false><<<GBG_M,256,0,stream>>>(cagg_b, wt+6*4096, gbu+64,
      nullptr, nullptr, nullptr, UF4, nullptr, f41_b,
      nullptr, nullptr, nullptr, nullptr, nullptr, M_CL, NT_M);
  // ---- FUSED [f5 -> UF5] + [g2' -> gbuf] ----
  k_gemm<true,0,true,true,true,false,1,false><<<GBG_N,256,0,stream>>>(f41_b, wt+12*4096, b_l,
      W_l+4096, rel, labels, nullptr, nullptr, UF5,
      wt+9*4096, mbe+128, mWe+2*4288, points, gbuf, N_PTS, NT_N);
  // ---- layer2: agg -> FUSED [f6 = relu+f5+f2_1 -> UF6] + [g3' -> gbuf] ----
  k_edge_agg<<<GB_N,256,0,stream>>>(offs0, csr0, points, gbuf, wpp+2*192, abuf, N_PTS);
  k_gemm<true,2,false,false,true,false,1,false><<<GBG_N,256,0,stream>>>(abuf, wt+2*4096, mbu+128,
      nullptr, nullptr, nullptr, UF5, UF21, UF6,
      wt+10*4096, mbe+192, mWe+3*4288, points, gbuf, N_PTS, NT_N);
  // ---- layer3: agg -> FUSED [final = relu+f6+f2] + [out = final@W_c + b_c] ----
  k_edge_agg<<<GB_N,256,0,stream>>>(offs0, csr0, points, gbuf, wpp+3*192, abuf, N_PTS);
  k_gemm<true,2,false,false,false,false,2,false><<<GBG_N,256,0,stream>>>(abuf, wt+3*4096, mbu+192,
      nullptr, nullptr, nullptr, UF6, UF2, nullptr,
      wtc, b_c, nullptr, nullptr, out, N_PTS, NT_N);
}

// Round 5
// 459.356 us; speedup vs baseline: 1.4198x; 1.0020x over previous
//
#include <hip/hip_runtime.h>

// R5 (from R4 = 460 µs): hotspot k_bin_f1g (45 µs, occupancy 29%, all rooflines <20%).
// (1) BIN_CAP 32->16: stage 32KB->16KB (LDS/block 34.8->18.4KB, 4->8 blocks/CU) and
//     flush loop 32->16 iters (4 buckets x 16 entries per wave-iter). Overflow ~0.3%.
// (2) Exclusive scan folded into k_build_all (each block scans the 256 counters
//     locally); k_scan_all dispatch removed.
// R4 carried: permuted column storage (phys p = (c&15)*4 + (c>>4)) for all 16-bit
// activations; K-permuted weights; fused bin+f1g; R0-shape agg (MLP=8, 128B/edge).

#define N_PTS   100000
#define M_CL    12500
#define E0_N    1600000
#define E1_N    400000

#define NB      256
#define BIN_CAP 16
#define RANGE0  391
#define RANGE1  49
#define BCAP0   8192
#define BCAP1   2048
#define BCAPL   1024

#define LSTR    72           // LDS row stride (shorts): 144 B

typedef unsigned short ushortT;
typedef short  short8 __attribute__((ext_vector_type(8)));
typedef short  s4v    __attribute__((ext_vector_type(4)));
typedef float  v4f    __attribute__((ext_vector_type(4)));
typedef _Float16 h2   __attribute__((ext_vector_type(2)));
typedef unsigned u4v  __attribute__((ext_vector_type(4)));

__device__ inline ushortT f2bf(float x){
  union{float f; unsigned u;} v; v.f = x;
  unsigned r = v.u + 0x7fffu + ((v.u >> 16) & 1u);   // RNE
  return (ushortT)(r >> 16);
}
__device__ inline float bf2f(ushortT h){
  union{unsigned u; float f;} v; v.u = ((unsigned)h) << 16;
  return v.f;
}
__device__ inline ushortT f2h(float x){
  union{_Float16 h; ushortT u;} v; v.h = (_Float16)x;
  return v.u;
}
__device__ inline float h2f(ushortT u){
  union{ushortT u; _Float16 h;} v; v.u = u;
  return (float)v.h;
}
__device__ inline h2 pkmax(h2 a, h2 b){ return __builtin_elementwise_max(a, b); }
__device__ inline h2 u2h(unsigned u){ union{unsigned u; h2 h;} v{u}; return v.h; }

// ============================ weight prep + counter init ============================
// K-permutation: physical slot p holds logical k = (p&3)*16 + (p>>2).

struct WSrc { const float* p[22]; };

__global__ __launch_bounds__(256) void k_init_wprep(WSrc s, ushortT* __restrict__ wt, ushortT* __restrict__ wtc,
                                                    float* __restrict__ wpp,
                                                    int* c0, int* c1, int* cL){
  int blk = blockIdx.x;
  if (blk == 0){
    int t = threadIdx.x;
    c0[t] = t*BCAP0; c1[t] = t*BCAP1; cL[t] = t*BCAPL;
    return;
  }
  int slot = blk - 1;
  if (slot < 15){
    const float* src = s.p[slot];
    ushortT* dst = wt + slot*4096;
    for (int e=threadIdx.x; e<4096; e+=256){
      int nn = e>>6, p = e&63;
      int kk = (p&3)*16 + (p>>2);
      dst[e] = f2bf(src[kk*64+nn]);
    }
  } else if (slot == 15){
    const float* src = s.p[15];
    for (int e=threadIdx.x; e<1024; e+=256){
      int nn = e>>6, p = e&63;
      int kk = (p&3)*16 + (p>>2);
      wtc[e] = (nn<8) ? f2bf(src[kk*8+nn]) : (ushortT)0;
    }
  } else {
    // permuted pos-weight rows for the agg epilogue: 6 matrices x 3 rows x 64
    for (int e=threadIdx.x; e<6*192; e+=256){
      int i = e/192, rem = e - i*192, r = rem>>6, p = rem&63;
      wpp[e] = s.p[16+i][r*64 + ((p&3)*16 + (p>>2))];
    }
  }
}

// ============================ bucketed CSR build ============================

template<int RANGE, bool LAB>
__device__ void bin_seg(const int* __restrict__ edges, int E,
                        int* __restrict__ bcur, unsigned* __restrict__ tmp,
                        int bid, int nblk,
                        unsigned* stage, int* scnt, int* sbase){
  int tid = threadIdx.x;
  int nchunks = (E + 2047) / 2048;
  for (int c = bid; c < nchunks; c += nblk){
    int base = c*2048;
    scnt[tid] = 0;
    __syncthreads();
    #pragma unroll
    for (int r=0;r<8;++r){
      int e = base + r*256 + tid;
      if (e < E){
        int s, d;
        if (LAB){ s = e; d = edges[e]; }
        else    { s = edges[2*e]; d = edges[2*e+1]; }
        int bk = d / RANGE;
        unsigned packed = ((unsigned)s << 11) | (unsigned)(d - bk*RANGE);
        int pos = atomicAdd(&scnt[bk], 1);
        if (pos < BIN_CAP) stage[bk*BIN_CAP+pos] = packed;
        else tmp[atomicAdd(&bcur[bk],1)] = packed;
      }
    }
    __syncthreads();
    {
      int nfl = scnt[tid]; if (nfl > BIN_CAP) nfl = BIN_CAP;
      sbase[tid] = atomicAdd(&bcur[tid], nfl);
    }
    __syncthreads();
    // flush: 16 iters, each wave covers 4 buckets x 16 entries
    int wv = tid >> 6, ln = tid & 63;
    for (int bb=0; bb<16; ++bb){
      int bk = wv*64 + bb*4 + (ln>>4);
      int ent = ln & 15;
      int nf = scnt[bk]; if (nf > BIN_CAP) nf = BIN_CAP;
      if (ent < nf) tmp[sbase[bk]+ent] = stage[bk*BIN_CAP+ent];
    }
    __syncthreads();
  }
}

template<int RANGE, int BCAP, int K>
__device__ void csr_build_seg(const unsigned* __restrict__ tmp, const int* __restrict__ bcur,
                              int n, int* __restrict__ offs, int* __restrict__ csr,
                              int b, int* hist, int* part){
  int tid = threadIdx.x;
  int dlo = b*RANGE;
  int range = n - dlo; if (range > RANGE) range = RANGE; if (range < 0) range = 0;
  int cnt = bcur[b] - b*BCAP;
  // ---- integrated exclusive scan of the 256 bucket counts (replaces k_scan_all) ----
  part[tid] = bcur[tid] - tid*BCAP;
  __syncthreads();
  for (int st=1; st<256; st<<=1){
    int x = (tid >= st) ? part[tid-st] : 0;
    __syncthreads();
    part[tid] += x;
    __syncthreads();
  }
  int gb = part[b] - cnt;          // exclusive prefix for this bucket
  int total = part[NB-1];
  if (b == NB-1 && tid == 0) offs[n] = total;
  __syncthreads();                 // part[] is reused below
  // ---- histogram within bucket ----
  for (int t=tid; t<RANGE; t+=256) hist[t] = 0;
  __syncthreads();
  const unsigned* sl = tmp + (size_t)b*BCAP;
  for (int j=tid; j<cnt; j+=256) atomicAdd(&hist[sl[j] & 2047u], 1);
  __syncthreads();
  int s = 0; int loc[K];
  #pragma unroll
  for (int kk=0; kk<K; ++kk){
    int idx = tid*K + kk;
    int v = (idx < RANGE) ? hist[idx] : 0;
    loc[kk] = s; s += v;
  }
  part[tid] = s; __syncthreads();
  int own = s;
  for (int st=1; st<256; st<<=1){
    int x = (tid >= st) ? part[tid-st] : 0;
    __syncthreads();
    part[tid] += x;
    __syncthreads();
  }
  int ebase = part[tid] - own;
  __syncthreads();
  #pragma unroll
  for (int kk=0; kk<K; ++kk){
    int idx = tid*K + kk;
    if (idx < RANGE){
      int ex = ebase + loc[kk];
      if (idx < range) offs[dlo+idx] = gb + ex;
      hist[idx] = ex;
    }
  }
  __syncthreads();
  for (int j=tid; j<cnt; j+=256){
    unsigned p = sl[j];
    int pos = atomicAdd(&hist[p & 2047u], 1);
    csr[gb + pos] = (int)(p >> 11);
  }
}

__global__ __launch_bounds__(256) void k_build_all(
    const unsigned* t0, const int* bc0, int* offs0, int* csr0,
    const unsigned* t1, const int* bc1, int* offs1, int* csr1,
    const unsigned* tL, const int* bcL, int* offsL, int* csrL){
  __shared__ int hist[RANGE0];
  __shared__ int part[256];
  int b = blockIdx.x;
  if (b < 256)      csr_build_seg<RANGE0,BCAP0,2>(t0, bc0, N_PTS, offs0, csr0, b, hist, part);
  else if (b < 512) csr_build_seg<RANGE1,BCAP1,1>(t1, bc1, M_CL, offs1, csr1, b-256, hist, part);
  else              csr_build_seg<RANGE1,BCAPL,1>(tL, bcL, M_CL, offsL, csrL, b-512, hist, part);
}

// ============================ FUSED: CSR binning (blocks 0..500) + f1g encoder (blocks 501+) ============================

__global__ __launch_bounds__(256) void k_bin_f1g(
    const int* __restrict__ l0e, const int* __restrict__ l1e, const int* __restrict__ labels,
    int* bc0, int* bc1, int* bcL,
    unsigned* t0, unsigned* t1, unsigned* tL,
    const float* __restrict__ features, const float* __restrict__ points,
    const float* __restrict__ centers,
    const float* __restrict__ W, const float* __restrict__ bfe,
    const ushortT* __restrict__ Wt2, const float* __restrict__ bias2,
    const float* __restrict__ Wr2,
    float* __restrict__ rel, ushortT* __restrict__ f1b,
    ushortT* __restrict__ gout, int n, int ntiles, int nf1blk)
{
  __shared__ char smem[18432];   // bin: stage 16384 + scnt 1024 + sbase 1024; f1g: 9216
  int b = blockIdx.x;
  if (b < 501){
    unsigned* stage = (unsigned*)smem;
    int* scnt = (int*)(smem + 16384);
    int* sbase = (int*)(smem + 17408);
    if (b < 256)      bin_seg<RANGE0,false>(l0e, E0_N, bc0, t0, b, 256, stage, scnt, sbase);
    else if (b < 452) bin_seg<RANGE1,false>(l1e, E1_N, bc1, t1, b-256, 196, stage, scnt, sbase);
    else              bin_seg<RANGE1,true >(labels, N_PTS, bcL, tL, b-452, 49, stage, scnt, sbase);
    return;
  }
  // ---- f1g: rel + f1 (bf16, permuted cols) + g0' (f16, permuted cols) ----
  ushortT* lds = (ushortT*)smem;
  int bb = b - 501;
  int tid = threadIdx.x;
  int lane = tid & 63, wslot = tid >> 6;
  int quad = lane >> 4, l15 = lane & 15;
  int permL = (lane & 15)*4 + (lane >> 4);   // physical slot of logical col `lane`
  int gw = (bb*256 + tid) >> 6;
  int nw = (nf1blk*256) >> 6;
  float Wf0=W[0*64+lane], Wf1=W[1*64+lane], Wf2=W[2*64+lane], Wf3=W[3*64+lane];
  float wr0=W[4*64+lane], wr1=W[5*64+lane], wr2=W[6*64+lane];
  float bias=bfe[lane];
  short8 s0_0 = *(const short8*)(Wt2 + ( 0 + l15)*64 +  0 + quad*8);
  short8 s0_1 = *(const short8*)(Wt2 + ( 0 + l15)*64 + 32 + quad*8);
  short8 s1_0 = *(const short8*)(Wt2 + (16 + l15)*64 +  0 + quad*8);
  short8 s1_1 = *(const short8*)(Wt2 + (16 + l15)*64 + 32 + quad*8);
  short8 s2_0 = *(const short8*)(Wt2 + (32 + l15)*64 +  0 + quad*8);
  short8 s2_1 = *(const short8*)(Wt2 + (32 + l15)*64 + 32 + quad*8);
  short8 s3_0 = *(const short8*)(Wt2 + (48 + l15)*64 +  0 + quad*8);
  short8 s3_1 = *(const short8*)(Wt2 + (48 + l15)*64 + 32 + quad*8);
  float eb0 = bias2[l15], eb1 = bias2[16+l15], eb2 = bias2[32+l15], eb3 = bias2[48+l15];
  float e0c0=Wr2[0*64+l15], e0c1=Wr2[0*64+16+l15], e0c2=Wr2[0*64+32+l15], e0c3=Wr2[0*64+48+l15];
  float e1c0=Wr2[1*64+l15], e1c1=Wr2[1*64+16+l15], e1c2=Wr2[1*64+32+l15], e1c3=Wr2[1*64+48+l15];
  float e2c0=Wr2[2*64+l15], e2c1=Wr2[2*64+16+l15], e2c2=Wr2[2*64+32+l15], e2c3=Wr2[2*64+48+l15];

  for (int t=gw; t<ntiles; t+=nw){
    int i0 = t*16;
    for (int r=0;r<16;++r){
      int row = i0 + r;
      bool ok = row < n;
      int rr = ok ? row : n-1;
      int lb = labels[rr];
      float rx = points[rr*3+0]-centers[lb*3+0];
      float ry = points[rr*3+1]-centers[lb*3+1];
      float rz = points[rr*3+2]-centers[lb*3+2];
      float acc = bias + wr0*rx + wr1*ry + wr2*rz;
      acc += features[rr*4+0]*Wf0 + features[rr*4+1]*Wf1;
      acc += features[rr*4+2]*Wf2 + features[rr*4+3]*Wf3;
      acc = fmaxf(acc, 0.f);
      ushortT ab = f2bf(acc);
      if (ok){
        f1b[(size_t)row*64 + permL] = ab;
        if (lane==0){ rel[row*3+0]=rx; rel[row*3+1]=ry; rel[row*3+2]=rz; }
      }
      lds[wslot*(16*LSTR) + r*LSTR + permL] = ab;
    }
    __builtin_amdgcn_wave_barrier();
    const ushortT* lp = lds + wslot*(16*LSTR) + l15*LSTR + quad*8;
    short8 sa0 = *(const short8*)(lp);
    short8 sa1 = *(const short8*)(lp + 32);
    __builtin_amdgcn_wave_barrier();
    v4f ec0 = {0.f,0.f,0.f,0.f}, ec1 = ec0, ec2 = ec0, ec3 = ec0;
    ec0 = __builtin_amdgcn_mfma_f32_16x16x32_bf16(sa0, s0_0, ec0, 0,0,0);
    ec1 = __builtin_amdgcn_mfma_f32_16x16x32_bf16(sa0, s1_0, ec1, 0,0,0);
    ec2 = __builtin_amdgcn_mfma_f32_16x16x32_bf16(sa0, s2_0, ec2, 0,0,0);
    ec3 = __builtin_amdgcn_mfma_f32_16x16x32_bf16(sa0, s3_0, ec3, 0,0,0);
    ec0 = __builtin_amdgcn_mfma_f32_16x16x32_bf16(sa1, s0_1, ec0, 0,0,0);
    ec1 = __builtin_amdgcn_mfma_f32_16x16x32_bf16(sa1, s1_1, ec1, 0,0,0);
    ec2 = __builtin_amdgcn_mfma_f32_16x16x32_bf16(sa1, s2_1, ec2, 0,0,0);
    ec3 = __builtin_amdgcn_mfma_f32_16x16x32_bf16(sa1, s3_1, ec3, 0,0,0);
    #pragma unroll
    for (int r=0;r<4;++r){
      int row = i0 + quad*4 + r;
      if (row < n){
        float vx=points[row*3+0], vy=points[row*3+1], vz=points[row*3+2];
        float g0 = ec0[r] + eb0 + vx*e0c0 + vy*e1c0 + vz*e2c0;
        float g1 = ec1[r] + eb1 + vx*e0c1 + vy*e1c1 + vz*e2c1;
        float g2 = ec2[r] + eb2 + vx*e0c2 + vy*e1c2 + vz*e2c2;
        float g3 = ec3[r] + eb3 + vx*e0c3 + vy*e1c3 + vz*e2c3;
        s4v o; o.x=(short)f2h(g0); o.y=(short)f2h(g1); o.z=(short)f2h(g2); o.w=(short)f2h(g3);
        *(s4v*)(gout + (size_t)row*64 + l15*4) = o;
      }
    }
  }
}

// ============================ MFMA GEMM with optional fused secondary GEMM ============================
// All 16-bit activation buffers in permuted layout. Lane (quad,l15): accumulators
// v0..v3 (logical cols {0,16,32,48}+l15) stored contiguously at phys l15*4.

template<bool RELU, int NRES, bool USEREL, bool GATHER, bool OUT16, bool F16O, int EMODE, bool ERELU>
__global__ __launch_bounds__(256) void k_gemm(
    const ushortT* __restrict__ A, const ushortT* __restrict__ Wt,
    const float* __restrict__ bias, const float* __restrict__ Wr,
    const float* __restrict__ rel, const int* __restrict__ gidx,
    const ushortT* __restrict__ r1, const ushortT* __restrict__ r2,
    ushortT* __restrict__ out16,
    const ushortT* __restrict__ Wt2, const float* __restrict__ bias2,
    const float* __restrict__ Wr2, const float* __restrict__ vec2,
    void* __restrict__ eout,
    int n, int ntiles)
{
  constexpr int LDSZ = (EMODE>0) ? 4*16*LSTR : 4;
  __shared__ ushortT lds[LDSZ];
  int tid = threadIdx.x;
  int lane = tid & 63, wslot = tid >> 6;
  int quad = lane >> 4, l15 = lane & 15;
  int gw = (blockIdx.x*256 + tid) >> 6;
  int nw = (gridDim.x*256) >> 6;

  short8 bfr0_0 = *(const short8*)(Wt + ( 0 + l15)*64 +  0 + quad*8);
  short8 bfr0_1 = *(const short8*)(Wt + ( 0 + l15)*64 + 32 + quad*8);
  short8 bfr1_0 = *(const short8*)(Wt + (16 + l15)*64 +  0 + quad*8);
  short8 bfr1_1 = *(const short8*)(Wt + (16 + l15)*64 + 32 + quad*8);
  short8 bfr2_0 = *(const short8*)(Wt + (32 + l15)*64 +  0 + quad*8);
  short8 bfr2_1 = *(const short8*)(Wt + (32 + l15)*64 + 32 + quad*8);
  short8 bfr3_0 = *(const short8*)(Wt + (48 + l15)*64 +  0 + quad*8);
  short8 bfr3_1 = *(const short8*)(Wt + (48 + l15)*64 + 32 + quad*8);
  float bs0 = bias[ 0 + l15], bs1 = bias[16 + l15];
  float bs2 = bias[32 + l15], bs3 = bias[48 + l15];
  float w0c0=0,w0c1=0,w0c2=0,w0c3=0, w1c0=0,w1c1=0,w1c2=0,w1c3=0, w2c0=0,w2c1=0,w2c2=0,w2c3=0;
  if (USEREL){
    w0c0=Wr[0*64+l15]; w0c1=Wr[0*64+16+l15]; w0c2=Wr[0*64+32+l15]; w0c3=Wr[0*64+48+l15];
    w1c0=Wr[1*64+l15]; w1c1=Wr[1*64+16+l15]; w1c2=Wr[1*64+32+l15]; w1c3=Wr[1*64+48+l15];
    w2c0=Wr[2*64+l15]; w2c1=Wr[2*64+16+l15]; w2c2=Wr[2*64+32+l15]; w2c3=Wr[2*64+48+l15];
  }

  short8 s0_0{}, s0_1{}, s1_0{}, s1_1{}, s2_0{}, s2_1{}, s3_0{}, s3_1{};
  float eb0=0, eb1=0, eb2=0, eb3=0;
  float e0c0=0,e0c1=0,e0c2=0,e0c3=0, e1c0=0,e1c1=0,e1c2=0,e1c3=0, e2c0=0,e2c1=0,e2c2=0,e2c3=0;
  float ebias_c = 0.f;
  if (EMODE == 1){
    s0_0 = *(const short8*)(Wt2 + ( 0 + l15)*64 +  0 + quad*8);
    s0_1 = *(const short8*)(Wt2 + ( 0 + l15)*64 + 32 + quad*8);
    s1_0 = *(const short8*)(Wt2 + (16 + l15)*64 +  0 + quad*8);
    s1_1 = *(const short8*)(Wt2 + (16 + l15)*64 + 32 + quad*8);
    s2_0 = *(const short8*)(Wt2 + (32 + l15)*64 +  0 + quad*8);
    s2_1 = *(const short8*)(Wt2 + (32 + l15)*64 + 32 + quad*8);
    s3_0 = *(const short8*)(Wt2 + (48 + l15)*64 +  0 + quad*8);
    s3_1 = *(const short8*)(Wt2 + (48 + l15)*64 + 32 + quad*8);
    eb0 = bias2[l15]; eb1 = bias2[16+l15]; eb2 = bias2[32+l15]; eb3 = bias2[48+l15];
    e0c0=Wr2[0*64+l15]; e0c1=Wr2[0*64+16+l15]; e0c2=Wr2[0*64+32+l15]; e0c3=Wr2[0*64+48+l15];
    e1c0=Wr2[1*64+l15]; e1c1=Wr2[1*64+16+l15]; e1c2=Wr2[1*64+32+l15]; e1c3=Wr2[1*64+48+l15];
    e2c0=Wr2[2*64+l15]; e2c1=Wr2[2*64+16+l15]; e2c2=Wr2[2*64+32+l15]; e2c3=Wr2[2*64+48+l15];
  } else if (EMODE == 2){
    s0_0 = *(const short8*)(Wt2 + l15*64 +  0 + quad*8);
    s0_1 = *(const short8*)(Wt2 + l15*64 + 32 + quad*8);
    ebias_c = (l15 < 8) ? bias2[l15] : 0.f;
  }

  for (int t=gw; t<ntiles; t+=nw){
    int i0 = t*16;
    int rowA = i0 + l15; if (rowA >= n) rowA = n-1;
    if (GATHER) rowA = gidx[rowA];
    const ushortT* ap = A + (size_t)rowA*64 + quad*8;
    short8 a0 = *(const short8*)(ap);
    short8 a1 = *(const short8*)(ap + 32);
    v4f ac0 = {0.f,0.f,0.f,0.f}, ac1 = ac0, ac2 = ac0, ac3 = ac0;
    ac0 = __builtin_amdgcn_mfma_f32_16x16x32_bf16(a0, bfr0_0, ac0, 0,0,0);
    ac1 = __builtin_amdgcn_mfma_f32_16x16x32_bf16(a0, bfr1_0, ac1, 0,0,0);
    ac2 = __builtin_amdgcn_mfma_f32_16x16x32_bf16(a0, bfr2_0, ac2, 0,0,0);
    ac3 = __builtin_amdgcn_mfma_f32_16x16x32_bf16(a0, bfr3_0, ac3, 0,0,0);
    ac0 = __builtin_amdgcn_mfma_f32_16x16x32_bf16(a1, bfr0_1, ac0, 0,0,0);
    ac1 = __builtin_amdgcn_mfma_f32_16x16x32_bf16(a1, bfr1_1, ac1, 0,0,0);
    ac2 = __builtin_amdgcn_mfma_f32_16x16x32_bf16(a1, bfr2_1, ac2, 0,0,0);
    ac3 = __builtin_amdgcn_mfma_f32_16x16x32_bf16(a1, bfr3_1, ac3, 0,0,0);

    #pragma unroll
    for (int r=0;r<4;++r){
      int row = i0 + quad*4 + r;
      bool rowok = (row < n);
      float rx=0.f, ry=0.f, rz=0.f;
      if (USEREL && rowok){ rx=rel[row*3+0]; ry=rel[row*3+1]; rz=rel[row*3+2]; }
      float v0 = ac0[r] + bs0, v1 = ac1[r] + bs1, v2 = ac2[r] + bs2, v3 = ac3[r] + bs3;
      if (USEREL){
        v0 += rx*w0c0 + ry*w1c0 + rz*w2c0;
        v1 += rx*w0c1 + ry*w1c1 + rz*w2c1;
        v2 += rx*w0c2 + ry*w1c2 + rz*w2c2;
        v3 += rx*w0c3 + ry*w1c3 + rz*w2c3;
      }
      if (RELU){ v0=fmaxf(v0,0.f); v1=fmaxf(v1,0.f); v2=fmaxf(v2,0.f); v3=fmaxf(v3,0.f); }
      size_t pb = (size_t)row*64 + l15*4;
      if (rowok){
        if (NRES>=1){
          s4v rv = *(const s4v*)(r1 + pb);
          v0 += bf2f((ushortT)rv.x); v1 += bf2f((ushortT)rv.y);
          v2 += bf2f((ushortT)rv.z); v3 += bf2f((ushortT)rv.w);
        }
        if (NRES>=2){
          s4v rv = *(const s4v*)(r2 + pb);
          v0 += bf2f((ushortT)rv.x); v1 += bf2f((ushortT)rv.y);
          v2 += bf2f((ushortT)rv.z); v3 += bf2f((ushortT)rv.w);
        }
        if (OUT16){
          s4v o;
          if (F16O){ o.x=(short)f2h(v0); o.y=(short)f2h(v1); o.z=(short)f2h(v2); o.w=(short)f2h(v3); }
          else     { o.x=(short)f2bf(v0); o.y=(short)f2bf(v1); o.z=(short)f2bf(v2); o.w=(short)f2bf(v3); }
          *(s4v*)(out16 + pb) = o;
        }
      }
      if (EMODE > 0){
        int lb = wslot*(16*LSTR) + (quad*4+r)*LSTR + l15*4;
        s4v o; o.x=(short)f2bf(v0); o.y=(short)f2bf(v1); o.z=(short)f2bf(v2); o.w=(short)f2bf(v3);
        *(s4v*)(lds + lb) = o;
      }
    }

    if (EMODE > 0){
      __builtin_amdgcn_wave_barrier();
      const ushortT* lp = lds + wslot*(16*LSTR) + l15*LSTR + quad*8;
      short8 sa0 = *(const short8*)(lp);
      short8 sa1 = *(const short8*)(lp + 32);
      __builtin_amdgcn_wave_barrier();
      if (EMODE == 1){
        v4f ec0 = {0.f,0.f,0.f,0.f}, ec1 = ec0, ec2 = ec0, ec3 = ec0;
        ec0 = __builtin_amdgcn_mfma_f32_16x16x32_bf16(sa0, s0_0, ec0, 0,0,0);
        ec1 = __builtin_amdgcn_mfma_f32_16x16x32_bf16(sa0, s1_0, ec1, 0,0,0);
        ec2 = __builtin_amdgcn_mfma_f32_16x16x32_bf16(sa0, s2_0, ec2, 0,0,0);
        ec3 = __builtin_amdgcn_mfma_f32_16x16x32_bf16(sa0, s3_0, ec3, 0,0,0);
        ec0 = __builtin_amdgcn_mfma_f32_16x16x32_bf16(sa1, s0_1, ec0, 0,0,0);
        ec1 = __builtin_amdgcn_mfma_f32_16x16x32_bf16(sa1, s1_1, ec1, 0,0,0);
        ec2 = __builtin_amdgcn_mfma_f32_16x16x32_bf16(sa1, s2_1, ec2, 0,0,0);
        ec3 = __builtin_amdgcn_mfma_f32_16x16x32_bf16(sa1, s3_1, ec3, 0,0,0);
        ushortT* eo = (ushortT*)eout;
        #pragma unroll
        for (int r=0;r<4;++r){
          int row = i0 + quad*4 + r;
          if (row < n){
            float vx=vec2[row*3+0], vy=vec2[row*3+1], vz=vec2[row*3+2];
            float g0 = ec0[r] + eb0 + vx*e0c0 + vy*e1c0 + vz*e2c0;
            float g1 = ec1[r] + eb1 + vx*e0c1 + vy*e1c1 + vz*e2c1;
            float g2 = ec2[r] + eb2 + vx*e0c2 + vy*e1c2 + vz*e2c2;
            float g3 = ec3[r] + eb3 + vx*e0c3 + vy*e1c3 + vz*e2c3;
            if (ERELU){ g0=fmaxf(g0,0.f); g1=fmaxf(g1,0.f); g2=fmaxf(g2,0.f); g3=fmaxf(g3,0.f); }
            s4v o; o.x=(short)f2h(g0); o.y=(short)f2h(g1); o.z=(short)f2h(g2); o.w=(short)f2h(g3);
            *(s4v*)(eo + (size_t)row*64 + l15*4) = o;
          }
        }
      } else {
        v4f ec = {0.f,0.f,0.f,0.f};
        ec = __builtin_amdgcn_mfma_f32_16x16x32_bf16(sa0, s0_0, ec, 0,0,0);
        ec = __builtin_amdgcn_mfma_f32_16x16x32_bf16(sa1, s0_1, ec, 0,0,0);
        if (l15 < 8){
          float* eo = (float*)eout;
          #pragma unroll
          for (int r=0;r<4;++r){
            int row = i0 + quad*4 + r;
            if (row < n) eo[(size_t)row*8 + l15] = ec[r] + ebias_c;
          }
        }
      }
    }
  }
}

// ============================ edge aggregation: 8 dsts/wave, 8 lanes per dst (R0 shape) ============================
// Wp is the PERMUTED 3x64 pos-weight block (wpp), matching the permuted column storage.

__global__ __launch_bounds__(256) void k_edge_agg(const int* __restrict__ offs, const int* __restrict__ csr,
                                                  const float* __restrict__ pos, const ushortT* __restrict__ g,
                                                  const float* __restrict__ Wp, ushortT* __restrict__ agg, int n){
  int lane = threadIdx.x & 63;
  int grp = lane >> 3, d8 = lane & 7;
  int gbase = lane & 56;
  int gw = (blockIdx.x*256 + threadIdx.x) >> 6;
  int nw = (gridDim.x*256) >> 6;
  const u4v* g4 = (const u4v*)g;
  float2 w0[4], w1[4], w2[4];
  #pragma unroll
  for (int q=0;q<4;++q){
    w0[q] = *(const float2*)(Wp + 0*64 + d8*8 + 2*q);
    w1[q] = *(const float2*)(Wp + 1*64 + d8*8 + 2*q);
    w2[q] = *(const float2*)(Wp + 2*64 + d8*8 + 2*q);
  }
  const h2 NEGBIG = {(_Float16)-60000.f, (_Float16)-60000.f};
  int n8 = (n+7) >> 3;
  for (int ii=gw; ii<n8; ii+=nw){
    int i0 = ii*8;
    int ig = i0 + grp; bool ok = ig < n; if (!ok) ig = n-1;
    int b = offs[ig], e = offs[ig+1];
    int cnt = e - b, c1 = cnt - 1;
    int mx = cnt;
    mx = max(mx, __shfl_xor(mx, 8, 64));
    mx = max(mx, __shfl_xor(mx, 16, 64));
    mx = max(mx, __shfl_xor(mx, 32, 64));
    h2 m0=NEGBIG, m1=NEGBIG, m2=NEGBIG, m3=NEGBIG;
    for (int J=0; J<mx; J+=8){
      if (J < cnt){
        int sv = csr[b + min(J + d8, c1)];
        #pragma unroll
        for (int jj=0; jj<8; ++jj){
          int s = __shfl(sv, gbase + jj, 64);
          u4v u = g4[(size_t)s*8 + d8];
          m0 = pkmax(m0, u2h(u.x));
          m1 = pkmax(m1, u2h(u.y));
          m2 = pkmax(m2, u2h(u.z));
          m3 = pkmax(m3, u2h(u.w));
        }
      }
    }
    float px = pos[ig*3+0], py = pos[ig*3+1], pz = pos[ig*3+2];
    u4v outv;
    {
      float sA = w0[0].x*px + w1[0].x*py + w2[0].x*pz;
      float sB = w0[0].y*px + w1[0].y*py + w2[0].y*pz;
      outv.x = (unsigned)f2bf(fmaxf((float)m0.x - sA, 0.f)) |
               ((unsigned)f2bf(fmaxf((float)m0.y - sB, 0.f)) << 16);
    }
    {
      float sA = w0[1].x*px + w1[1].x*py + w2[1].x*pz;
      float sB = w0[1].y*px + w1[1].y*py + w2[1].y*pz;
      outv.y = (unsigned)f2bf(fmaxf((float)m1.x - sA, 0.f)) |
               ((unsigned)f2bf(fmaxf((float)m1.y - sB, 0.f)) << 16);
    }
    {
      float sA = w0[2].x*px + w1[2].x*py + w2[2].x*pz;
      float sB = w0[2].y*px + w1[2].y*py + w2[2].y*pz;
      outv.z = (unsigned)f2bf(fmaxf((float)m2.x - sA, 0.f)) |
               ((unsigned)f2bf(fmaxf((float)m2.y - sB, 0.f)) << 16);
    }
    {
      float sA = w0[3].x*px + w1[3].x*py + w2[3].x*pz;
      float sB = w0[3].y*px + w1[3].y*py + w2[3].y*pz;
      outv.w = (unsigned)f2bf(fmaxf((float)m3.x - sA, 0.f)) |
               ((unsigned)f2bf(fmaxf((float)m3.y - sB, 0.f)) << 16);
    }
    if (ok) ((u4v*)agg)[(size_t)ig*8 + d8] = outv;
  }
}

// ============================ segment sum via label CSR (f16 in, bf16 out) ============================
// Column-preserving element-wise op: identical on permuted layout.

__global__ __launch_bounds__(256) void k_seg_gather(const int* __restrict__ offs, const int* __restrict__ csr,
                                                    const ushortT* __restrict__ h, ushortT* __restrict__ c, int m){
  int lane = threadIdx.x & 63;
  int wv = (blockIdx.x*256 + threadIdx.x) >> 6;
  if (wv >= m) return;
  int b = offs[wv], e = offs[wv+1];
  float acc = 0.f;
  for (int k=b; k<e; ++k){
    int i = csr[k];
    acc += h2f(h[(size_t)i*64+lane]);
  }
  c[(size_t)wv*64+lane] = f2bf(acc);
}

// ============================ host launcher ============================

extern "C" void kernel_launch(void* const* d_in, const int* in_sizes, int n_in,
                              void* d_out, int out_size, void* d_ws, size_t ws_size,
                              hipStream_t stream){
  const float* features = (const float*)d_in[0];
  const float* points   = (const float*)d_in[1];
  const float* centers  = (const float*)d_in[2];
  const int*   l0e      = (const int*)d_in[3];
  const int*   l1e      = (const int*)d_in[4];
  const int*   labels   = (const int*)d_in[5];
  const float* W_fe = (const float*)d_in[6];
  const float* b_fe = (const float*)d_in[7];
  const float* mWe  = (const float*)d_in[8];
  const float* mbe  = (const float*)d_in[9];
  const float* mWu  = (const float*)d_in[10];
  const float* mbu  = (const float*)d_in[11];
  const float* W_m1 = (const float*)d_in[12];
  const float* b_m1 = (const float*)d_in[13];
  const float* W_m2 = (const float*)d_in[14];
  const float* b_m2 = (const float*)d_in[15];
  const float* gWe  = (const float*)d_in[16];
  const float* gbe  = (const float*)d_in[17];
  const float* gWu  = (const float*)d_in[18];
  const float* gbu  = (const float*)d_in[19];
  const float* W_l  = (const float*)d_in[20];
  const float* b_l  = (const float*)d_in[21];
  const float* W_c  = (const float*)d_in[22];
  const float* b_c  = (const float*)d_in[23];
  float* out = (float*)d_out;

  char* w = (char*)d_ws;
  size_t off = 0;
  auto alloc = [&](size_t bytes)->void*{
    void* p = (void*)(w + off);
    off = (off + bytes + 255) & ~(size_t)255;
    return p;
  };
  float* rel  = (float*)alloc((size_t)N_PTS*3*4);
  ushortT* UF1 = (ushortT*)alloc((size_t)N_PTS*64*2);
  ushortT* UF2 = (ushortT*)alloc((size_t)N_PTS*64*2);
  ushortT* UF21= (ushortT*)alloc((size_t)N_PTS*64*2);
  ushortT* UF5 = (ushortT*)alloc((size_t)N_PTS*64*2);
  ushortT* UF6 = (ushortT*)alloc((size_t)N_PTS*64*2);
  ushortT* gbuf= (ushortT*)alloc((size_t)N_PTS*64*2);
  ushortT* abuf= (ushortT*)alloc((size_t)N_PTS*64*2);
  ushortT* cb_b= (ushortT*)alloc((size_t)M_CL*64*2);
  ushortT* UF3 = (ushortT*)alloc((size_t)M_CL*64*2);
  ushortT* UF4 = (ushortT*)alloc((size_t)M_CL*64*2);
  ushortT* cg_b= (ushortT*)alloc((size_t)M_CL*64*2);
  ushortT* cagg_b = (ushortT*)alloc((size_t)M_CL*64*2);
  ushortT* f41_b  = (ushortT*)alloc((size_t)M_CL*64*2);
  ushortT* wt  = (ushortT*)alloc((size_t)15*4096*2);
  ushortT* wtc = (ushortT*)alloc((size_t)1024*2);
  float* wpp = (float*)alloc((size_t)6*192*4);
  int* offs0 = (int*)alloc((size_t)(N_PTS+1)*4);
  int* csr0  = (int*)alloc((size_t)E0_N*4);
  int* offs1 = (int*)alloc((size_t)(M_CL+1)*4);
  int* csr1  = (int*)alloc((size_t)E1_N*4);
  int* offsL = (int*)alloc((size_t)(M_CL+1)*4);
  int* csrL  = (int*)alloc((size_t)N_PTS*4);
  unsigned* tmp0 = (unsigned*)alloc((size_t)NB*BCAP0*4);
  unsigned* tmp1 = (unsigned*)alloc((size_t)NB*BCAP1*4);
  unsigned* tmpL = (unsigned*)alloc((size_t)NB*BCAPL*4);
  int* bcur0 = (int*)alloc(NB*4);
  int* bcur1 = (int*)alloc(NB*4);
  int* bcurL = (int*)alloc(NB*4);
  (void)ws_size; (void)in_sizes; (void)n_in; (void)out_size;

  const int NT_N = (N_PTS+15)/16;
  const int NT_M = (M_CL +15)/16;
  const int GBG_N = 1563;
  const int GBG_M = 196;
  const int GB_N  = 3125;

  // ---- setup: weights(K-permuted) + wpp + counters (1), bin+f1g fused (1), build w/ integrated scan (1) ----
  WSrc ws{};
  ws.p[0]=mWu+0*4096; ws.p[1]=mWu+1*4096; ws.p[2]=mWu+2*4096; ws.p[3]=mWu+3*4096;
  ws.p[4]=W_m2; ws.p[5]=gWu+0*4096; ws.p[6]=gWu+1*4096;
  ws.p[7]=mWe+0*4288+192; ws.p[8]=mWe+1*4288+192; ws.p[9]=mWe+2*4288+192; ws.p[10]=mWe+3*4288+192;
  ws.p[11]=W_m1; ws.p[12]=W_l; ws.p[13]=gWe+0*4288+192; ws.p[14]=gWe+1*4288+192;
  ws.p[15]=W_c;
  ws.p[16]=mWe+0*4288; ws.p[17]=mWe+1*4288; ws.p[18]=mWe+2*4288; ws.p[19]=mWe+3*4288;
  ws.p[20]=gWe+0*4288; ws.p[21]=gWe+1*4288;
  k_init_wprep<<<18, 256, 0, stream>>>(ws, wt, wtc, wpp, bcur0, bcur1, bcurL);
  k_bin_f1g<<<501 + GBG_N, 256, 0, stream>>>(l0e, l1e, labels, bcur0, bcur1, bcurL, tmp0, tmp1, tmpL,
      features, points, centers, W_fe, b_fe,
      wt+7*4096, mbe+0, mWe+0*4288, rel, UF1, gbuf, N_PTS, NT_N, GBG_N);
  k_build_all<<<768, 256, 0, stream>>>(tmp0, bcur0, offs0, csr0,
                                       tmp1, bcur1, offs1, csr1,
                                       tmpL, bcurL, offsL, csrL);

  // ---- layer0: agg -> FUSED [f2 -> UF2] + [g1' -> gbuf] ----
  k_edge_agg<<<GB_N,256,0,stream>>>(offs0, csr0, points, gbuf, wpp+0*192, abuf, N_PTS);
  k_gemm<true,1,false,false,true,false,1,false><<<GBG_N,256,0,stream>>>(abuf, wt+0*4096, mbu+0,
      nullptr, nullptr, nullptr, UF1, nullptr, UF2,
      wt+8*4096, mbe+64, mWe+1*4288, points, gbuf, N_PTS, NT_N);
  // ---- layer1: agg -> FUSED [f2_1 -> UF21] + [h -> gbuf] ----
  k_edge_agg<<<GB_N,256,0,stream>>>(offs0, csr0, points, gbuf, wpp+1*192, abuf, N_PTS);
  k_gemm<true,1,false,false,true,false,1,true><<<GBG_N,256,0,stream>>>(abuf, wt+1*4096, mbu+64,
      nullptr, nullptr, nullptr, UF2, nullptr, UF21,
      wt+11*4096, b_m1, W_m1+4096, rel, gbuf, N_PTS, NT_N);
  // ---- c = segsum(h); FUSED [f3 -> UF3] + [cg0' -> cg_b] ----
  k_seg_gather<<<(M_CL*64+255)/256, 256, 0, stream>>>(offsL, csrL, gbuf, cb_b, M_CL);
  k_gemm<true,0,false,false,true,false,1,false><<<GBG_M,256,0,stream>>>(cb_b, wt+4*4096, b_m2,
      nullptr, nullptr, nullptr, nullptr, nullptr, UF3,
      wt+13*4096, gbe+0, gWe+0*4288, centers, cg_b, M_CL, NT_M);
  // ---- cluster layer0: agg -> FUSED [f4 -> UF4] + [cg1' -> cg_b] ----
  k_edge_agg<<<GBG_M,256,0,stream>>>(offs1, csr1, centers, cg_b, wpp+4*192, cagg_b, M_CL);
  k_gemm<true,1,false,false,true,false,1,false><<<GBG_M,256,0,stream>>>(cagg_b, wt+5*4096, gbu+0,
      nullptr, nullptr, nullptr, UF3, nullptr, UF4,
      wt+14*4096, gbe+64, gWe+1*4288, centers, cg_b, M_CL, NT_M);
  // ---- cluster layer1: agg -> f4_1 -> f41_b ----
  k_edge_agg<<<GBG_M,256,0,stream>>>(offs1, csr1, centers, cg_b, wpp+5*192, cagg_b, M_CL);
  k_gemm<true,1,false,false,true,false,0,false><<<GBG_M,256,0,stream>>>(cagg_b, wt+6*4096, gbu+64,
      nullptr, nullptr, nullptr, UF4, nullptr, f41_b,
      nullptr, nullptr, nullptr, nullptr, nullptr, M_CL, NT_M);
  // ---- FUSED [f5 -> UF5] + [g2' -> gbuf] ----
  k_gemm<true,0,true,true,true,false,1,false><<<GBG_N,256,0,stream>>>(f41_b, wt+12*4096, b_l,
      W_l+4096, rel, labels, nullptr, nullptr, UF5,
      wt+9*4096, mbe+128, mWe+2*4288, points, gbuf, N_PTS, NT_N);
  // ---- layer2: agg -> FUSED [f6 = relu+f5+f2_1 -> UF6] + [g3' -> gbuf] ----
  k_edge_agg<<<GB_N,256,0,stream>>>(offs0, csr0, points, gbuf, wpp+2*192, abuf, N_PTS);
  k_gemm<true,2,false,false,true,false,1,false><<<GBG_N,256,0,stream>>>(abuf, wt+2*4096, mbu+128,
      nullptr, nullptr, nullptr, UF5, UF21, UF6,
      wt+10*4096, mbe+192, mWe+3*4288, points, gbuf, N_PTS, NT_N);
  // ---- layer3: agg -> FUSED [final = relu+f6+f2] + [out = final@W_c + b_c] ----
  k_edge_agg<<<GB_N,256,0,stream>>>(offs0, csr0, points, gbuf, wpp+3*192, abuf, N_PTS);
  k_gemm<true,2,false,false,false,false,2,false><<<GBG_N,256,0,stream>>>(abuf, wt+3*4096, mbu+192,
      nullptr, nullptr, nullptr, UF6, UF2, nullptr,
      wtc, b_c, nullptr, nullptr, out, N_PTS, NT_N);
}

// Round 6
// 458.205 us; speedup vs baseline: 1.4233x; 1.0025x over previous
//
#include <hip/hip_runtime.h>

// R6 (from R5 = 459 µs): occupancy signature said the 501-block bin phase is the
// long pole of k_bin_f1g (E0 blocks serialize 3 chunks each).
// (1) one chunk per bin block (1027 bin blocks), int2 edge loads;
// (2) f1g row stage cooperative: 4 coalesced loads + shfl redistribution instead
//     of ~176 uniform scalar loads per tile; coalesced rel store;
// (3) k_gemm EMODE1 vec2 / USEREL rel loads staged cooperatively (48-lane load +
//     shfl) instead of 12 uniform loads per tile.
// Carried: permuted column storage, K-permuted weights, integrated scan in build,
// BIN_CAP=16, R0-shape agg (128B/edge, MLP=8 — measured L3-throughput roofline).

#define N_PTS   100000
#define M_CL    12500
#define E0_N    1600000
#define E1_N    400000

#define NB      256
#define BIN_CAP 16
#define RANGE0  391
#define RANGE1  49
#define BCAP0   8192
#define BCAP1   2048
#define BCAPL   1024

#define LSTR    72           // LDS row stride (shorts): 144 B

typedef unsigned short ushortT;
typedef short  short8 __attribute__((ext_vector_type(8)));
typedef short  s4v    __attribute__((ext_vector_type(4)));
typedef float  v4f    __attribute__((ext_vector_type(4)));
typedef _Float16 h2   __attribute__((ext_vector_type(2)));
typedef unsigned u4v  __attribute__((ext_vector_type(4)));

__device__ inline ushortT f2bf(float x){
  union{float f; unsigned u;} v; v.f = x;
  unsigned r = v.u + 0x7fffu + ((v.u >> 16) & 1u);   // RNE
  return (ushortT)(r >> 16);
}
__device__ inline float bf2f(ushortT h){
  union{unsigned u; float f;} v; v.u = ((unsigned)h) << 16;
  return v.f;
}
__device__ inline ushortT f2h(float x){
  union{_Float16 h; ushortT u;} v; v.h = (_Float16)x;
  return v.u;
}
__device__ inline float h2f(ushortT u){
  union{ushortT u; _Float16 h;} v; v.u = u;
  return (float)v.h;
}
__device__ inline h2 pkmax(h2 a, h2 b){ return __builtin_elementwise_max(a, b); }
__device__ inline h2 u2h(unsigned u){ union{unsigned u; h2 h;} v{u}; return v.h; }

// ============================ weight prep + counter init ============================
// K-permutation: physical slot p holds logical k = (p&3)*16 + (p>>2).

struct WSrc { const float* p[22]; };

__global__ __launch_bounds__(256) void k_init_wprep(WSrc s, ushortT* __restrict__ wt, ushortT* __restrict__ wtc,
                                                    float* __restrict__ wpp,
                                                    int* c0, int* c1, int* cL){
  int blk = blockIdx.x;
  if (blk == 0){
    int t = threadIdx.x;
    c0[t] = t*BCAP0; c1[t] = t*BCAP1; cL[t] = t*BCAPL;
    return;
  }
  int slot = blk - 1;
  if (slot < 15){
    const float* src = s.p[slot];
    ushortT* dst = wt + slot*4096;
    for (int e=threadIdx.x; e<4096; e+=256){
      int nn = e>>6, p = e&63;
      int kk = (p&3)*16 + (p>>2);
      dst[e] = f2bf(src[kk*64+nn]);
    }
  } else if (slot == 15){
    const float* src = s.p[15];
    for (int e=threadIdx.x; e<1024; e+=256){
      int nn = e>>6, p = e&63;
      int kk = (p&3)*16 + (p>>2);
      wtc[e] = (nn<8) ? f2bf(src[kk*8+nn]) : (ushortT)0;
    }
  } else {
    // permuted pos-weight rows for the agg epilogue: 6 matrices x 3 rows x 64
    for (int e=threadIdx.x; e<6*192; e+=256){
      int i = e/192, rem = e - i*192, r = rem>>6, p = rem&63;
      wpp[e] = s.p[16+i][r*64 + ((p&3)*16 + (p>>2))];
    }
  }
}

// ============================ bucketed CSR build ============================
// One chunk per call (bid = chunk index, nblk = nchunks -> single iteration).

template<int RANGE, bool LAB>
__device__ void bin_seg(const int* __restrict__ edges, int E,
                        int* __restrict__ bcur, unsigned* __restrict__ tmp,
                        int bid, int nblk,
                        unsigned* stage, int* scnt, int* sbase){
  int tid = threadIdx.x;
  int nchunks = (E + 2047) / 2048;
  for (int c = bid; c < nchunks; c += nblk){
    int base = c*2048;
    scnt[tid] = 0;
    __syncthreads();
    #pragma unroll
    for (int r=0;r<8;++r){
      int e = base + r*256 + tid;
      if (e < E){
        int s, d;
        if (LAB){ s = e; d = edges[e]; }
        else    { int2 ed = ((const int2*)edges)[e]; s = ed.x; d = ed.y; }
        int bk = d / RANGE;
        unsigned packed = ((unsigned)s << 11) | (unsigned)(d - bk*RANGE);
        int pos = atomicAdd(&scnt[bk], 1);
        if (pos < BIN_CAP) stage[bk*BIN_CAP+pos] = packed;
        else tmp[atomicAdd(&bcur[bk],1)] = packed;
      }
    }
    __syncthreads();
    {
      int nfl = scnt[tid]; if (nfl > BIN_CAP) nfl = BIN_CAP;
      sbase[tid] = atomicAdd(&bcur[tid], nfl);
    }
    __syncthreads();
    // flush: 16 iters, each wave covers 4 buckets x 16 entries
    int wv = tid >> 6, ln = tid & 63;
    for (int bb=0; bb<16; ++bb){
      int bk = wv*64 + bb*4 + (ln>>4);
      int ent = ln & 15;
      int nf = scnt[bk]; if (nf > BIN_CAP) nf = BIN_CAP;
      if (ent < nf) tmp[sbase[bk]+ent] = stage[bk*BIN_CAP+ent];
    }
    __syncthreads();
  }
}

template<int RANGE, int BCAP, int K>
__device__ void csr_build_seg(const unsigned* __restrict__ tmp, const int* __restrict__ bcur,
                              int n, int* __restrict__ offs, int* __restrict__ csr,
                              int b, int* hist, int* part){
  int tid = threadIdx.x;
  int dlo = b*RANGE;
  int range = n - dlo; if (range > RANGE) range = RANGE; if (range < 0) range = 0;
  int cnt = bcur[b] - b*BCAP;
  // ---- integrated exclusive scan of the 256 bucket counts ----
  part[tid] = bcur[tid] - tid*BCAP;
  __syncthreads();
  for (int st=1; st<256; st<<=1){
    int x = (tid >= st) ? part[tid-st] : 0;
    __syncthreads();
    part[tid] += x;
    __syncthreads();
  }
  int gb = part[b] - cnt;          // exclusive prefix for this bucket
  int total = part[NB-1];
  if (b == NB-1 && tid == 0) offs[n] = total;
  __syncthreads();                 // part[] is reused below
  // ---- histogram within bucket ----
  for (int t=tid; t<RANGE; t+=256) hist[t] = 0;
  __syncthreads();
  const unsigned* sl = tmp + (size_t)b*BCAP;
  for (int j=tid; j<cnt; j+=256) atomicAdd(&hist[sl[j] & 2047u], 1);
  __syncthreads();
  int s = 0; int loc[K];
  #pragma unroll
  for (int kk=0; kk<K; ++kk){
    int idx = tid*K + kk;
    int v = (idx < RANGE) ? hist[idx] : 0;
    loc[kk] = s; s += v;
  }
  part[tid] = s; __syncthreads();
  int own = s;
  for (int st=1; st<256; st<<=1){
    int x = (tid >= st) ? part[tid-st] : 0;
    __syncthreads();
    part[tid] += x;
    __syncthreads();
  }
  int ebase = part[tid] - own;
  __syncthreads();
  #pragma unroll
  for (int kk=0; kk<K; ++kk){
    int idx = tid*K + kk;
    if (idx < RANGE){
      int ex = ebase + loc[kk];
      if (idx < range) offs[dlo+idx] = gb + ex;
      hist[idx] = ex;
    }
  }
  __syncthreads();
  for (int j=tid; j<cnt; j+=256){
    unsigned p = sl[j];
    int pos = atomicAdd(&hist[p & 2047u], 1);
    csr[gb + pos] = (int)(p >> 11);
  }
}

__global__ __launch_bounds__(256) void k_build_all(
    const unsigned* t0, const int* bc0, int* offs0, int* csr0,
    const unsigned* t1, const int* bc1, int* offs1, int* csr1,
    const unsigned* tL, const int* bcL, int* offsL, int* csrL){
  __shared__ int hist[RANGE0];
  __shared__ int part[256];
  int b = blockIdx.x;
  if (b < 256)      csr_build_seg<RANGE0,BCAP0,2>(t0, bc0, N_PTS, offs0, csr0, b, hist, part);
  else if (b < 512) csr_build_seg<RANGE1,BCAP1,1>(t1, bc1, M_CL, offs1, csr1, b-256, hist, part);
  else              csr_build_seg<RANGE1,BCAPL,1>(tL, bcL, M_CL, offsL, csrL, b-512, hist, part);
}

// ============================ FUSED: CSR binning (1 chunk/block, 1027 blocks) + f1g ============================
// bin blocks: [0,782) E0, [782,978) E1, [978,1027) labels. f1g blocks: [1027, 1027+nf1blk).

__global__ __launch_bounds__(256) void k_bin_f1g(
    const int* __restrict__ l0e, const int* __restrict__ l1e, const int* __restrict__ labels,
    int* bc0, int* bc1, int* bcL,
    unsigned* t0, unsigned* t1, unsigned* tL,
    const float* __restrict__ features, const float* __restrict__ points,
    const float* __restrict__ centers,
    const float* __restrict__ W, const float* __restrict__ bfe,
    const ushortT* __restrict__ Wt2, const float* __restrict__ bias2,
    const float* __restrict__ Wr2,
    float* __restrict__ rel, ushortT* __restrict__ f1b,
    ushortT* __restrict__ gout, int n, int ntiles, int nf1blk)
{
  __shared__ char smem[18432];   // bin: stage 16384 + scnt 1024 + sbase 1024; f1g: 9216
  int b = blockIdx.x;
  if (b < 1027){
    unsigned* stage = (unsigned*)smem;
    int* scnt = (int*)(smem + 16384);
    int* sbase = (int*)(smem + 17408);
    if (b < 782)      bin_seg<RANGE0,false>(l0e, E0_N, bc0, t0, b, 782, stage, scnt, sbase);
    else if (b < 978) bin_seg<RANGE1,false>(l1e, E1_N, bc1, t1, b-782, 196, stage, scnt, sbase);
    else              bin_seg<RANGE1,true >(labels, N_PTS, bcL, tL, b-978, 49, stage, scnt, sbase);
    return;
  }
  // ---- f1g: rel + f1 (bf16, permuted cols) + g0' (f16, permuted cols) ----
  ushortT* lds = (ushortT*)smem;
  int bb = b - 1027;
  int tid = threadIdx.x;
  int lane = tid & 63, wslot = tid >> 6;
  int quad = lane >> 4, l15 = lane & 15;
  int permL = (lane & 15)*4 + (lane >> 4);   // physical slot of logical col `lane`
  int r3 = lane/3, c3 = lane - r3*3;         // 48-lane pos mapping
  int gw = (bb*256 + tid) >> 6;
  int nw = (nf1blk*256) >> 6;
  float Wf0=W[0*64+lane], Wf1=W[1*64+lane], Wf2=W[2*64+lane], Wf3=W[3*64+lane];
  float wr0=W[4*64+lane], wr1=W[5*64+lane], wr2=W[6*64+lane];
  float bias=bfe[lane];
  short8 s0_0 = *(const short8*)(Wt2 + ( 0 + l15)*64 +  0 + quad*8);
  short8 s0_1 = *(const short8*)(Wt2 + ( 0 + l15)*64 + 32 + quad*8);
  short8 s1_0 = *(const short8*)(Wt2 + (16 + l15)*64 +  0 + quad*8);
  short8 s1_1 = *(const short8*)(Wt2 + (16 + l15)*64 + 32 + quad*8);
  short8 s2_0 = *(const short8*)(Wt2 + (32 + l15)*64 +  0 + quad*8);
  short8 s2_1 = *(const short8*)(Wt2 + (32 + l15)*64 + 32 + quad*8);
  short8 s3_0 = *(const short8*)(Wt2 + (48 + l15)*64 +  0 + quad*8);
  short8 s3_1 = *(const short8*)(Wt2 + (48 + l15)*64 + 32 + quad*8);
  float eb0 = bias2[l15], eb1 = bias2[16+l15], eb2 = bias2[32+l15], eb3 = bias2[48+l15];
  float e0c0=Wr2[0*64+l15], e0c1=Wr2[0*64+16+l15], e0c2=Wr2[0*64+32+l15], e0c3=Wr2[0*64+48+l15];
  float e1c0=Wr2[1*64+l15], e1c1=Wr2[1*64+16+l15], e1c2=Wr2[1*64+32+l15], e1c3=Wr2[1*64+48+l15];
  float e2c0=Wr2[2*64+l15], e2c1=Wr2[2*64+16+l15], e2c2=Wr2[2*64+32+l15], e2c3=Wr2[2*64+48+l15];

  for (int t=gw; t<ntiles; t+=nw){
    int i0 = t*16;
    // ---- cooperative stage: labels(16), features(64), points(48), centers-gather(48) ----
    int lab16 = labels[min(i0 + (lane & 15), n-1)];
    float fv  = features[(size_t)min(i0 + (lane>>2), n-1)*4 + (lane & 3)];
    int lb = __shfl(lab16, (r3 < 16) ? r3 : 0, 64);
    float pv = 0.f, relv = 0.f;
    if (lane < 48){
      int rowp = i0 + r3;
      int rc = (rowp < n) ? rowp : (n-1);
      pv = points[(size_t)rc*3 + c3];
      float cv = centers[(size_t)lb*3 + c3];
      relv = pv - cv;
      if (rowp < n) rel[(size_t)rowp*3 + c3] = relv;
    }
    #pragma unroll
    for (int r=0;r<16;++r){
      float rx = __shfl(relv, 3*r+0, 64);
      float ry = __shfl(relv, 3*r+1, 64);
      float rz = __shfl(relv, 3*r+2, 64);
      float f0 = __shfl(fv, 4*r+0, 64);
      float f1 = __shfl(fv, 4*r+1, 64);
      float f2 = __shfl(fv, 4*r+2, 64);
      float f3 = __shfl(fv, 4*r+3, 64);
      float acc = bias + wr0*rx + wr1*ry + wr2*rz;
      acc += f0*Wf0 + f1*Wf1;
      acc += f2*Wf2 + f3*Wf3;
      acc = fmaxf(acc, 0.f);
      ushortT ab = f2bf(acc);
      int row = i0 + r;
      if (row < n) f1b[(size_t)row*64 + permL] = ab;
      lds[wslot*(16*LSTR) + r*LSTR + permL] = ab;
    }
    __builtin_amdgcn_wave_barrier();
    const ushortT* lp = lds + wslot*(16*LSTR) + l15*LSTR + quad*8;
    short8 sa0 = *(const short8*)(lp);
    short8 sa1 = *(const short8*)(lp + 32);
    __builtin_amdgcn_wave_barrier();
    v4f ec0 = {0.f,0.f,0.f,0.f}, ec1 = ec0, ec2 = ec0, ec3 = ec0;
    ec0 = __builtin_amdgcn_mfma_f32_16x16x32_bf16(sa0, s0_0, ec0, 0,0,0);
    ec1 = __builtin_amdgcn_mfma_f32_16x16x32_bf16(sa0, s1_0, ec1, 0,0,0);
    ec2 = __builtin_amdgcn_mfma_f32_16x16x32_bf16(sa0, s2_0, ec2, 0,0,0);
    ec3 = __builtin_amdgcn_mfma_f32_16x16x32_bf16(sa0, s3_0, ec3, 0,0,0);
    ec0 = __builtin_amdgcn_mfma_f32_16x16x32_bf16(sa1, s0_1, ec0, 0,0,0);
    ec1 = __builtin_amdgcn_mfma_f32_16x16x32_bf16(sa1, s1_1, ec1, 0,0,0);
    ec2 = __builtin_amdgcn_mfma_f32_16x16x32_bf16(sa1, s2_1, ec2, 0,0,0);
    ec3 = __builtin_amdgcn_mfma_f32_16x16x32_bf16(sa1, s3_1, ec3, 0,0,0);
    #pragma unroll
    for (int r=0;r<4;++r){
      int row = i0 + quad*4 + r;
      if (row < n){
        int rr4 = quad*4 + r;
        float vx = __shfl(pv, 3*rr4+0, 64);
        float vy = __shfl(pv, 3*rr4+1, 64);
        float vz = __shfl(pv, 3*rr4+2, 64);
        float g0 = ec0[r] + eb0 + vx*e0c0 + vy*e1c0 + vz*e2c0;
        float g1 = ec1[r] + eb1 + vx*e0c1 + vy*e1c1 + vz*e2c1;
        float g2 = ec2[r] + eb2 + vx*e0c2 + vy*e1c2 + vz*e2c2;
        float g3 = ec3[r] + eb3 + vx*e0c3 + vy*e1c3 + vz*e2c3;
        s4v o; o.x=(short)f2h(g0); o.y=(short)f2h(g1); o.z=(short)f2h(g2); o.w=(short)f2h(g3);
        *(s4v*)(gout + (size_t)row*64 + l15*4) = o;
      }
    }
  }
}

// ============================ MFMA GEMM with optional fused secondary GEMM ============================
// Permuted activation layout. vec2 (EMODE1) and rel (USEREL) staged cooperatively:
// one 48-lane coalesced load + shfl instead of 12 uniform loads per tile.

template<bool RELU, int NRES, bool USEREL, bool GATHER, bool OUT16, bool F16O, int EMODE, bool ERELU>
__global__ __launch_bounds__(256) void k_gemm(
    const ushortT* __restrict__ A, const ushortT* __restrict__ Wt,
    const float* __restrict__ bias, const float* __restrict__ Wr,
    const float* __restrict__ rel, const int* __restrict__ gidx,
    const ushortT* __restrict__ r1, const ushortT* __restrict__ r2,
    ushortT* __restrict__ out16,
    const ushortT* __restrict__ Wt2, const float* __restrict__ bias2,
    const float* __restrict__ Wr2, const float* __restrict__ vec2,
    void* __restrict__ eout,
    int n, int ntiles)
{
  constexpr int LDSZ = (EMODE>0) ? 4*16*LSTR : 4;
  __shared__ ushortT lds[LDSZ];
  int tid = threadIdx.x;
  int lane = tid & 63, wslot = tid >> 6;
  int quad = lane >> 4, l15 = lane & 15;
  int r3 = lane/3, c3 = lane - r3*3;
  int gw = (blockIdx.x*256 + tid) >> 6;
  int nw = (gridDim.x*256) >> 6;

  short8 bfr0_0 = *(const short8*)(Wt + ( 0 + l15)*64 +  0 + quad*8);
  short8 bfr0_1 = *(const short8*)(Wt + ( 0 + l15)*64 + 32 + quad*8);
  short8 bfr1_0 = *(const short8*)(Wt + (16 + l15)*64 +  0 + quad*8);
  short8 bfr1_1 = *(const short8*)(Wt + (16 + l15)*64 + 32 + quad*8);
  short8 bfr2_0 = *(const short8*)(Wt + (32 + l15)*64 +  0 + quad*8);
  short8 bfr2_1 = *(const short8*)(Wt + (32 + l15)*64 + 32 + quad*8);
  short8 bfr3_0 = *(const short8*)(Wt + (48 + l15)*64 +  0 + quad*8);
  short8 bfr3_1 = *(const short8*)(Wt + (48 + l15)*64 + 32 + quad*8);
  float bs0 = bias[ 0 + l15], bs1 = bias[16 + l15];
  float bs2 = bias[32 + l15], bs3 = bias[48 + l15];
  float w0c0=0,w0c1=0,w0c2=0,w0c3=0, w1c0=0,w1c1=0,w1c2=0,w1c3=0, w2c0=0,w2c1=0,w2c2=0,w2c3=0;
  if (USEREL){
    w0c0=Wr[0*64+l15]; w0c1=Wr[0*64+16+l15]; w0c2=Wr[0*64+32+l15]; w0c3=Wr[0*64+48+l15];
    w1c0=Wr[1*64+l15]; w1c1=Wr[1*64+16+l15]; w1c2=Wr[1*64+32+l15]; w1c3=Wr[1*64+48+l15];
    w2c0=Wr[2*64+l15]; w2c1=Wr[2*64+16+l15]; w2c2=Wr[2*64+32+l15]; w2c3=Wr[2*64+48+l15];
  }

  short8 s0_0{}, s0_1{}, s1_0{}, s1_1{}, s2_0{}, s2_1{}, s3_0{}, s3_1{};
  float eb0=0, eb1=0, eb2=0, eb3=0;
  float e0c0=0,e0c1=0,e0c2=0,e0c3=0, e1c0=0,e1c1=0,e1c2=0,e1c3=0, e2c0=0,e2c1=0,e2c2=0,e2c3=0;
  float ebias_c = 0.f;
  if (EMODE == 1){
    s0_0 = *(const short8*)(Wt2 + ( 0 + l15)*64 +  0 + quad*8);
    s0_1 = *(const short8*)(Wt2 + ( 0 + l15)*64 + 32 + quad*8);
    s1_0 = *(const short8*)(Wt2 + (16 + l15)*64 +  0 + quad*8);
    s1_1 = *(const short8*)(Wt2 + (16 + l15)*64 + 32 + quad*8);
    s2_0 = *(const short8*)(Wt2 + (32 + l15)*64 +  0 + quad*8);
    s2_1 = *(const short8*)(Wt2 + (32 + l15)*64 + 32 + quad*8);
    s3_0 = *(const short8*)(Wt2 + (48 + l15)*64 +  0 + quad*8);
    s3_1 = *(const short8*)(Wt2 + (48 + l15)*64 + 32 + quad*8);
    eb0 = bias2[l15]; eb1 = bias2[16+l15]; eb2 = bias2[32+l15]; eb3 = bias2[48+l15];
    e0c0=Wr2[0*64+l15]; e0c1=Wr2[0*64+16+l15]; e0c2=Wr2[0*64+32+l15]; e0c3=Wr2[0*64+48+l15];
    e1c0=Wr2[1*64+l15]; e1c1=Wr2[1*64+16+l15]; e1c2=Wr2[1*64+32+l15]; e1c3=Wr2[1*64+48+l15];
    e2c0=Wr2[2*64+l15]; e2c1=Wr2[2*64+16+l15]; e2c2=Wr2[2*64+32+l15]; e2c3=Wr2[2*64+48+l15];
  } else if (EMODE == 2){
    s0_0 = *(const short8*)(Wt2 + l15*64 +  0 + quad*8);
    s0_1 = *(const short8*)(Wt2 + l15*64 + 32 + quad*8);
    ebias_c = (l15 < 8) ? bias2[l15] : 0.f;
  }

  for (int t=gw; t<ntiles; t+=nw){
    int i0 = t*16;
    int rowA = i0 + l15; if (rowA >= n) rowA = n-1;
    if (GATHER) rowA = gidx[rowA];
    const ushortT* ap = A + (size_t)rowA*64 + quad*8;
    short8 a0 = *(const short8*)(ap);
    short8 a1 = *(const short8*)(ap + 32);
    // cooperative stage of rel (USEREL): 48-lane coalesced load
    float relL = 0.f;
    if (USEREL && lane < 48){
      int rc = i0 + r3; if (rc >= n) rc = n-1;
      relL = rel[(size_t)rc*3 + c3];
    }
    v4f ac0 = {0.f,0.f,0.f,0.f}, ac1 = ac0, ac2 = ac0, ac3 = ac0;
    ac0 = __builtin_amdgcn_mfma_f32_16x16x32_bf16(a0, bfr0_0, ac0, 0,0,0);
    ac1 = __builtin_amdgcn_mfma_f32_16x16x32_bf16(a0, bfr1_0, ac1, 0,0,0);
    ac2 = __builtin_amdgcn_mfma_f32_16x16x32_bf16(a0, bfr2_0, ac2, 0,0,0);
    ac3 = __builtin_amdgcn_mfma_f32_16x16x32_bf16(a0, bfr3_0, ac3, 0,0,0);
    ac0 = __builtin_amdgcn_mfma_f32_16x16x32_bf16(a1, bfr0_1, ac0, 0,0,0);
    ac1 = __builtin_amdgcn_mfma_f32_16x16x32_bf16(a1, bfr1_1, ac1, 0,0,0);
    ac2 = __builtin_amdgcn_mfma_f32_16x16x32_bf16(a1, bfr2_1, ac2, 0,0,0);
    ac3 = __builtin_amdgcn_mfma_f32_16x16x32_bf16(a1, bfr3_1, ac3, 0,0,0);

    #pragma unroll
    for (int r=0;r<4;++r){
      int row = i0 + quad*4 + r;
      bool rowok = (row < n);
      float v0 = ac0[r] + bs0, v1 = ac1[r] + bs1, v2 = ac2[r] + bs2, v3 = ac3[r] + bs3;
      if (USEREL){
        int rr4 = quad*4 + r;
        float rx = __shfl(relL, 3*rr4+0, 64);
        float ry = __shfl(relL, 3*rr4+1, 64);
        float rz = __shfl(relL, 3*rr4+2, 64);
        v0 += rx*w0c0 + ry*w1c0 + rz*w2c0;
        v1 += rx*w0c1 + ry*w1c1 + rz*w2c1;
        v2 += rx*w0c2 + ry*w1c2 + rz*w2c2;
        v3 += rx*w0c3 + ry*w1c3 + rz*w2c3;
      }
      if (RELU){ v0=fmaxf(v0,0.f); v1=fmaxf(v1,0.f); v2=fmaxf(v2,0.f); v3=fmaxf(v3,0.f); }
      size_t pb = (size_t)row*64 + l15*4;
      if (rowok){
        if (NRES>=1){
          s4v rv = *(const s4v*)(r1 + pb);
          v0 += bf2f((ushortT)rv.x); v1 += bf2f((ushortT)rv.y);
          v2 += bf2f((ushortT)rv.z); v3 += bf2f((ushortT)rv.w);
        }
        if (NRES>=2){
          s4v rv = *(const s4v*)(r2 + pb);
          v0 += bf2f((ushortT)rv.x); v1 += bf2f((ushortT)rv.y);
          v2 += bf2f((ushortT)rv.z); v3 += bf2f((ushortT)rv.w);
        }
        if (OUT16){
          s4v o;
          if (F16O){ o.x=(short)f2h(v0); o.y=(short)f2h(v1); o.z=(short)f2h(v2); o.w=(short)f2h(v3); }
          else     { o.x=(short)f2bf(v0); o.y=(short)f2bf(v1); o.z=(short)f2bf(v2); o.w=(short)f2bf(v3); }
          *(s4v*)(out16 + pb) = o;
        }
      }
      if (EMODE > 0){
        int lb = wslot*(16*LSTR) + (quad*4+r)*LSTR + l15*4;
        s4v o; o.x=(short)f2bf(v0); o.y=(short)f2bf(v1); o.z=(short)f2bf(v2); o.w=(short)f2bf(v3);
        *(s4v*)(lds + lb) = o;
      }
    }

    if (EMODE > 0){
      __builtin_amdgcn_wave_barrier();
      const ushortT* lp = lds + wslot*(16*LSTR) + l15*LSTR + quad*8;
      short8 sa0 = *(const short8*)(lp);
      short8 sa1 = *(const short8*)(lp + 32);
      __builtin_amdgcn_wave_barrier();
      if (EMODE == 1){
        // cooperative stage of vec2: 48-lane coalesced load
        float posv = 0.f;
        if (lane < 48){
          int rc = i0 + r3; if (rc >= n) rc = n-1;
          posv = vec2[(size_t)rc*3 + c3];
        }
        v4f ec0 = {0.f,0.f,0.f,0.f}, ec1 = ec0, ec2 = ec0, ec3 = ec0;
        ec0 = __builtin_amdgcn_mfma_f32_16x16x32_bf16(sa0, s0_0, ec0, 0,0,0);
        ec1 = __builtin_amdgcn_mfma_f32_16x16x32_bf16(sa0, s1_0, ec1, 0,0,0);
        ec2 = __builtin_amdgcn_mfma_f32_16x16x32_bf16(sa0, s2_0, ec2, 0,0,0);
        ec3 = __builtin_amdgcn_mfma_f32_16x16x32_bf16(sa0, s3_0, ec3, 0,0,0);
        ec0 = __builtin_amdgcn_mfma_f32_16x16x32_bf16(sa1, s0_1, ec0, 0,0,0);
        ec1 = __builtin_amdgcn_mfma_f32_16x16x32_bf16(sa1, s1_1, ec1, 0,0,0);
        ec2 = __builtin_amdgcn_mfma_f32_16x16x32_bf16(sa1, s2_1, ec2, 0,0,0);
        ec3 = __builtin_amdgcn_mfma_f32_16x16x32_bf16(sa1, s3_1, ec3, 0,0,0);
        ushortT* eo = (ushortT*)eout;
        #pragma unroll
        for (int r=0;r<4;++r){
          int row = i0 + quad*4 + r;
          if (row < n){
            int rr4 = quad*4 + r;
            float vx = __shfl(posv, 3*rr4+0, 64);
            float vy = __shfl(posv, 3*rr4+1, 64);
            float vz = __shfl(posv, 3*rr4+2, 64);
            float g0 = ec0[r] + eb0 + vx*e0c0 + vy*e1c0 + vz*e2c0;
            float g1 = ec1[r] + eb1 + vx*e0c1 + vy*e1c1 + vz*e2c1;
            float g2 = ec2[r] + eb2 + vx*e0c2 + vy*e1c2 + vz*e2c2;
            float g3 = ec3[r] + eb3 + vx*e0c3 + vy*e1c3 + vz*e2c3;
            if (ERELU){ g0=fmaxf(g0,0.f); g1=fmaxf(g1,0.f); g2=fmaxf(g2,0.f); g3=fmaxf(g3,0.f); }
            s4v o; o.x=(short)f2h(g0); o.y=(short)f2h(g1); o.z=(short)f2h(g2); o.w=(short)f2h(g3);
            *(s4v*)(eo + (size_t)row*64 + l15*4) = o;
          }
        }
      } else {
        v4f ec = {0.f,0.f,0.f,0.f};
        ec = __builtin_amdgcn_mfma_f32_16x16x32_bf16(sa0, s0_0, ec, 0,0,0);
        ec = __builtin_amdgcn_mfma_f32_16x16x32_bf16(sa1, s0_1, ec, 0,0,0);
        if (l15 < 8){
          float* eo = (float*)eout;
          #pragma unroll
          for (int r=0;r<4;++r){
            int row = i0 + quad*4 + r;
            if (row < n) eo[(size_t)row*8 + l15] = ec[r] + ebias_c;
          }
        }
      }
    }
  }
}

// ============================ edge aggregation: 8 dsts/wave, 8 lanes per dst (R0 shape) ============================
// Wp is the PERMUTED 3x64 pos-weight block (wpp), matching the permuted column storage.

__global__ __launch_bounds__(256) void k_edge_agg(const int* __restrict__ offs, const int* __restrict__ csr,
                                                  const float* __restrict__ pos, const ushortT* __restrict__ g,
                                                  const float* __restrict__ Wp, ushortT* __restrict__ agg, int n){
  int lane = threadIdx.x & 63;
  int grp = lane >> 3, d8 = lane & 7;
  int gbase = lane & 56;
  int gw = (blockIdx.x*256 + threadIdx.x) >> 6;
  int nw = (gridDim.x*256) >> 6;
  const u4v* g4 = (const u4v*)g;
  float2 w0[4], w1[4], w2[4];
  #pragma unroll
  for (int q=0;q<4;++q){
    w0[q] = *(const float2*)(Wp + 0*64 + d8*8 + 2*q);
    w1[q] = *(const float2*)(Wp + 1*64 + d8*8 + 2*q);
    w2[q] = *(const float2*)(Wp + 2*64 + d8*8 + 2*q);
  }
  const h2 NEGBIG = {(_Float16)-60000.f, (_Float16)-60000.f};
  int n8 = (n+7) >> 3;
  for (int ii=gw; ii<n8; ii+=nw){
    int i0 = ii*8;
    int ig = i0 + grp; bool ok = ig < n; if (!ok) ig = n-1;
    int b = offs[ig], e = offs[ig+1];
    int cnt = e - b, c1 = cnt - 1;
    int mx = cnt;
    mx = max(mx, __shfl_xor(mx, 8, 64));
    mx = max(mx, __shfl_xor(mx, 16, 64));
    mx = max(mx, __shfl_xor(mx, 32, 64));
    h2 m0=NEGBIG, m1=NEGBIG, m2=NEGBIG, m3=NEGBIG;
    for (int J=0; J<mx; J+=8){
      if (J < cnt){
        int sv = csr[b + min(J + d8, c1)];
        #pragma unroll
        for (int jj=0; jj<8; ++jj){
          int s = __shfl(sv, gbase + jj, 64);
          u4v u = g4[(size_t)s*8 + d8];
          m0 = pkmax(m0, u2h(u.x));
          m1 = pkmax(m1, u2h(u.y));
          m2 = pkmax(m2, u2h(u.z));
          m3 = pkmax(m3, u2h(u.w));
        }
      }
    }
    float px = pos[ig*3+0], py = pos[ig*3+1], pz = pos[ig*3+2];
    u4v outv;
    {
      float sA = w0[0].x*px + w1[0].x*py + w2[0].x*pz;
      float sB = w0[0].y*px + w1[0].y*py + w2[0].y*pz;
      outv.x = (unsigned)f2bf(fmaxf((float)m0.x - sA, 0.f)) |
               ((unsigned)f2bf(fmaxf((float)m0.y - sB, 0.f)) << 16);
    }
    {
      float sA = w0[1].x*px + w1[1].x*py + w2[1].x*pz;
      float sB = w0[1].y*px + w1[1].y*py + w2[1].y*pz;
      outv.y = (unsigned)f2bf(fmaxf((float)m1.x - sA, 0.f)) |
               ((unsigned)f2bf(fmaxf((float)m1.y - sB, 0.f)) << 16);
    }
    {
      float sA = w0[2].x*px + w1[2].x*py + w2[2].x*pz;
      float sB = w0[2].y*px + w1[2].y*py + w2[2].y*pz;
      outv.z = (unsigned)f2bf(fmaxf((float)m2.x - sA, 0.f)) |
               ((unsigned)f2bf(fmaxf((float)m2.y - sB, 0.f)) << 16);
    }
    {
      float sA = w0[3].x*px + w1[3].x*py + w2[3].x*pz;
      float sB = w0[3].y*px + w1[3].y*py + w2[3].y*pz;
      outv.w = (unsigned)f2bf(fmaxf((float)m3.x - sA, 0.f)) |
               ((unsigned)f2bf(fmaxf((float)m3.y - sB, 0.f)) << 16);
    }
    if (ok) ((u4v*)agg)[(size_t)ig*8 + d8] = outv;
  }
}

// ============================ segment sum via label CSR (f16 in, bf16 out) ============================

__global__ __launch_bounds__(256) void k_seg_gather(const int* __restrict__ offs, const int* __restrict__ csr,
                                                    const ushortT* __restrict__ h, ushortT* __restrict__ c, int m){
  int lane = threadIdx.x & 63;
  int wv = (blockIdx.x*256 + threadIdx.x) >> 6;
  if (wv >= m) return;
  int b = offs[wv], e = offs[wv+1];
  float acc = 0.f;
  for (int k=b; k<e; ++k){
    int i = csr[k];
    acc += h2f(h[(size_t)i*64+lane]);
  }
  c[(size_t)wv*64+lane] = f2bf(acc);
}

// ============================ host launcher ============================

extern "C" void kernel_launch(void* const* d_in, const int* in_sizes, int n_in,
                              void* d_out, int out_size, void* d_ws, size_t ws_size,
                              hipStream_t stream){
  const float* features = (const float*)d_in[0];
  const float* points   = (const float*)d_in[1];
  const float* centers  = (const float*)d_in[2];
  const int*   l0e      = (const int*)d_in[3];
  const int*   l1e      = (const int*)d_in[4];
  const int*   labels   = (const int*)d_in[5];
  const float* W_fe = (const float*)d_in[6];
  const float* b_fe = (const float*)d_in[7];
  const float* mWe  = (const float*)d_in[8];
  const float* mbe  = (const float*)d_in[9];
  const float* mWu  = (const float*)d_in[10];
  const float* mbu  = (const float*)d_in[11];
  const float* W_m1 = (const float*)d_in[12];
  const float* b_m1 = (const float*)d_in[13];
  const float* W_m2 = (const float*)d_in[14];
  const float* b_m2 = (const float*)d_in[15];
  const float* gWe  = (const float*)d_in[16];
  const float* gbe  = (const float*)d_in[17];
  const float* gWu  = (const float*)d_in[18];
  const float* gbu  = (const float*)d_in[19];
  const float* W_l  = (const float*)d_in[20];
  const float* b_l  = (const float*)d_in[21];
  const float* W_c  = (const float*)d_in[22];
  const float* b_c  = (const float*)d_in[23];
  float* out = (float*)d_out;

  char* w = (char*)d_ws;
  size_t off = 0;
  auto alloc = [&](size_t bytes)->void*{
    void* p = (void*)(w + off);
    off = (off + bytes + 255) & ~(size_t)255;
    return p;
  };
  float* rel  = (float*)alloc((size_t)N_PTS*3*4);
  ushortT* UF1 = (ushortT*)alloc((size_t)N_PTS*64*2);
  ushortT* UF2 = (ushortT*)alloc((size_t)N_PTS*64*2);
  ushortT* UF21= (ushortT*)alloc((size_t)N_PTS*64*2);
  ushortT* UF5 = (ushortT*)alloc((size_t)N_PTS*64*2);
  ushortT* UF6 = (ushortT*)alloc((size_t)N_PTS*64*2);
  ushortT* gbuf= (ushortT*)alloc((size_t)N_PTS*64*2);
  ushortT* abuf= (ushortT*)alloc((size_t)N_PTS*64*2);
  ushortT* cb_b= (ushortT*)alloc((size_t)M_CL*64*2);
  ushortT* UF3 = (ushortT*)alloc((size_t)M_CL*64*2);
  ushortT* UF4 = (ushortT*)alloc((size_t)M_CL*64*2);
  ushortT* cg_b= (ushortT*)alloc((size_t)M_CL*64*2);
  ushortT* cagg_b = (ushortT*)alloc((size_t)M_CL*64*2);
  ushortT* f41_b  = (ushortT*)alloc((size_t)M_CL*64*2);
  ushortT* wt  = (ushortT*)alloc((size_t)15*4096*2);
  ushortT* wtc = (ushortT*)alloc((size_t)1024*2);
  float* wpp = (float*)alloc((size_t)6*192*4);
  int* offs0 = (int*)alloc((size_t)(N_PTS+1)*4);
  int* csr0  = (int*)alloc((size_t)E0_N*4);
  int* offs1 = (int*)alloc((size_t)(M_CL+1)*4);
  int* csr1  = (int*)alloc((size_t)E1_N*4);
  int* offsL = (int*)alloc((size_t)(M_CL+1)*4);
  int* csrL  = (int*)alloc((size_t)N_PTS*4);
  unsigned* tmp0 = (unsigned*)alloc((size_t)NB*BCAP0*4);
  unsigned* tmp1 = (unsigned*)alloc((size_t)NB*BCAP1*4);
  unsigned* tmpL = (unsigned*)alloc((size_t)NB*BCAPL*4);
  int* bcur0 = (int*)alloc(NB*4);
  int* bcur1 = (int*)alloc(NB*4);
  int* bcurL = (int*)alloc(NB*4);
  (void)ws_size; (void)in_sizes; (void)n_in; (void)out_size;

  const int NT_N = (N_PTS+15)/16;
  const int NT_M = (M_CL +15)/16;
  const int GBG_N = 1563;
  const int GBG_M = 196;
  const int GB_N  = 3125;
  const int GB_BIN = 1027;    // 782 + 196 + 49 chunks, one per block

  // ---- setup: weights(K-permuted) + wpp + counters (1), bin+f1g fused (1), build (1) ----
  WSrc ws{};
  ws.p[0]=mWu+0*4096; ws.p[1]=mWu+1*4096; ws.p[2]=mWu+2*4096; ws.p[3]=mWu+3*4096;
  ws.p[4]=W_m2; ws.p[5]=gWu+0*4096; ws.p[6]=gWu+1*4096;
  ws.p[7]=mWe+0*4288+192; ws.p[8]=mWe+1*4288+192; ws.p[9]=mWe+2*4288+192; ws.p[10]=mWe+3*4288+192;
  ws.p[11]=W_m1; ws.p[12]=W_l; ws.p[13]=gWe+0*4288+192; ws.p[14]=gWe+1*4288+192;
  ws.p[15]=W_c;
  ws.p[16]=mWe+0*4288; ws.p[17]=mWe+1*4288; ws.p[18]=mWe+2*4288; ws.p[19]=mWe+3*4288;
  ws.p[20]=gWe+0*4288; ws.p[21]=gWe+1*4288;
  k_init_wprep<<<18, 256, 0, stream>>>(ws, wt, wtc, wpp, bcur0, bcur1, bcurL);
  k_bin_f1g<<<GB_BIN + GBG_N, 256, 0, stream>>>(l0e, l1e, labels, bcur0, bcur1, bcurL, tmp0, tmp1, tmpL,
      features, points, centers, W_fe, b_fe,
      wt+7*4096, mbe+0, mWe+0*4288, rel, UF1, gbuf, N_PTS, NT_N, GBG_N);
  k_build_all<<<768, 256, 0, stream>>>(tmp0, bcur0, offs0, csr0,
                                       tmp1, bcur1, offs1, csr1,
                                       tmpL, bcurL, offsL, csrL);

  // ---- layer0: agg -> FUSED [f2 -> UF2] + [g1' -> gbuf] ----
  k_edge_agg<<<GB_N,256,0,stream>>>(offs0, csr0, points, gbuf, wpp+0*192, abuf, N_PTS);
  k_gemm<true,1,false,false,true,false,1,false><<<GBG_N,256,0,stream>>>(abuf, wt+0*4096, mbu+0,
      nullptr, nullptr, nullptr, UF1, nullptr, UF2,
      wt+8*4096, mbe+64, mWe+1*4288, points, gbuf, N_PTS, NT_N);
  // ---- layer1: agg -> FUSED [f2_1 -> UF21] + [h -> gbuf] ----
  k_edge_agg<<<GB_N,256,0,stream>>>(offs0, csr0, points, gbuf, wpp+1*192, abuf, N_PTS);
  k_gemm<true,1,false,false,true,false,1,true><<<GBG_N,256,0,stream>>>(abuf, wt+1*4096, mbu+64,
      nullptr, nullptr, nullptr, UF2, nullptr, UF21,
      wt+11*4096, b_m1, W_m1+4096, rel, gbuf, N_PTS, NT_N);
  // ---- c = segsum(h); FUSED [f3 -> UF3] + [cg0' -> cg_b] ----
  k_seg_gather<<<(M_CL*64+255)/256, 256, 0, stream>>>(offsL, csrL, gbuf, cb_b, M_CL);
  k_gemm<true,0,false,false,true,false,1,false><<<GBG_M,256,0,stream>>>(cb_b, wt+4*4096, b_m2,
      nullptr, nullptr, nullptr, nullptr, nullptr, UF3,
      wt+13*4096, gbe+0, gWe+0*4288, centers, cg_b, M_CL, NT_M);
  // ---- cluster layer0: agg -> FUSED [f4 -> UF4] + [cg1' -> cg_b] ----
  k_edge_agg<<<GBG_M,256,0,stream>>>(offs1, csr1, centers, cg_b, wpp+4*192, cagg_b, M_CL);
  k_gemm<true,1,false,false,true,false,1,false><<<GBG_M,256,0,stream>>>(cagg_b, wt+5*4096, gbu+0,
      nullptr, nullptr, nullptr, UF3, nullptr, UF4,
      wt+14*4096, gbe+64, gWe+1*4288, centers, cg_b, M_CL, NT_M);
  // ---- cluster layer1: agg -> f4_1 -> f41_b ----
  k_edge_agg<<<GBG_M,256,0,stream>>>(offs1, csr1, centers, cg_b, wpp+5*192, cagg_b, M_CL);
  k_gemm<true,1,false,false,true,false,0,false><<<GBG_M,256,0,stream>>>(cagg_b, wt+6*4096, gbu+64,
      nullptr, nullptr, nullptr, UF4, nullptr, f41_b,
      nullptr, nullptr, nullptr, nullptr, nullptr, M_CL, NT_M);
  // ---- FUSED [f5 -> UF5] + [g2' -> gbuf] ----
  k_gemm<true,0,true,true,true,false,1,false><<<GBG_N,256,0,stream>>>(f41_b, wt+12*4096, b_l,
      W_l+4096, rel, labels, nullptr, nullptr, UF5,
      wt+9*4096, mbe+128, mWe+2*4288, points, gbuf, N_PTS, NT_N);
  // ---- layer2: agg -> FUSED [f6 = relu+f5+f2_1 -> UF6] + [g3' -> gbuf] ----
  k_edge_agg<<<GB_N,256,0,stream>>>(offs0, csr0, points, gbuf, wpp+2*192, abuf, N_PTS);
  k_gemm<true,2,false,false,true,false,1,false><<<GBG_N,256,0,stream>>>(abuf, wt+2*4096, mbu+128,
      nullptr, nullptr, nullptr, UF5, UF21, UF6,
      wt+10*4096, mbe+192, mWe+3*4288, points, gbuf, N_PTS, NT_N);
  // ---- layer3: agg -> FUSED [final = relu+f6+f2] + [out = final@W_c + b_c] ----
  k_edge_agg<<<GB_N,256,0,stream>>>(offs0, csr0, points, gbuf, wpp+3*192, abuf, N_PTS);
  k_gemm<true,2,false,false,false,false,2,false><<<GBG_N,256,0,stream>>>(abuf, wt+3*4096, mbu+192,
      nullptr, nullptr, nullptr, UF6, UF2, nullptr,
      wtc, b_c, nullptr, nullptr, out, N_PTS, NT_N);
}